// Round 8
// baseline (1289.793 us; speedup 1.0000x reference)
//
#include <hip/hip_runtime.h>

using short8  = __attribute__((ext_vector_type(8))) short;
using floatx4 = __attribute__((ext_vector_type(4))) float;

__device__ __forceinline__ unsigned short f2bf(float x) {
  unsigned int u = __float_as_uint(x);
  return (unsigned short)((u + 0x7FFFu + ((u >> 16) & 1u)) >> 16);
}
__device__ __forceinline__ float bf2f(unsigned short h) {
  return __uint_as_float(((unsigned int)h) << 16);
}

// ---------------- small elementwise / setup kernels ----------------
__global__ void k_fill1(float* __restrict__ p, int n) {
  int i = blockIdx.x * 256 + threadIdx.x;
  if (i < n) p[i] = 1.0f;
}

__global__ void k_edge_deg(const int* __restrict__ ei, float* __restrict__ deg, int E) {
  int e = blockIdx.x * 256 + threadIdx.x;
  if (e < E) atomicAdd(&deg[ei[E + e]], 1.0f);
}

__global__ void k_rsqrt(float* __restrict__ dinv, const float* __restrict__ deg, int n) {
  int i = blockIdx.x * 256 + threadIdx.x;
  if (i < n) dinv[i] = rsqrtf(deg[i]);
}

__global__ void k_f32bf16(const float* __restrict__ src, unsigned short* __restrict__ dst, int n) {
  int i = blockIdx.x * 256 + threadIdx.x;
  if (i < n) dst[i] = f2bf(src[i]);
}

// hi = bf16(x); lo = bf16(x - hi)
__global__ void k_f32bf16_split(const float* __restrict__ src, unsigned short* __restrict__ hi,
                                unsigned short* __restrict__ lo, int n) {
  int i = blockIdx.x * 256 + threadIdx.x;
  if (i < n) {
    float x = src[i];
    unsigned short h = f2bf(x);
    hi[i] = h;
    lo[i] = f2bf(x - bf2f(h));
  }
}

// ---------------- CSR build: scan + scatter ----------------
__global__ __launch_bounds__(1024) void k_scan(const float* __restrict__ deg,
                                               int* __restrict__ off, int N) {
  __shared__ int wsum[16];
  __shared__ int carry;
  if (threadIdx.x == 0) carry = 0;
  int lane = threadIdx.x & 63, wv = threadIdx.x >> 6;
  for (int base = 0; base < N; base += 1024) {
    int i = base + threadIdx.x;
    int c = (i < N) ? ((int)deg[i] - 1) : 0;
    int s = c;
    #pragma unroll
    for (int o = 1; o < 64; o <<= 1) {
      int t = __shfl_up(s, o);
      if (lane >= o) s += t;
    }
    __syncthreads();
    if (lane == 63) wsum[wv] = s;
    __syncthreads();
    int wpre = 0, total = 0;
    #pragma unroll
    for (int w = 0; w < 16; ++w) {
      int v = wsum[w];
      if (w < wv) wpre += v;
      total += v;
    }
    if (i < N) off[i] = carry + wpre + s - c;
    __syncthreads();
    if (threadIdx.x == 0) carry += total;
  }
  __syncthreads();
  if (threadIdx.x == 0) off[N] = carry;
}

__global__ void k_scatter(const int* __restrict__ ei, int* __restrict__ cur,
                          int* __restrict__ srcs, int E) {
  int e = blockIdx.x * 256 + threadIdx.x;
  if (e < E) {
    int r = ei[e], c = ei[E + e];
    int p = atomicAdd(&cur[c], 1);
    srcs[p] = r;
  }
}

__global__ __launch_bounds__(256) void k_gcn_agg(const int* __restrict__ off,
    const int* __restrict__ srcs, const float* __restrict__ dinv,
    const float* __restrict__ h0, const float* __restrict__ gcn_b,
    float* __restrict__ Hb, int N) {
  int node = blockIdx.x * 4 + (threadIdx.x >> 6);
  if (node >= N) return;
  int c2 = (threadIdx.x & 63) * 2;
  float dc = dinv[node];
  float a0 = 0.f, a1 = 0.f;
  int j = off[node], end = off[node + 1];
  for (; j + 1 < end; j += 2) {
    int s0 = srcs[j], s1 = srcs[j + 1];
    float w0 = dinv[s0] * dc, w1 = dinv[s1] * dc;
    float2 h0v = *(const float2*)&h0[(long)s0 * 128 + c2];
    float2 h1v = *(const float2*)&h0[(long)s1 * 128 + c2];
    a0 += w0 * h0v.x + w1 * h1v.x;
    a1 += w0 * h0v.y + w1 * h1v.y;
  }
  if (j < end) {
    int s0 = srcs[j];
    float w0 = dinv[s0] * dc;
    float2 hv = *(const float2*)&h0[(long)s0 * 128 + c2];
    a0 += w0 * hv.x;
    a1 += w0 * hv.y;
  }
  float2 hv = *(const float2*)&h0[(long)node * 128 + c2];
  float2 b  = *(const float2*)&gcn_b[c2];
  float v0 = a0 + dc * dc * hv.x + b.x;
  float v1 = a1 + dc * dc * hv.y + b.y;
  *(float2*)&Hb[(long)node * 128 + c2] = make_float2(fmaxf(v0, 0.f), fmaxf(v1, 0.f));
}

__global__ void k_final(const float* __restrict__ T, const float* __restrict__ Hb,
                        float* __restrict__ out, int N) {
  long i = (long)blockIdx.x * 256 + threadIdx.x;
  if (i >= (long)N * 32) return;
  long off = i * 4;
  float4 t = *(const float4*)&T[off];
  float4 h = *(const float4*)&Hb[off];
  float4 o;
  o.x = fmaxf(t.x + h.x, 0.f);
  o.y = fmaxf(t.y + h.y, 0.f);
  o.z = fmaxf(t.z + h.z, 0.f);
  o.w = fmaxf(t.w + h.w, 0.f);
  *(float4*)&out[off] = o;
}

// Wc[l] = out_w[l] @ Wv[l]; bc[l] = out_w[l] @ bv[l] + out_b[l]
__global__ void k_combine(const float* __restrict__ in_w, const float* __restrict__ in_b,
                          const float* __restrict__ out_w, const float* __restrict__ out_b,
                          float* __restrict__ Wc, float* __restrict__ bc) {
  __shared__ float Wvs[128][129];
  int l = blockIdx.x;
  const float* Wv = in_w + (long)l * 384 * 128 + 256 * 128;
  const float* bv = in_b + l * 384 + 256;
  const float* Wo = out_w + (long)l * 128 * 128;
  for (int i = threadIdx.x; i < 128 * 128; i += 256)
    Wvs[i >> 7][i & 127] = Wv[i];
  __syncthreads();
  for (int o = threadIdx.x; o < 128 * 128; o += 256) {
    int i = o >> 7, j = o & 127;
    float acc = 0.f;
    for (int k = 0; k < 128; ++k) acc += Wo[i * 128 + k] * Wvs[k][j];
    Wc[(long)l * 16384 + o] = acc;
  }
  if (threadIdx.x < 128) {
    int i = threadIdx.x;
    float acc = out_b[l * 128 + i];
    for (int k = 0; k < 128; ++k) acc += Wo[i * 128 + k] * bv[k];
    bc[l * 128 + i] = acc;
  }
}

// ---------------- round-4 MFMA GEMM helpers (verified) ----------------
__device__ __forceinline__ void stage_xf32_split(unsigned short (*dh)[136], unsigned short (*dl)[136],
                                                 const float* __restrict__ src, long row0, int N) {
  #pragma unroll
  for (int it = 0; it < 2; ++it) {
    int i = it * 512 + threadIdx.x;
    int r = i >> 4, c8 = (i & 15) * 8;
    long gr = row0 + r;
    uint4 wh = make_uint4(0u, 0u, 0u, 0u);
    uint4 wl = make_uint4(0u, 0u, 0u, 0u);
    if (gr < N) {
      const float* p = src + gr * 128 + c8;
      float v[8];
      *(float4*)&v[0] = *(const float4*)p;
      *(float4*)&v[4] = *(const float4*)(p + 4);
      unsigned short h[8], l[8];
      #pragma unroll
      for (int j = 0; j < 8; ++j) {
        h[j] = f2bf(v[j]);
        l[j] = f2bf(v[j] - bf2f(h[j]));
      }
      wh.x = (unsigned)h[0] | ((unsigned)h[1] << 16);
      wh.y = (unsigned)h[2] | ((unsigned)h[3] << 16);
      wh.z = (unsigned)h[4] | ((unsigned)h[5] << 16);
      wh.w = (unsigned)h[6] | ((unsigned)h[7] << 16);
      wl.x = (unsigned)l[0] | ((unsigned)l[1] << 16);
      wl.y = (unsigned)l[2] | ((unsigned)l[3] << 16);
      wl.z = (unsigned)l[4] | ((unsigned)l[5] << 16);
      wl.w = (unsigned)l[6] | ((unsigned)l[7] << 16);
    }
    *(uint4*)&dh[r][c8] = wh;
    *(uint4*)&dl[r][c8] = wl;
  }
}

__device__ __forceinline__ void stage_w(unsigned short (*dst)[136], const unsigned short* __restrict__ src,
                                        int ld) {
  #pragma unroll
  for (int it = 0; it < 4; ++it) {
    int i = it * 512 + threadIdx.x;
    int r = i >> 4, c8 = (i & 15) * 8;
    *(uint4*)&dst[r][c8] = *(const uint4*)&src[(long)r * ld + c8];
  }
}

__device__ __forceinline__ void mfma_64x128_3(const unsigned short (*Ah)[136], const unsigned short (*Al)[136],
                                              const unsigned short (*Bh)[136], const unsigned short (*Bl)[136],
                                              floatx4 acc[2][2]) {
  int lane = threadIdx.x & 63;
  int wave = threadIdx.x >> 6;
  int wr = (wave >> 2) * 32;
  int wc = (wave & 3) * 32;
  int r16 = lane & 15;
  int k8 = (lane >> 4) * 8;
  #pragma unroll
  for (int ks = 0; ks < 4; ++ks) {
    int k0 = ks * 32 + k8;
    short8 a0h = *(const short8*)&Ah[wr + r16][k0];
    short8 a1h = *(const short8*)&Ah[wr + 16 + r16][k0];
    short8 a0l = *(const short8*)&Al[wr + r16][k0];
    short8 a1l = *(const short8*)&Al[wr + 16 + r16][k0];
    short8 b0h = *(const short8*)&Bh[wc + r16][k0];
    short8 b1h = *(const short8*)&Bh[wc + 16 + r16][k0];
    short8 b0l = *(const short8*)&Bl[wc + r16][k0];
    short8 b1l = *(const short8*)&Bl[wc + 16 + r16][k0];
    acc[0][0] = __builtin_amdgcn_mfma_f32_16x16x32_bf16(a0h, b0h, acc[0][0], 0, 0, 0);
    acc[0][0] = __builtin_amdgcn_mfma_f32_16x16x32_bf16(a0h, b0l, acc[0][0], 0, 0, 0);
    acc[0][0] = __builtin_amdgcn_mfma_f32_16x16x32_bf16(a0l, b0h, acc[0][0], 0, 0, 0);
    acc[0][1] = __builtin_amdgcn_mfma_f32_16x16x32_bf16(a0h, b1h, acc[0][1], 0, 0, 0);
    acc[0][1] = __builtin_amdgcn_mfma_f32_16x16x32_bf16(a0h, b1l, acc[0][1], 0, 0, 0);
    acc[0][1] = __builtin_amdgcn_mfma_f32_16x16x32_bf16(a0l, b1h, acc[0][1], 0, 0, 0);
    acc[1][0] = __builtin_amdgcn_mfma_f32_16x16x32_bf16(a1h, b0h, acc[1][0], 0, 0, 0);
    acc[1][0] = __builtin_amdgcn_mfma_f32_16x16x32_bf16(a1h, b0l, acc[1][0], 0, 0, 0);
    acc[1][0] = __builtin_amdgcn_mfma_f32_16x16x32_bf16(a1l, b0h, acc[1][0], 0, 0, 0);
    acc[1][1] = __builtin_amdgcn_mfma_f32_16x16x32_bf16(a1h, b1h, acc[1][1], 0, 0, 0);
    acc[1][1] = __builtin_amdgcn_mfma_f32_16x16x32_bf16(a1h, b1l, acc[1][1], 0, 0, 0);
    acc[1][1] = __builtin_amdgcn_mfma_f32_16x16x32_bf16(a1l, b1h, acc[1][1], 0, 0, 0);
  }
}

__device__ __forceinline__ void frag_to_ys(float (*Ys)[132], const floatx4 acc[2][2]) {
  int lane = threadIdx.x & 63;
  int wave = threadIdx.x >> 6;
  int row0 = (wave >> 2) * 32 + (lane >> 4) * 4;
  int col0 = (wave & 3) * 32 + (lane & 15);
  #pragma unroll
  for (int mi = 0; mi < 2; ++mi)
    #pragma unroll
    for (int ni = 0; ni < 2; ++ni)
      #pragma unroll
      for (int r = 0; r < 4; ++r)
        Ys[row0 + mi * 16 + r][col0 + ni * 16] = acc[mi][ni][r];
}

__device__ __forceinline__ void ln_store(const float (*Ys)[132],
    const float* __restrict__ bias, const float* __restrict__ res,
    const float* __restrict__ g, const float* __restrict__ bl,
    float* __restrict__ Y, long row0, int N) {
  int r = threadIdx.x >> 3;
  int seg = (threadIdx.x & 7) * 16;
  long gr = row0 + r;
  float y[16];
  float s = 0.f, s2 = 0.f;
  if (gr < N) {
    #pragma unroll
    for (int q = 0; q < 4; ++q) {
      float4 v  = *(const float4*)&Ys[r][seg + q * 4];
      float4 b4 = *(const float4*)&bias[seg + q * 4];
      float4 rv = *(const float4*)&res[gr * 128 + seg + q * 4];
      float t0 = v.x + b4.x + rv.x;
      float t1 = v.y + b4.y + rv.y;
      float t2 = v.z + b4.z + rv.z;
      float t3 = v.w + b4.w + rv.w;
      y[q*4+0] = t0; y[q*4+1] = t1; y[q*4+2] = t2; y[q*4+3] = t3;
      s  += t0 + t1 + t2 + t3;
      s2 += t0*t0 + t1*t1 + t2*t2 + t3*t3;
    }
  } else {
    #pragma unroll
    for (int q = 0; q < 16; ++q) y[q] = 0.f;
  }
  #pragma unroll
  for (int off = 1; off < 8; off <<= 1) {
    s  += __shfl_xor(s, off);
    s2 += __shfl_xor(s2, off);
  }
  float m   = s * (1.f / 128.f);
  float var = s2 * (1.f / 128.f) - m * m;
  float inv = rsqrtf(var + 1e-5f);
  if (gr < N) {
    #pragma unroll
    for (int q = 0; q < 4; ++q) {
      float4 g4 = *(const float4*)&g[seg + q * 4];
      float4 b4 = *(const float4*)&bl[seg + q * 4];
      float4 o;
      o.x = (y[q*4+0] - m) * inv * g4.x + b4.x;
      o.y = (y[q*4+1] - m) * inv * g4.y + b4.y;
      o.z = (y[q*4+2] - m) * inv * g4.z + b4.z;
      o.w = (y[q*4+3] - m) * inv * g4.w + b4.w;
      *(float4*)&Y[gr * 128 + seg + q * 4] = o;
    }
  }
}

// ---------------- packed-fragment helpers for k_ffn ----------------
// slot(row,ks,g) = (((row>>4)*4 + ks)*4 + g)*16 + (row&15),  k = ks*32 + g*8
template<bool LO>
__device__ __forceinline__ void stage_x_packed(uint4* __restrict__ dst,
    const float* __restrict__ src, long row0, int N) {
  #pragma unroll
  for (int it = 0; it < 2; ++it) {
    int s = it * 512 + threadIdx.x;
    int r16 = s & 15, g = (s >> 4) & 3, ks = (s >> 6) & 3, rb = s >> 8;
    long gr = row0 + rb * 16 + r16;
    uint4 w = make_uint4(0u, 0u, 0u, 0u);
    if (gr < N) {
      const float* p = src + gr * 128 + ks * 32 + g * 8;
      float v[8];
      *(float4*)&v[0] = *(const float4*)p;
      *(float4*)&v[4] = *(const float4*)(p + 4);
      unsigned q[8];
      #pragma unroll
      for (int j = 0; j < 8; ++j) {
        unsigned short h = f2bf(v[j]);
        q[j] = LO ? (unsigned)f2bf(v[j] - bf2f(h)) : (unsigned)h;
      }
      w.x = q[0] | (q[1] << 16);
      w.y = q[2] | (q[3] << 16);
      w.z = q[4] | (q[5] << 16);
      w.w = q[6] | (q[7] << 16);
    }
    dst[s] = w;
  }
}

__device__ __forceinline__ void load_afrags(short8 af[2][4], const uint4* __restrict__ Xp, int wr) {
  int lane = threadIdx.x & 63;
  #pragma unroll
  for (int mi = 0; mi < 2; ++mi)
    #pragma unroll
    for (int ks = 0; ks < 4; ++ks)
      af[mi][ks] = *(const short8*)&Xp[((wr >> 4) + mi) * 256 + ks * 64 + lane];
}

// W staging split into load(global->regs) / write(regs->LDS), packed layout
__device__ __forceinline__ void stage_load(uint4 st[4], const unsigned short* __restrict__ src,
                                           long ld) {
  #pragma unroll
  for (int it = 0; it < 4; ++it) {
    int s = it * 512 + threadIdx.x;
    int n16 = s & 15, g = (s >> 4) & 3, ks = (s >> 6) & 3, nb = s >> 8;
    st[it] = *(const uint4*)&src[(long)(nb * 16 + n16) * ld + ks * 32 + g * 8];
  }
}

__device__ __forceinline__ void stage_write(uint4* __restrict__ dst, const uint4 st[4]) {
  #pragma unroll
  for (int it = 0; it < 4; ++it) dst[it * 512 + threadIdx.x] = st[it];
}

#define MF(a, b, c) __builtin_amdgcn_mfma_f32_16x16x32_bf16(a, b, c, 0, 0, 0)

// ---------------- big kernels ----------------
// round-4 exact: split-bf16 GEMM, plain store
__global__ __launch_bounds__(512) void k_gemm_plain(const float* __restrict__ X,
    const unsigned short* __restrict__ Wh, const unsigned short* __restrict__ Wl,
    float* __restrict__ Y, int N) {
  __shared__ __align__(16) unsigned short XsH[64][136];
  __shared__ __align__(16) unsigned short XsL[64][136];
  __shared__ __align__(16) unsigned short WsH[128][136];
  __shared__ __align__(16) unsigned short WsL[128][136];
  long row0 = (long)blockIdx.x * 64;
  stage_xf32_split(XsH, XsL, X, row0, N);
  stage_w(WsH, Wh, 128);
  stage_w(WsL, Wl, 128);
  __syncthreads();
  floatx4 zero = {0.f, 0.f, 0.f, 0.f};
  floatx4 acc[2][2] = {{zero, zero}, {zero, zero}};
  mfma_64x128_3(XsH, XsL, WsH, WsL, acc);
  int lane = threadIdx.x & 63;
  int wave = threadIdx.x >> 6;
  int rowb = (wave >> 2) * 32 + (lane >> 4) * 4;
  int colb = (wave & 3) * 32 + (lane & 15);
  #pragma unroll
  for (int mi = 0; mi < 2; ++mi)
    #pragma unroll
    for (int ni = 0; ni < 2; ++ni)
      #pragma unroll
      for (int r = 0; r < 4; ++r) {
        long gr = row0 + rowb + mi * 16 + r;
        if (gr < N) Y[gr * 128 + colb + ni * 16] = acc[mi][ni][r];
      }
}

// round-4 exact: split-bf16 GEMM + residual + LN epilogue
__global__ __launch_bounds__(512) void k_gemm_ln(const float* __restrict__ X,
    const unsigned short* __restrict__ Wh, const unsigned short* __restrict__ Wl,
    const float* __restrict__ bias,
    const float* __restrict__ g, const float* __restrict__ bl,
    float* __restrict__ Y, int N) {
  __shared__ __align__(16) unsigned short XsH[64][136];
  __shared__ __align__(16) unsigned short XsL[64][136];
  __shared__ union __align__(16) WY {
    struct { unsigned short h[128][136]; unsigned short l[128][136]; } w;
    float ys[64][132];
  } wy;
  long row0 = (long)blockIdx.x * 64;
  stage_xf32_split(XsH, XsL, X, row0, N);
  stage_w(wy.w.h, Wh, 128);
  stage_w(wy.w.l, Wl, 128);
  __syncthreads();
  floatx4 zero = {0.f, 0.f, 0.f, 0.f};
  floatx4 acc[2][2] = {{zero, zero}, {zero, zero}};
  mfma_64x128_3(XsH, XsL, wy.w.h, wy.w.l, acc);
  __syncthreads();
  frag_to_ys(wy.ys, acc);
  __syncthreads();
  ln_store(wy.ys, bias, X, g, bl, Y, row0, N);
}

// k_ffn v3: round-4 numerics (X split + W1 split, single Z@W2).
// X frags in regs (r7-verified), Z packed LDS (r7-verified),
// W1h/W1l/W2 staged to LDS in packed layout with async load/write split.
// LDS = 64K(w1, ys overlay) + 32K(w2) + 16K(z) = 112KB.
__global__ __launch_bounds__(512) void k_ffn(const float* __restrict__ T1,
    const unsigned short* __restrict__ W1h, const unsigned short* __restrict__ W1l,
    const float* __restrict__ b1,
    const unsigned short* __restrict__ W2b, const float* __restrict__ b2,
    const float* __restrict__ gam, const float* __restrict__ bet,
    float* __restrict__ Y, int N) {
  __shared__ union __align__(16) U1 {
    struct { uint4 h[2048]; uint4 l[2048]; } w1;
    float ys[64][132];
  } u1;
  __shared__ __align__(16) uint4 w2s[2048];
  __shared__ __align__(16) uint4 zx[1024];
  long row0 = (long)blockIdx.x * 64;
  int lane = threadIdx.x & 63;
  int wave = threadIdx.x >> 6;
  int wr = (wave >> 2) * 32, wc = (wave & 3) * 32;
  int gq = lane >> 4, r16c = lane & 15;

  // issue chunk-0 W loads early (latency hides under X staging)
  uint4 s1h[4], s1l[4], s2[4];
  stage_load(s1h, W1h, 128);
  stage_load(s1l, W1l, 128);
  stage_load(s2,  W2b, 2048);

  // X hi+lo fragments -> registers (r7-verified pattern)
  stage_x_packed<false>(zx, T1, row0, N);
  __syncthreads();
  short8 afh[2][4], afl[2][4];
  load_afrags(afh, zx, wr);
  __syncthreads();
  stage_x_packed<true>(zx, T1, row0, N);
  __syncthreads();
  load_afrags(afl, zx, wr);
  // write chunk-0 W to LDS
  stage_write(u1.w1.h, s1h);
  stage_write(u1.w1.l, s1l);
  stage_write(w2s, s2);
  __syncthreads();                         // afl reads done; W visible; zx -> Z buffer

  unsigned short* Zu = (unsigned short*)zx;
  int zb0 = (((wr >> 4) + 0) * 4 + (wc >> 5)) * 4 + (r16c >> 3);
  int zb1 = (((wr >> 4) + 1) * 4 + (wc >> 5)) * 4 + (r16c >> 3);

  floatx4 zero = {0.f, 0.f, 0.f, 0.f};
  floatx4 acc2[2][2] = {{zero, zero}, {zero, zero}};

  for (int fc = 0; fc < 16; ++fc) {
    // prefetch next chunk's W into registers (off critical path)
    if (fc < 15) {
      stage_load(s1h, W1h + (long)(fc + 1) * 16384, 128);
      stage_load(s1l, W1l + (long)(fc + 1) * 16384, 128);
      stage_load(s2,  W2b + (fc + 1) * 128, 2048);
    }
    // phase A: Zc = relu(X @ W1c^T + b1c)   (X regs, W1 LDS packed, split 3-product)
    floatx4 acc1[2][2] = {{zero, zero}, {zero, zero}};
    int nbb = (wc >> 4) * 256;
    #pragma unroll
    for (int ks = 0; ks < 4; ++ks) {
      int nb = nbb + ks * 64 + lane;
      short8 bh0 = *(const short8*)&u1.w1.h[nb];
      short8 bh1 = *(const short8*)&u1.w1.h[nb + 256];
      short8 bl0 = *(const short8*)&u1.w1.l[nb];
      short8 bl1 = *(const short8*)&u1.w1.l[nb + 256];
      acc1[0][0] = MF(afh[0][ks], bh0, acc1[0][0]);
      acc1[0][0] = MF(afh[0][ks], bl0, acc1[0][0]);
      acc1[0][0] = MF(afl[0][ks], bh0, acc1[0][0]);
      acc1[0][1] = MF(afh[0][ks], bh1, acc1[0][1]);
      acc1[0][1] = MF(afh[0][ks], bl1, acc1[0][1]);
      acc1[0][1] = MF(afl[0][ks], bh1, acc1[0][1]);
      acc1[1][0] = MF(afh[1][ks], bh0, acc1[1][0]);
      acc1[1][0] = MF(afh[1][ks], bl0, acc1[1][0]);
      acc1[1][0] = MF(afl[1][ks], bh0, acc1[1][0]);
      acc1[1][1] = MF(afh[1][ks], bh1, acc1[1][1]);
      acc1[1][1] = MF(afh[1][ks], bl1, acc1[1][1]);
      acc1[1][1] = MF(afl[1][ks], bh1, acc1[1][1]);
    }
    float bv0 = b1[fc * 128 + wc + r16c];
    float bv1 = b1[fc * 128 + wc + 16 + r16c];
    #pragma unroll
    for (int mi = 0; mi < 2; ++mi) {
      int zb = mi ? zb1 : zb0;
      #pragma unroll
      for (int ni = 0; ni < 2; ++ni) {
        float bv = ni ? bv1 : bv0;
        #pragma unroll
        for (int r = 0; r < 4; ++r) {
          float z = fmaxf(acc1[mi][ni][r] + bv, 0.f);
          Zu[(zb + 2 * ni) * 128 + (4 * gq + r) * 8 + (r16c & 7)] = f2bf(z);
        }
      }
    }
    __syncthreads();                       // Z visible; w1 reads done
    // phase B: acc2 += Zc @ W2c^T  (single bf16)
    #pragma unroll
    for (int ks = 0; ks < 4; ++ks) {
      int za = (wr >> 4) * 256 + ks * 64 + lane;
      short8 a0 = *(const short8*)&zx[za];
      short8 a1 = *(const short8*)&zx[za + 256];
      int nb = nbb + ks * 64 + lane;
      short8 b0  = *(const short8*)&w2s[nb];
      short8 b1f = *(const short8*)&w2s[nb + 256];
      acc2[0][0] = MF(a0, b0,  acc2[0][0]);
      acc2[0][1] = MF(a0, b1f, acc2[0][1]);
      acc2[1][0] = MF(a1, b0,  acc2[1][0]);
      acc2[1][1] = MF(a1, b1f, acc2[1][1]);
    }
    __syncthreads();                       // all chunk-fc LDS reads done
    if (fc < 15) {
      stage_write(u1.w1.h, s1h);
      stage_write(u1.w1.l, s1l);
      stage_write(w2s, s2);
    }
    __syncthreads();                       // next-chunk W visible (and Z writable)
  }
  frag_to_ys(u1.ys, acc2);
  __syncthreads();
  ln_store(u1.ys, b2, T1, gam, bet, Y, row0, N);
}

// ---------------- launcher ----------------
extern "C" void kernel_launch(void* const* d_in, const int* in_sizes, int n_in,
                              void* d_out, int out_size, void* d_ws, size_t ws_size,
                              hipStream_t stream) {
  const int N = in_sizes[0] / 128;
  const int E = in_sizes[1] / 2;
  const float* x     = (const float*)d_in[0];
  const int*   ei    = (const int*)d_in[1];
  const float* gcn_w = (const float*)d_in[2];
  const float* gcn_b = (const float*)d_in[3];
  const float* in_w  = (const float*)d_in[4];
  const float* in_b  = (const float*)d_in[5];
  const float* out_w = (const float*)d_in[6];
  const float* out_b = (const float*)d_in[7];
  const float* ln1_g = (const float*)d_in[8];
  const float* ln1_b = (const float*)d_in[9];
  const float* ff1_w = (const float*)d_in[10];
  const float* ff1_b = (const float*)d_in[11];
  const float* ff2_w = (const float*)d_in[12];
  const float* ff2_b = (const float*)d_in[13];
  const float* ln2_g = (const float*)d_in[14];
  const float* ln2_b = (const float*)d_in[15];
  float* out = (float*)d_out;

  char* w = (char*)d_ws;
  auto alloc = [&](size_t bytes) { char* p = w; w += (bytes + 255) & ~(size_t)255; return p; };
  float* deg  = (float*)alloc((size_t)N * 4);
  float* dinv = (float*)alloc((size_t)N * 4);
  int*   off  = (int*)alloc((size_t)(N + 1) * 4);
  int*   cur  = (int*)alloc((size_t)N * 4);
  int*   srcs = (int*)alloc((size_t)E * 4);
  float* h0   = (float*)alloc((size_t)N * 128 * 4);   // reused as B2
  float* Hb   = (float*)alloc((size_t)N * 128 * 4);
  float* B1   = (float*)alloc((size_t)N * 128 * 4);
  float* Wc   = (float*)alloc(2 * 16384 * 4);
  float* bc   = (float*)alloc(2 * 128 * 4);
  unsigned short* gcnh = (unsigned short*)alloc(16384 * 2);
  unsigned short* gcnl = (unsigned short*)alloc(16384 * 2);
  unsigned short* Wch  = (unsigned short*)alloc(2 * 16384 * 2);
  unsigned short* Wcl  = (unsigned short*)alloc(2 * 16384 * 2);
  unsigned short* ff1h = (unsigned short*)alloc(2 * 262144 * 2);
  unsigned short* ff1l = (unsigned short*)alloc(2 * 262144 * 2);
  unsigned short* ff2h = (unsigned short*)alloc(2 * 262144 * 2);
  float* B2 = h0;

  const int gN = (N + 255) / 256;
  const int gT = (N + 63) / 64;
  const int gV = (int)(((long)N * 32 + 255) / 256);

  // CSR build
  k_fill1<<<gN, 256, 0, stream>>>(deg, N);
  k_edge_deg<<<(E + 255) / 256, 256, 0, stream>>>(ei, deg, E);
  k_rsqrt<<<gN, 256, 0, stream>>>(dinv, deg, N);
  k_scan<<<1, 1024, 0, stream>>>(deg, off, N);
  hipMemcpyAsync(cur, off, (size_t)N * 4, hipMemcpyDeviceToDevice, stream);
  k_scatter<<<(E + 255) / 256, 256, 0, stream>>>(ei, cur, srcs, E);

  // weight prep
  k_combine<<<2, 256, 0, stream>>>(in_w, in_b, out_w, out_b, Wc, bc);
  k_f32bf16_split<<<(16384 + 255) / 256, 256, 0, stream>>>(gcn_w, gcnh, gcnl, 16384);
  k_f32bf16_split<<<(32768 + 255) / 256, 256, 0, stream>>>(Wc, Wch, Wcl, 32768);
  k_f32bf16_split<<<(524288 + 255) / 256, 256, 0, stream>>>(ff1_w, ff1h, ff1l, 524288);
  k_f32bf16<<<(524288 + 255) / 256, 256, 0, stream>>>(ff2_w, ff2h, 524288);

  // GCN
  k_gemm_plain<<<gT, 512, 0, stream>>>(x, gcnh, gcnl, h0, N);
  k_gcn_agg<<<(N + 3) / 4, 256, 0, stream>>>(off, srcs, dinv, h0, gcn_b, Hb, N);

  for (int l = 0; l < 2; ++l) {
    const float* src = (l == 0) ? Hb : B2;
    k_gemm_ln<<<gT, 512, 0, stream>>>(src, Wch + l * 16384, Wcl + l * 16384, bc + l * 128,
                                      ln1_g + l * 128, ln1_b + l * 128, B1, N);
    k_ffn<<<gT, 512, 0, stream>>>(B1, ff1h + l * 262144, ff1l + l * 262144, ff1_b + l * 2048,
                                  ff2h + l * 262144, ff2_b + l * 128,
                                  ln2_g + l * 128, ln2_b + l * 128, B2, N);
  }

  k_final<<<gV, 256, 0, stream>>>(B2, Hb, out, N);
}

// Round 9
// 1289.480 us; speedup vs baseline: 1.0002x; 1.0002x over previous
//
#include <hip/hip_runtime.h>

using short8  = __attribute__((ext_vector_type(8))) short;
using floatx4 = __attribute__((ext_vector_type(4))) float;

__device__ __forceinline__ unsigned short f2bf(float x) {
  unsigned int u = __float_as_uint(x);
  return (unsigned short)((u + 0x7FFFu + ((u >> 16) & 1u)) >> 16);
}
__device__ __forceinline__ float bf2f(unsigned short h) {
  return __uint_as_float(((unsigned int)h) << 16);
}

// ---------------- small elementwise / setup kernels ----------------
__global__ void k_fill1(float* __restrict__ p, int n) {
  int i = blockIdx.x * 256 + threadIdx.x;
  if (i < n) p[i] = 1.0f;
}

__global__ void k_edge_deg(const int* __restrict__ ei, float* __restrict__ deg, int E) {
  int e = blockIdx.x * 256 + threadIdx.x;
  if (e < E) atomicAdd(&deg[ei[E + e]], 1.0f);
}

__global__ void k_rsqrt(float* __restrict__ dinv, const float* __restrict__ deg, int n) {
  int i = blockIdx.x * 256 + threadIdx.x;
  if (i < n) dinv[i] = rsqrtf(deg[i]);
}

__global__ void k_f32bf16(const float* __restrict__ src, unsigned short* __restrict__ dst, int n) {
  int i = blockIdx.x * 256 + threadIdx.x;
  if (i < n) dst[i] = f2bf(src[i]);
}

// hi = bf16(x); lo = bf16(x - hi)
__global__ void k_f32bf16_split(const float* __restrict__ src, unsigned short* __restrict__ hi,
                                unsigned short* __restrict__ lo, int n) {
  int i = blockIdx.x * 256 + threadIdx.x;
  if (i < n) {
    float x = src[i];
    unsigned short h = f2bf(x);
    hi[i] = h;
    lo[i] = f2bf(x - bf2f(h));
  }
}

// ---------------- CSR build: scan + scatter ----------------
__global__ __launch_bounds__(1024) void k_scan(const float* __restrict__ deg,
                                               int* __restrict__ off, int N) {
  __shared__ int wsum[16];
  __shared__ int carry;
  if (threadIdx.x == 0) carry = 0;
  int lane = threadIdx.x & 63, wv = threadIdx.x >> 6;
  for (int base = 0; base < N; base += 1024) {
    int i = base + threadIdx.x;
    int c = (i < N) ? ((int)deg[i] - 1) : 0;
    int s = c;
    #pragma unroll
    for (int o = 1; o < 64; o <<= 1) {
      int t = __shfl_up(s, o);
      if (lane >= o) s += t;
    }
    __syncthreads();
    if (lane == 63) wsum[wv] = s;
    __syncthreads();
    int wpre = 0, total = 0;
    #pragma unroll
    for (int w = 0; w < 16; ++w) {
      int v = wsum[w];
      if (w < wv) wpre += v;
      total += v;
    }
    if (i < N) off[i] = carry + wpre + s - c;
    __syncthreads();
    if (threadIdx.x == 0) carry += total;
  }
  __syncthreads();
  if (threadIdx.x == 0) off[N] = carry;
}

__global__ void k_scatter(const int* __restrict__ ei, int* __restrict__ cur,
                          int* __restrict__ srcs, int E) {
  int e = blockIdx.x * 256 + threadIdx.x;
  if (e < E) {
    int r = ei[e], c = ei[E + e];
    int p = atomicAdd(&cur[c], 1);
    srcs[p] = r;
  }
}

__global__ __launch_bounds__(256) void k_gcn_agg(const int* __restrict__ off,
    const int* __restrict__ srcs, const float* __restrict__ dinv,
    const float* __restrict__ h0, const float* __restrict__ gcn_b,
    float* __restrict__ Hb, int N) {
  int node = blockIdx.x * 4 + (threadIdx.x >> 6);
  if (node >= N) return;
  int c2 = (threadIdx.x & 63) * 2;
  float dc = dinv[node];
  float a0 = 0.f, a1 = 0.f;
  int j = off[node], end = off[node + 1];
  for (; j + 1 < end; j += 2) {
    int s0 = srcs[j], s1 = srcs[j + 1];
    float w0 = dinv[s0] * dc, w1 = dinv[s1] * dc;
    float2 h0v = *(const float2*)&h0[(long)s0 * 128 + c2];
    float2 h1v = *(const float2*)&h0[(long)s1 * 128 + c2];
    a0 += w0 * h0v.x + w1 * h1v.x;
    a1 += w0 * h0v.y + w1 * h1v.y;
  }
  if (j < end) {
    int s0 = srcs[j];
    float w0 = dinv[s0] * dc;
    float2 hv = *(const float2*)&h0[(long)s0 * 128 + c2];
    a0 += w0 * hv.x;
    a1 += w0 * hv.y;
  }
  float2 hv = *(const float2*)&h0[(long)node * 128 + c2];
  float2 b  = *(const float2*)&gcn_b[c2];
  float v0 = a0 + dc * dc * hv.x + b.x;
  float v1 = a1 + dc * dc * hv.y + b.y;
  *(float2*)&Hb[(long)node * 128 + c2] = make_float2(fmaxf(v0, 0.f), fmaxf(v1, 0.f));
}

__global__ void k_final(const float* __restrict__ T, const float* __restrict__ Hb,
                        float* __restrict__ out, int N) {
  long i = (long)blockIdx.x * 256 + threadIdx.x;
  if (i >= (long)N * 32) return;
  long off = i * 4;
  float4 t = *(const float4*)&T[off];
  float4 h = *(const float4*)&Hb[off];
  float4 o;
  o.x = fmaxf(t.x + h.x, 0.f);
  o.y = fmaxf(t.y + h.y, 0.f);
  o.z = fmaxf(t.z + h.z, 0.f);
  o.w = fmaxf(t.w + h.w, 0.f);
  *(float4*)&out[off] = o;
}

// Wc[l] = out_w[l] @ Wv[l]; bc[l] = out_w[l] @ bv[l] + out_b[l]
__global__ void k_combine(const float* __restrict__ in_w, const float* __restrict__ in_b,
                          const float* __restrict__ out_w, const float* __restrict__ out_b,
                          float* __restrict__ Wc, float* __restrict__ bc) {
  __shared__ float Wvs[128][129];
  int l = blockIdx.x;
  const float* Wv = in_w + (long)l * 384 * 128 + 256 * 128;
  const float* bv = in_b + l * 384 + 256;
  const float* Wo = out_w + (long)l * 128 * 128;
  for (int i = threadIdx.x; i < 128 * 128; i += 256)
    Wvs[i >> 7][i & 127] = Wv[i];
  __syncthreads();
  for (int o = threadIdx.x; o < 128 * 128; o += 256) {
    int i = o >> 7, j = o & 127;
    float acc = 0.f;
    for (int k = 0; k < 128; ++k) acc += Wo[i * 128 + k] * Wvs[k][j];
    Wc[(long)l * 16384 + o] = acc;
  }
  if (threadIdx.x < 128) {
    int i = threadIdx.x;
    float acc = out_b[l * 128 + i];
    for (int k = 0; k < 128; ++k) acc += Wo[i * 128 + k] * bv[k];
    bc[l * 128 + i] = acc;
  }
}

// ---------------- round-4 MFMA GEMM helpers (verified) ----------------
__device__ __forceinline__ void stage_xf32_split(unsigned short (*dh)[136], unsigned short (*dl)[136],
                                                 const float* __restrict__ src, long row0, int N) {
  #pragma unroll
  for (int it = 0; it < 2; ++it) {
    int i = it * 512 + threadIdx.x;
    int r = i >> 4, c8 = (i & 15) * 8;
    long gr = row0 + r;
    uint4 wh = make_uint4(0u, 0u, 0u, 0u);
    uint4 wl = make_uint4(0u, 0u, 0u, 0u);
    if (gr < N) {
      const float* p = src + gr * 128 + c8;
      float v[8];
      *(float4*)&v[0] = *(const float4*)p;
      *(float4*)&v[4] = *(const float4*)(p + 4);
      unsigned short h[8], l[8];
      #pragma unroll
      for (int j = 0; j < 8; ++j) {
        h[j] = f2bf(v[j]);
        l[j] = f2bf(v[j] - bf2f(h[j]));
      }
      wh.x = (unsigned)h[0] | ((unsigned)h[1] << 16);
      wh.y = (unsigned)h[2] | ((unsigned)h[3] << 16);
      wh.z = (unsigned)h[4] | ((unsigned)h[5] << 16);
      wh.w = (unsigned)h[6] | ((unsigned)h[7] << 16);
      wl.x = (unsigned)l[0] | ((unsigned)l[1] << 16);
      wl.y = (unsigned)l[2] | ((unsigned)l[3] << 16);
      wl.z = (unsigned)l[4] | ((unsigned)l[5] << 16);
      wl.w = (unsigned)l[6] | ((unsigned)l[7] << 16);
    }
    *(uint4*)&dh[r][c8] = wh;
    *(uint4*)&dl[r][c8] = wl;
  }
}

__device__ __forceinline__ void stage_w(unsigned short (*dst)[136], const unsigned short* __restrict__ src,
                                        int ld) {
  #pragma unroll
  for (int it = 0; it < 4; ++it) {
    int i = it * 512 + threadIdx.x;
    int r = i >> 4, c8 = (i & 15) * 8;
    *(uint4*)&dst[r][c8] = *(const uint4*)&src[(long)r * ld + c8];
  }
}

__device__ __forceinline__ void mfma_64x128_3(const unsigned short (*Ah)[136], const unsigned short (*Al)[136],
                                              const unsigned short (*Bh)[136], const unsigned short (*Bl)[136],
                                              floatx4 acc[2][2]) {
  int lane = threadIdx.x & 63;
  int wave = threadIdx.x >> 6;
  int wr = (wave >> 2) * 32;
  int wc = (wave & 3) * 32;
  int r16 = lane & 15;
  int k8 = (lane >> 4) * 8;
  #pragma unroll
  for (int ks = 0; ks < 4; ++ks) {
    int k0 = ks * 32 + k8;
    short8 a0h = *(const short8*)&Ah[wr + r16][k0];
    short8 a1h = *(const short8*)&Ah[wr + 16 + r16][k0];
    short8 a0l = *(const short8*)&Al[wr + r16][k0];
    short8 a1l = *(const short8*)&Al[wr + 16 + r16][k0];
    short8 b0h = *(const short8*)&Bh[wc + r16][k0];
    short8 b1h = *(const short8*)&Bh[wc + 16 + r16][k0];
    short8 b0l = *(const short8*)&Bl[wc + r16][k0];
    short8 b1l = *(const short8*)&Bl[wc + 16 + r16][k0];
    acc[0][0] = __builtin_amdgcn_mfma_f32_16x16x32_bf16(a0h, b0h, acc[0][0], 0, 0, 0);
    acc[0][0] = __builtin_amdgcn_mfma_f32_16x16x32_bf16(a0h, b0l, acc[0][0], 0, 0, 0);
    acc[0][0] = __builtin_amdgcn_mfma_f32_16x16x32_bf16(a0l, b0h, acc[0][0], 0, 0, 0);
    acc[0][1] = __builtin_amdgcn_mfma_f32_16x16x32_bf16(a0h, b1h, acc[0][1], 0, 0, 0);
    acc[0][1] = __builtin_amdgcn_mfma_f32_16x16x32_bf16(a0h, b1l, acc[0][1], 0, 0, 0);
    acc[0][1] = __builtin_amdgcn_mfma_f32_16x16x32_bf16(a0l, b1h, acc[0][1], 0, 0, 0);
    acc[1][0] = __builtin_amdgcn_mfma_f32_16x16x32_bf16(a1h, b0h, acc[1][0], 0, 0, 0);
    acc[1][0] = __builtin_amdgcn_mfma_f32_16x16x32_bf16(a1h, b0l, acc[1][0], 0, 0, 0);
    acc[1][0] = __builtin_amdgcn_mfma_f32_16x16x32_bf16(a1l, b0h, acc[1][0], 0, 0, 0);
    acc[1][1] = __builtin_amdgcn_mfma_f32_16x16x32_bf16(a1h, b1h, acc[1][1], 0, 0, 0);
    acc[1][1] = __builtin_amdgcn_mfma_f32_16x16x32_bf16(a1h, b1l, acc[1][1], 0, 0, 0);
    acc[1][1] = __builtin_amdgcn_mfma_f32_16x16x32_bf16(a1l, b1h, acc[1][1], 0, 0, 0);
  }
}

__device__ __forceinline__ void frag_to_ys(float (*Ys)[132], const floatx4 acc[2][2]) {
  int lane = threadIdx.x & 63;
  int wave = threadIdx.x >> 6;
  int row0 = (wave >> 2) * 32 + (lane >> 4) * 4;
  int col0 = (wave & 3) * 32 + (lane & 15);
  #pragma unroll
  for (int mi = 0; mi < 2; ++mi)
    #pragma unroll
    for (int ni = 0; ni < 2; ++ni)
      #pragma unroll
      for (int r = 0; r < 4; ++r)
        Ys[row0 + mi * 16 + r][col0 + ni * 16] = acc[mi][ni][r];
}

__device__ __forceinline__ void ln_store(const float (*Ys)[132],
    const float* __restrict__ bias, const float* __restrict__ res,
    const float* __restrict__ g, const float* __restrict__ bl,
    float* __restrict__ Y, long row0, int N) {
  int r = threadIdx.x >> 3;
  int seg = (threadIdx.x & 7) * 16;
  long gr = row0 + r;
  float y[16];
  float s = 0.f, s2 = 0.f;
  if (gr < N) {
    #pragma unroll
    for (int q = 0; q < 4; ++q) {
      float4 v  = *(const float4*)&Ys[r][seg + q * 4];
      float4 b4 = *(const float4*)&bias[seg + q * 4];
      float4 rv = *(const float4*)&res[gr * 128 + seg + q * 4];
      float t0 = v.x + b4.x + rv.x;
      float t1 = v.y + b4.y + rv.y;
      float t2 = v.z + b4.z + rv.z;
      float t3 = v.w + b4.w + rv.w;
      y[q*4+0] = t0; y[q*4+1] = t1; y[q*4+2] = t2; y[q*4+3] = t3;
      s  += t0 + t1 + t2 + t3;
      s2 += t0*t0 + t1*t1 + t2*t2 + t3*t3;
    }
  } else {
    #pragma unroll
    for (int q = 0; q < 16; ++q) y[q] = 0.f;
  }
  #pragma unroll
  for (int off = 1; off < 8; off <<= 1) {
    s  += __shfl_xor(s, off);
    s2 += __shfl_xor(s2, off);
  }
  float m   = s * (1.f / 128.f);
  float var = s2 * (1.f / 128.f) - m * m;
  float inv = rsqrtf(var + 1e-5f);
  if (gr < N) {
    #pragma unroll
    for (int q = 0; q < 4; ++q) {
      float4 g4 = *(const float4*)&g[seg + q * 4];
      float4 b4 = *(const float4*)&bl[seg + q * 4];
      float4 o;
      o.x = (y[q*4+0] - m) * inv * g4.x + b4.x;
      o.y = (y[q*4+1] - m) * inv * g4.y + b4.y;
      o.z = (y[q*4+2] - m) * inv * g4.z + b4.z;
      o.w = (y[q*4+3] - m) * inv * g4.w + b4.w;
      *(float4*)&Y[gr * 128 + seg + q * 4] = o;
    }
  }
}

// ---------------- packed-fragment helpers for k_ffn ----------------
// slot(row,ks,g) = (((row>>4)*4 + ks)*4 + g)*16 + (row&15),  k = ks*32 + g*8
template<bool LO>
__device__ __forceinline__ void stage_x_packed(uint4* __restrict__ dst,
    const float* __restrict__ src, long row0, int N) {
  #pragma unroll
  for (int it = 0; it < 2; ++it) {
    int s = it * 512 + threadIdx.x;
    int r16 = s & 15, g = (s >> 4) & 3, ks = (s >> 6) & 3, rb = s >> 8;
    long gr = row0 + rb * 16 + r16;
    uint4 w = make_uint4(0u, 0u, 0u, 0u);
    if (gr < N) {
      const float* p = src + gr * 128 + ks * 32 + g * 8;
      float v[8];
      *(float4*)&v[0] = *(const float4*)p;
      *(float4*)&v[4] = *(const float4*)(p + 4);
      unsigned q[8];
      #pragma unroll
      for (int j = 0; j < 8; ++j) {
        unsigned short h = f2bf(v[j]);
        q[j] = LO ? (unsigned)f2bf(v[j] - bf2f(h)) : (unsigned)h;
      }
      w.x = q[0] | (q[1] << 16);
      w.y = q[2] | (q[3] << 16);
      w.z = q[4] | (q[5] << 16);
      w.w = q[6] | (q[7] << 16);
    }
    dst[s] = w;
  }
}

__device__ __forceinline__ void load_afrags(short8 af[2][4], const uint4* __restrict__ Xp, int wr) {
  int lane = threadIdx.x & 63;
  #pragma unroll
  for (int mi = 0; mi < 2; ++mi)
    #pragma unroll
    for (int ks = 0; ks < 4; ++ks)
      af[mi][ks] = *(const short8*)&Xp[((wr >> 4) + mi) * 256 + ks * 64 + lane];
}

// W staging split into load(global->regs) / write(regs->LDS), packed layout
__device__ __forceinline__ void stage_load(uint4 st[4], const unsigned short* __restrict__ src,
                                           long ld) {
  #pragma unroll
  for (int it = 0; it < 4; ++it) {
    int s = it * 512 + threadIdx.x;
    int n16 = s & 15, g = (s >> 4) & 3, ks = (s >> 6) & 3, nb = s >> 8;
    st[it] = *(const uint4*)&src[(long)(nb * 16 + n16) * ld + ks * 32 + g * 8];
  }
}

__device__ __forceinline__ void stage_write(uint4* __restrict__ dst, const uint4 st[4]) {
  #pragma unroll
  for (int it = 0; it < 4; ++it) dst[it * 512 + threadIdx.x] = st[it];
}

#define MF(a, b, c) __builtin_amdgcn_mfma_f32_16x16x32_bf16(a, b, c, 0, 0, 0)

// ---------------- big kernels ----------------
// round-4 exact: split-bf16 GEMM, plain store
__global__ __launch_bounds__(512) void k_gemm_plain(const float* __restrict__ X,
    const unsigned short* __restrict__ Wh, const unsigned short* __restrict__ Wl,
    float* __restrict__ Y, int N) {
  __shared__ __align__(16) unsigned short XsH[64][136];
  __shared__ __align__(16) unsigned short XsL[64][136];
  __shared__ __align__(16) unsigned short WsH[128][136];
  __shared__ __align__(16) unsigned short WsL[128][136];
  long row0 = (long)blockIdx.x * 64;
  stage_xf32_split(XsH, XsL, X, row0, N);
  stage_w(WsH, Wh, 128);
  stage_w(WsL, Wl, 128);
  __syncthreads();
  floatx4 zero = {0.f, 0.f, 0.f, 0.f};
  floatx4 acc[2][2] = {{zero, zero}, {zero, zero}};
  mfma_64x128_3(XsH, XsL, WsH, WsL, acc);
  int lane = threadIdx.x & 63;
  int wave = threadIdx.x >> 6;
  int rowb = (wave >> 2) * 32 + (lane >> 4) * 4;
  int colb = (wave & 3) * 32 + (lane & 15);
  #pragma unroll
  for (int mi = 0; mi < 2; ++mi)
    #pragma unroll
    for (int ni = 0; ni < 2; ++ni)
      #pragma unroll
      for (int r = 0; r < 4; ++r) {
        long gr = row0 + rowb + mi * 16 + r;
        if (gr < N) Y[gr * 128 + colb + ni * 16] = acc[mi][ni][r];
      }
}

// round-4 exact: split-bf16 GEMM + residual + LN epilogue
__global__ __launch_bounds__(512) void k_gemm_ln(const float* __restrict__ X,
    const unsigned short* __restrict__ Wh, const unsigned short* __restrict__ Wl,
    const float* __restrict__ bias,
    const float* __restrict__ g, const float* __restrict__ bl,
    float* __restrict__ Y, int N) {
  __shared__ __align__(16) unsigned short XsH[64][136];
  __shared__ __align__(16) unsigned short XsL[64][136];
  __shared__ union __align__(16) WY {
    struct { unsigned short h[128][136]; unsigned short l[128][136]; } w;
    float ys[64][132];
  } wy;
  long row0 = (long)blockIdx.x * 64;
  stage_xf32_split(XsH, XsL, X, row0, N);
  stage_w(wy.w.h, Wh, 128);
  stage_w(wy.w.l, Wl, 128);
  __syncthreads();
  floatx4 zero = {0.f, 0.f, 0.f, 0.f};
  floatx4 acc[2][2] = {{zero, zero}, {zero, zero}};
  mfma_64x128_3(XsH, XsL, wy.w.h, wy.w.l, acc);
  __syncthreads();
  frag_to_ys(wy.ys, acc);
  __syncthreads();
  ln_store(wy.ys, bias, X, g, bl, Y, row0, N);
}

// k_ffn v3: round-4 numerics (X split + W1 split, single Z@W2).
// X frags in regs (r7-verified), Z packed LDS (r7-verified),
// W1h/W1l/W2 staged to LDS in packed layout with async load/write split.
// LDS = 64K(w1, ys overlay) + 32K(w2) + 16K(z) = 112KB.
__global__ __launch_bounds__(512) void k_ffn(const float* __restrict__ T1,
    const unsigned short* __restrict__ W1h, const unsigned short* __restrict__ W1l,
    const float* __restrict__ b1,
    const unsigned short* __restrict__ W2b, const float* __restrict__ b2,
    const float* __restrict__ gam, const float* __restrict__ bet,
    float* __restrict__ Y, int N) {
  __shared__ union __align__(16) U1 {
    struct { uint4 h[2048]; uint4 l[2048]; } w1;
    float ys[64][132];
  } u1;
  __shared__ __align__(16) uint4 w2s[2048];
  __shared__ __align__(16) uint4 zx[1024];
  long row0 = (long)blockIdx.x * 64;
  int lane = threadIdx.x & 63;
  int wave = threadIdx.x >> 6;
  int wr = (wave >> 2) * 32, wc = (wave & 3) * 32;
  int gq = lane >> 4, r16c = lane & 15;

  // issue chunk-0 W loads early (latency hides under X staging)
  uint4 s1h[4], s1l[4], s2[4];
  stage_load(s1h, W1h, 128);
  stage_load(s1l, W1l, 128);
  stage_load(s2,  W2b, 2048);

  // X hi+lo fragments -> registers (r7-verified pattern)
  stage_x_packed<false>(zx, T1, row0, N);
  __syncthreads();
  short8 afh[2][4], afl[2][4];
  load_afrags(afh, zx, wr);
  __syncthreads();
  stage_x_packed<true>(zx, T1, row0, N);
  __syncthreads();
  load_afrags(afl, zx, wr);
  // write chunk-0 W to LDS
  stage_write(u1.w1.h, s1h);
  stage_write(u1.w1.l, s1l);
  stage_write(w2s, s2);
  __syncthreads();                         // afl reads done; W visible; zx -> Z buffer

  unsigned short* Zu = (unsigned short*)zx;
  int zb0 = (((wr >> 4) + 0) * 4 + (wc >> 5)) * 4 + (r16c >> 3);
  int zb1 = (((wr >> 4) + 1) * 4 + (wc >> 5)) * 4 + (r16c >> 3);

  floatx4 zero = {0.f, 0.f, 0.f, 0.f};
  floatx4 acc2[2][2] = {{zero, zero}, {zero, zero}};

  for (int fc = 0; fc < 16; ++fc) {
    // prefetch next chunk's W into registers (off critical path)
    if (fc < 15) {
      stage_load(s1h, W1h + (long)(fc + 1) * 16384, 128);
      stage_load(s1l, W1l + (long)(fc + 1) * 16384, 128);
      stage_load(s2,  W2b + (fc + 1) * 128, 2048);
    }
    // phase A: Zc = relu(X @ W1c^T + b1c)   (X regs, W1 LDS packed, split 3-product)
    floatx4 acc1[2][2] = {{zero, zero}, {zero, zero}};
    int nbb = (wc >> 4) * 256;
    #pragma unroll
    for (int ks = 0; ks < 4; ++ks) {
      int nb = nbb + ks * 64 + lane;
      short8 bh0 = *(const short8*)&u1.w1.h[nb];
      short8 bh1 = *(const short8*)&u1.w1.h[nb + 256];
      short8 bl0 = *(const short8*)&u1.w1.l[nb];
      short8 bl1 = *(const short8*)&u1.w1.l[nb + 256];
      acc1[0][0] = MF(afh[0][ks], bh0, acc1[0][0]);
      acc1[0][0] = MF(afh[0][ks], bl0, acc1[0][0]);
      acc1[0][0] = MF(afl[0][ks], bh0, acc1[0][0]);
      acc1[0][1] = MF(afh[0][ks], bh1, acc1[0][1]);
      acc1[0][1] = MF(afh[0][ks], bl1, acc1[0][1]);
      acc1[0][1] = MF(afl[0][ks], bh1, acc1[0][1]);
      acc1[1][0] = MF(afh[1][ks], bh0, acc1[1][0]);
      acc1[1][0] = MF(afh[1][ks], bl0, acc1[1][0]);
      acc1[1][0] = MF(afl[1][ks], bh0, acc1[1][0]);
      acc1[1][1] = MF(afh[1][ks], bh1, acc1[1][1]);
      acc1[1][1] = MF(afh[1][ks], bl1, acc1[1][1]);
      acc1[1][1] = MF(afl[1][ks], bh1, acc1[1][1]);
    }
    float bv0 = b1[fc * 128 + wc + r16c];
    float bv1 = b1[fc * 128 + wc + 16 + r16c];
    #pragma unroll
    for (int mi = 0; mi < 2; ++mi) {
      int zb = mi ? zb1 : zb0;
      #pragma unroll
      for (int ni = 0; ni < 2; ++ni) {
        float bv = ni ? bv1 : bv0;
        #pragma unroll
        for (int r = 0; r < 4; ++r) {
          float z = fmaxf(acc1[mi][ni][r] + bv, 0.f);
          Zu[(zb + 2 * ni) * 128 + (4 * gq + r) * 8 + (r16c & 7)] = f2bf(z);
        }
      }
    }
    __syncthreads();                       // Z visible; w1 reads done
    // phase B: acc2 += Zc @ W2c^T  (single bf16)
    #pragma unroll
    for (int ks = 0; ks < 4; ++ks) {
      int za = (wr >> 4) * 256 + ks * 64 + lane;
      short8 a0 = *(const short8*)&zx[za];
      short8 a1 = *(const short8*)&zx[za + 256];
      int nb = nbb + ks * 64 + lane;
      short8 b0  = *(const short8*)&w2s[nb];
      short8 b1f = *(const short8*)&w2s[nb + 256];
      acc2[0][0] = MF(a0, b0,  acc2[0][0]);
      acc2[0][1] = MF(a0, b1f, acc2[0][1]);
      acc2[1][0] = MF(a1, b0,  acc2[1][0]);
      acc2[1][1] = MF(a1, b1f, acc2[1][1]);
    }
    __syncthreads();                       // all chunk-fc LDS reads done
    if (fc < 15) {
      stage_write(u1.w1.h, s1h);
      stage_write(u1.w1.l, s1l);
      stage_write(w2s, s2);
    }
    __syncthreads();                       // next-chunk W visible (and Z writable)
  }
  frag_to_ys(u1.ys, acc2);
  __syncthreads();
  ln_store(u1.ys, b2, T1, gam, bet, Y, row0, N);
}

// ---------------- launcher ----------------
extern "C" void kernel_launch(void* const* d_in, const int* in_sizes, int n_in,
                              void* d_out, int out_size, void* d_ws, size_t ws_size,
                              hipStream_t stream) {
  const int N = in_sizes[0] / 128;
  const int E = in_sizes[1] / 2;
  const float* x     = (const float*)d_in[0];
  const int*   ei    = (const int*)d_in[1];
  const float* gcn_w = (const float*)d_in[2];
  const float* gcn_b = (const float*)d_in[3];
  const float* in_w  = (const float*)d_in[4];
  const float* in_b  = (const float*)d_in[5];
  const float* out_w = (const float*)d_in[6];
  const float* out_b = (const float*)d_in[7];
  const float* ln1_g = (const float*)d_in[8];
  const float* ln1_b = (const float*)d_in[9];
  const float* ff1_w = (const float*)d_in[10];
  const float* ff1_b = (const float*)d_in[11];
  const float* ff2_w = (const float*)d_in[12];
  const float* ff2_b = (const float*)d_in[13];
  const float* ln2_g = (const float*)d_in[14];
  const float* ln2_b = (const float*)d_in[15];
  float* out = (float*)d_out;

  char* w = (char*)d_ws;
  auto alloc = [&](size_t bytes) { char* p = w; w += (bytes + 255) & ~(size_t)255; return p; };
  float* deg  = (float*)alloc((size_t)N * 4);
  float* dinv = (float*)alloc((size_t)N * 4);
  int*   off  = (int*)alloc((size_t)(N + 1) * 4);
  int*   cur  = (int*)alloc((size_t)N * 4);
  int*   srcs = (int*)alloc((size_t)E * 4);
  float* h0   = (float*)alloc((size_t)N * 128 * 4);   // reused as B2
  float* Hb   = (float*)alloc((size_t)N * 128 * 4);
  float* B1   = (float*)alloc((size_t)N * 128 * 4);
  float* Wc   = (float*)alloc(2 * 16384 * 4);
  float* bc   = (float*)alloc(2 * 128 * 4);
  unsigned short* gcnh = (unsigned short*)alloc(16384 * 2);
  unsigned short* gcnl = (unsigned short*)alloc(16384 * 2);
  unsigned short* Wch  = (unsigned short*)alloc(2 * 16384 * 2);
  unsigned short* Wcl  = (unsigned short*)alloc(2 * 16384 * 2);
  unsigned short* ff1h = (unsigned short*)alloc(2 * 262144 * 2);
  unsigned short* ff1l = (unsigned short*)alloc(2 * 262144 * 2);
  unsigned short* ff2h = (unsigned short*)alloc(2 * 262144 * 2);
  float* B2 = h0;

  const int gN = (N + 255) / 256;
  const int gT = (N + 63) / 64;
  const int gV = (int)(((long)N * 32 + 255) / 256);

  // CSR build
  k_fill1<<<gN, 256, 0, stream>>>(deg, N);
  k_edge_deg<<<(E + 255) / 256, 256, 0, stream>>>(ei, deg, E);
  k_rsqrt<<<gN, 256, 0, stream>>>(dinv, deg, N);
  k_scan<<<1, 1024, 0, stream>>>(deg, off, N);
  hipMemcpyAsync(cur, off, (size_t)N * 4, hipMemcpyDeviceToDevice, stream);
  k_scatter<<<(E + 255) / 256, 256, 0, stream>>>(ei, cur, srcs, E);

  // weight prep
  k_combine<<<2, 256, 0, stream>>>(in_w, in_b, out_w, out_b, Wc, bc);
  k_f32bf16_split<<<(16384 + 255) / 256, 256, 0, stream>>>(gcn_w, gcnh, gcnl, 16384);
  k_f32bf16_split<<<(32768 + 255) / 256, 256, 0, stream>>>(Wc, Wch, Wcl, 32768);
  k_f32bf16_split<<<(524288 + 255) / 256, 256, 0, stream>>>(ff1_w, ff1h, ff1l, 524288);
  k_f32bf16<<<(524288 + 255) / 256, 256, 0, stream>>>(ff2_w, ff2h, 524288);

  // GCN
  k_gemm_plain<<<gT, 512, 0, stream>>>(x, gcnh, gcnl, h0, N);
  k_gcn_agg<<<(N + 3) / 4, 256, 0, stream>>>(off, srcs, dinv, h0, gcn_b, Hb, N);

  for (int l = 0; l < 2; ++l) {
    const float* src = (l == 0) ? Hb : B2;
    k_gemm_ln<<<gT, 512, 0, stream>>>(src, Wch + l * 16384, Wcl + l * 16384, bc + l * 128,
                                      ln1_g + l * 128, ln1_b + l * 128, B1, N);
    k_ffn<<<gT, 512, 0, stream>>>(B1, ff1h + l * 262144, ff1l + l * 262144, ff1_b + l * 2048,
                                  ff2h + l * 262144, ff2_b + l * 128,
                                  ln2_g + l * 128, ln2_b + l * 128, B2, N);
  }

  k_final<<<gV, 256, 0, stream>>>(B2, Hb, out, N);
}

// Round 10
// 837.317 us; speedup vs baseline: 1.5404x; 1.5400x over previous
//
#include <hip/hip_runtime.h>

using short8  = __attribute__((ext_vector_type(8))) short;
using floatx4 = __attribute__((ext_vector_type(4))) float;

__device__ __forceinline__ unsigned short f2bf(float x) {
  unsigned int u = __float_as_uint(x);
  return (unsigned short)((u + 0x7FFFu + ((u >> 16) & 1u)) >> 16);
}
__device__ __forceinline__ float bf2f(unsigned short h) {
  return __uint_as_float(((unsigned int)h) << 16);
}

// ---------------- small elementwise / setup kernels ----------------
__global__ void k_fill1(float* __restrict__ p, int n) {
  int i = blockIdx.x * 256 + threadIdx.x;
  if (i < n) p[i] = 1.0f;
}

__global__ void k_edge_deg(const int* __restrict__ ei, float* __restrict__ deg, int E) {
  int e = blockIdx.x * 256 + threadIdx.x;
  if (e < E) atomicAdd(&deg[ei[E + e]], 1.0f);
}

__global__ void k_rsqrt(float* __restrict__ dinv, const float* __restrict__ deg, int n) {
  int i = blockIdx.x * 256 + threadIdx.x;
  if (i < n) dinv[i] = rsqrtf(deg[i]);
}

// hi = bf16(x); lo = bf16(x - hi)
__global__ void k_f32bf16_split(const float* __restrict__ src, unsigned short* __restrict__ hi,
                                unsigned short* __restrict__ lo, int n) {
  int i = blockIdx.x * 256 + threadIdx.x;
  if (i < n) {
    float x = src[i];
    unsigned short h = f2bf(x);
    hi[i] = h;
    lo[i] = f2bf(x - bf2f(h));
  }
}

// ---------------- packed-fragment weight prep (global fragment order) ----------------
// slot within 128x128 chunk: rem = c16*256 + ks*64 + g*16 + r16  (uint4 slots, 8 bf16 each)
//   covers out-feature = c16*16 + r16, k = ks*32 + g*8
// k_pack_rows: W[OUT][128], chunks along OUT (W1: OUT=2048)
__global__ void k_pack_rows(const float* __restrict__ W, unsigned short* __restrict__ hi,
                            unsigned short* __restrict__ lo, int nslots) {
  int s = blockIdx.x * 256 + threadIdx.x;
  if (s >= nslots) return;
  int chunk = s >> 11, rem = s & 2047;
  int c16 = rem >> 8, ks = (rem >> 6) & 3, g = (rem >> 4) & 3, r16 = rem & 15;
  int out = chunk * 128 + c16 * 16 + r16;
  int k   = ks * 32 + g * 8;
  const float* p = W + (long)out * 128 + k;
  float v[8];
  *(float4*)&v[0] = *(const float4*)p;
  *(float4*)&v[4] = *(const float4*)(p + 4);
  unsigned h[8], l[8];
  #pragma unroll
  for (int j = 0; j < 8; ++j) {
    unsigned short hh = f2bf(v[j]);
    h[j] = hh;
    l[j] = f2bf(v[j] - bf2f(hh));
  }
  uint4 wh = make_uint4(h[0] | (h[1] << 16), h[2] | (h[3] << 16),
                        h[4] | (h[5] << 16), h[6] | (h[7] << 16));
  *(uint4*)&hi[(long)s * 8] = wh;
  if (lo) {
    uint4 wl = make_uint4(l[0] | (l[1] << 16), l[2] | (l[3] << 16),
                          l[4] | (l[5] << 16), l[6] | (l[7] << 16));
    *(uint4*)&lo[(long)s * 8] = wl;
  }
}

// k_pack_cols: W[128][K], chunks along K (W2: K=2048), hi only
__global__ void k_pack_cols(const float* __restrict__ W, unsigned short* __restrict__ hi,
                            int K, int nslots) {
  int s = blockIdx.x * 256 + threadIdx.x;
  if (s >= nslots) return;
  int chunk = s >> 11, rem = s & 2047;
  int c16 = rem >> 8, ks = (rem >> 6) & 3, g = (rem >> 4) & 3, r16 = rem & 15;
  int out = c16 * 16 + r16;
  int k   = chunk * 128 + ks * 32 + g * 8;
  const float* p = W + (long)out * K + k;
  float v[8];
  *(float4*)&v[0] = *(const float4*)p;
  *(float4*)&v[4] = *(const float4*)(p + 4);
  unsigned h[8];
  #pragma unroll
  for (int j = 0; j < 8; ++j) h[j] = f2bf(v[j]);
  uint4 wh = make_uint4(h[0] | (h[1] << 16), h[2] | (h[3] << 16),
                        h[4] | (h[5] << 16), h[6] | (h[7] << 16));
  *(uint4*)&hi[(long)s * 8] = wh;
}

// ---------------- CSR build: scan + scatter ----------------
__global__ __launch_bounds__(1024) void k_scan(const float* __restrict__ deg,
                                               int* __restrict__ off, int N) {
  __shared__ int wsum[16];
  __shared__ int carry;
  if (threadIdx.x == 0) carry = 0;
  int lane = threadIdx.x & 63, wv = threadIdx.x >> 6;
  for (int base = 0; base < N; base += 1024) {
    int i = base + threadIdx.x;
    int c = (i < N) ? ((int)deg[i] - 1) : 0;
    int s = c;
    #pragma unroll
    for (int o = 1; o < 64; o <<= 1) {
      int t = __shfl_up(s, o);
      if (lane >= o) s += t;
    }
    __syncthreads();
    if (lane == 63) wsum[wv] = s;
    __syncthreads();
    int wpre = 0, total = 0;
    #pragma unroll
    for (int w = 0; w < 16; ++w) {
      int v = wsum[w];
      if (w < wv) wpre += v;
      total += v;
    }
    if (i < N) off[i] = carry + wpre + s - c;
    __syncthreads();
    if (threadIdx.x == 0) carry += total;
  }
  __syncthreads();
  if (threadIdx.x == 0) off[N] = carry;
}

__global__ void k_scatter(const int* __restrict__ ei, int* __restrict__ cur,
                          int* __restrict__ srcs, int E) {
  int e = blockIdx.x * 256 + threadIdx.x;
  if (e < E) {
    int r = ei[e], c = ei[E + e];
    int p = atomicAdd(&cur[c], 1);
    srcs[p] = r;
  }
}

__global__ __launch_bounds__(256) void k_gcn_agg(const int* __restrict__ off,
    const int* __restrict__ srcs, const float* __restrict__ dinv,
    const float* __restrict__ h0, const float* __restrict__ gcn_b,
    float* __restrict__ Hb, int N) {
  int node = blockIdx.x * 4 + (threadIdx.x >> 6);
  if (node >= N) return;
  int c2 = (threadIdx.x & 63) * 2;
  float dc = dinv[node];
  float a0 = 0.f, a1 = 0.f;
  int j = off[node], end = off[node + 1];
  for (; j + 1 < end; j += 2) {
    int s0 = srcs[j], s1 = srcs[j + 1];
    float w0 = dinv[s0] * dc, w1 = dinv[s1] * dc;
    float2 h0v = *(const float2*)&h0[(long)s0 * 128 + c2];
    float2 h1v = *(const float2*)&h0[(long)s1 * 128 + c2];
    a0 += w0 * h0v.x + w1 * h1v.x;
    a1 += w0 * h0v.y + w1 * h1v.y;
  }
  if (j < end) {
    int s0 = srcs[j];
    float w0 = dinv[s0] * dc;
    float2 hv = *(const float2*)&h0[(long)s0 * 128 + c2];
    a0 += w0 * hv.x;
    a1 += w0 * hv.y;
  }
  float2 hv = *(const float2*)&h0[(long)node * 128 + c2];
  float2 b  = *(const float2*)&gcn_b[c2];
  float v0 = a0 + dc * dc * hv.x + b.x;
  float v1 = a1 + dc * dc * hv.y + b.y;
  *(float2*)&Hb[(long)node * 128 + c2] = make_float2(fmaxf(v0, 0.f), fmaxf(v1, 0.f));
}

__global__ void k_final(const float* __restrict__ T, const float* __restrict__ Hb,
                        float* __restrict__ out, int N) {
  long i = (long)blockIdx.x * 256 + threadIdx.x;
  if (i >= (long)N * 32) return;
  long off = i * 4;
  float4 t = *(const float4*)&T[off];
  float4 h = *(const float4*)&Hb[off];
  float4 o;
  o.x = fmaxf(t.x + h.x, 0.f);
  o.y = fmaxf(t.y + h.y, 0.f);
  o.z = fmaxf(t.z + h.z, 0.f);
  o.w = fmaxf(t.w + h.w, 0.f);
  *(float4*)&out[off] = o;
}

// Wc[l] = out_w[l] @ Wv[l]; bc[l] = out_w[l] @ bv[l] + out_b[l]
__global__ void k_combine(const float* __restrict__ in_w, const float* __restrict__ in_b,
                          const float* __restrict__ out_w, const float* __restrict__ out_b,
                          float* __restrict__ Wc, float* __restrict__ bc) {
  __shared__ float Wvs[128][129];
  int l = blockIdx.x;
  const float* Wv = in_w + (long)l * 384 * 128 + 256 * 128;
  const float* bv = in_b + l * 384 + 256;
  const float* Wo = out_w + (long)l * 128 * 128;
  for (int i = threadIdx.x; i < 128 * 128; i += 256)
    Wvs[i >> 7][i & 127] = Wv[i];
  __syncthreads();
  for (int o = threadIdx.x; o < 128 * 128; o += 256) {
    int i = o >> 7, j = o & 127;
    float acc = 0.f;
    for (int k = 0; k < 128; ++k) acc += Wo[i * 128 + k] * Wvs[k][j];
    Wc[(long)l * 16384 + o] = acc;
  }
  if (threadIdx.x < 128) {
    int i = threadIdx.x;
    float acc = out_b[l * 128 + i];
    for (int k = 0; k < 128; ++k) acc += Wo[i * 128 + k] * bv[k];
    bc[l * 128 + i] = acc;
  }
}

// ---------------- round-4 MFMA GEMM helpers (verified) ----------------
__device__ __forceinline__ void stage_xf32_split(unsigned short (*dh)[136], unsigned short (*dl)[136],
                                                 const float* __restrict__ src, long row0, int N) {
  #pragma unroll
  for (int it = 0; it < 2; ++it) {
    int i = it * 512 + threadIdx.x;
    int r = i >> 4, c8 = (i & 15) * 8;
    long gr = row0 + r;
    uint4 wh = make_uint4(0u, 0u, 0u, 0u);
    uint4 wl = make_uint4(0u, 0u, 0u, 0u);
    if (gr < N) {
      const float* p = src + gr * 128 + c8;
      float v[8];
      *(float4*)&v[0] = *(const float4*)p;
      *(float4*)&v[4] = *(const float4*)(p + 4);
      unsigned short h[8], l[8];
      #pragma unroll
      for (int j = 0; j < 8; ++j) {
        h[j] = f2bf(v[j]);
        l[j] = f2bf(v[j] - bf2f(h[j]));
      }
      wh.x = (unsigned)h[0] | ((unsigned)h[1] << 16);
      wh.y = (unsigned)h[2] | ((unsigned)h[3] << 16);
      wh.z = (unsigned)h[4] | ((unsigned)h[5] << 16);
      wh.w = (unsigned)h[6] | ((unsigned)h[7] << 16);
      wl.x = (unsigned)l[0] | ((unsigned)l[1] << 16);
      wl.y = (unsigned)l[2] | ((unsigned)l[3] << 16);
      wl.z = (unsigned)l[4] | ((unsigned)l[5] << 16);
      wl.w = (unsigned)l[6] | ((unsigned)l[7] << 16);
    }
    *(uint4*)&dh[r][c8] = wh;
    *(uint4*)&dl[r][c8] = wl;
  }
}

__device__ __forceinline__ void stage_w(unsigned short (*dst)[136], const unsigned short* __restrict__ src,
                                        int ld) {
  #pragma unroll
  for (int it = 0; it < 4; ++it) {
    int i = it * 512 + threadIdx.x;
    int r = i >> 4, c8 = (i & 15) * 8;
    *(uint4*)&dst[r][c8] = *(const uint4*)&src[(long)r * ld + c8];
  }
}

__device__ __forceinline__ void mfma_64x128_3(const unsigned short (*Ah)[136], const unsigned short (*Al)[136],
                                              const unsigned short (*Bh)[136], const unsigned short (*Bl)[136],
                                              floatx4 acc[2][2]) {
  int lane = threadIdx.x & 63;
  int wave = threadIdx.x >> 6;
  int wr = (wave >> 2) * 32;
  int wc = (wave & 3) * 32;
  int r16 = lane & 15;
  int k8 = (lane >> 4) * 8;
  #pragma unroll
  for (int ks = 0; ks < 4; ++ks) {
    int k0 = ks * 32 + k8;
    short8 a0h = *(const short8*)&Ah[wr + r16][k0];
    short8 a1h = *(const short8*)&Ah[wr + 16 + r16][k0];
    short8 a0l = *(const short8*)&Al[wr + r16][k0];
    short8 a1l = *(const short8*)&Al[wr + 16 + r16][k0];
    short8 b0h = *(const short8*)&Bh[wc + r16][k0];
    short8 b1h = *(const short8*)&Bh[wc + 16 + r16][k0];
    short8 b0l = *(const short8*)&Bl[wc + r16][k0];
    short8 b1l = *(const short8*)&Bl[wc + 16 + r16][k0];
    acc[0][0] = __builtin_amdgcn_mfma_f32_16x16x32_bf16(a0h, b0h, acc[0][0], 0, 0, 0);
    acc[0][0] = __builtin_amdgcn_mfma_f32_16x16x32_bf16(a0h, b0l, acc[0][0], 0, 0, 0);
    acc[0][0] = __builtin_amdgcn_mfma_f32_16x16x32_bf16(a0l, b0h, acc[0][0], 0, 0, 0);
    acc[0][1] = __builtin_amdgcn_mfma_f32_16x16x32_bf16(a0h, b1h, acc[0][1], 0, 0, 0);
    acc[0][1] = __builtin_amdgcn_mfma_f32_16x16x32_bf16(a0h, b1l, acc[0][1], 0, 0, 0);
    acc[0][1] = __builtin_amdgcn_mfma_f32_16x16x32_bf16(a0l, b1h, acc[0][1], 0, 0, 0);
    acc[1][0] = __builtin_amdgcn_mfma_f32_16x16x32_bf16(a1h, b0h, acc[1][0], 0, 0, 0);
    acc[1][0] = __builtin_amdgcn_mfma_f32_16x16x32_bf16(a1h, b0l, acc[1][0], 0, 0, 0);
    acc[1][0] = __builtin_amdgcn_mfma_f32_16x16x32_bf16(a1l, b0h, acc[1][0], 0, 0, 0);
    acc[1][1] = __builtin_amdgcn_mfma_f32_16x16x32_bf16(a1h, b1h, acc[1][1], 0, 0, 0);
    acc[1][1] = __builtin_amdgcn_mfma_f32_16x16x32_bf16(a1h, b1l, acc[1][1], 0, 0, 0);
    acc[1][1] = __builtin_amdgcn_mfma_f32_16x16x32_bf16(a1l, b1h, acc[1][1], 0, 0, 0);
  }
}

__device__ __forceinline__ void frag_to_ys(float (*Ys)[132], const floatx4 acc[2][2]) {
  int lane = threadIdx.x & 63;
  int wave = threadIdx.x >> 6;
  int row0 = (wave >> 2) * 32 + (lane >> 4) * 4;
  int col0 = (wave & 3) * 32 + (lane & 15);
  #pragma unroll
  for (int mi = 0; mi < 2; ++mi)
    #pragma unroll
    for (int ni = 0; ni < 2; ++ni)
      #pragma unroll
      for (int r = 0; r < 4; ++r)
        Ys[row0 + mi * 16 + r][col0 + ni * 16] = acc[mi][ni][r];
}

__device__ __forceinline__ void ln_store(const float (*Ys)[132],
    const float* __restrict__ bias, const float* __restrict__ res,
    const float* __restrict__ g, const float* __restrict__ bl,
    float* __restrict__ Y, long row0, int N) {
  int r = threadIdx.x >> 3;
  int seg = (threadIdx.x & 7) * 16;
  long gr = row0 + r;
  float y[16];
  float s = 0.f, s2 = 0.f;
  if (gr < N) {
    #pragma unroll
    for (int q = 0; q < 4; ++q) {
      float4 v  = *(const float4*)&Ys[r][seg + q * 4];
      float4 b4 = *(const float4*)&bias[seg + q * 4];
      float4 rv = *(const float4*)&res[gr * 128 + seg + q * 4];
      float t0 = v.x + b4.x + rv.x;
      float t1 = v.y + b4.y + rv.y;
      float t2 = v.z + b4.z + rv.z;
      float t3 = v.w + b4.w + rv.w;
      y[q*4+0] = t0; y[q*4+1] = t1; y[q*4+2] = t2; y[q*4+3] = t3;
      s  += t0 + t1 + t2 + t3;
      s2 += t0*t0 + t1*t1 + t2*t2 + t3*t3;
    }
  } else {
    #pragma unroll
    for (int q = 0; q < 16; ++q) y[q] = 0.f;
  }
  #pragma unroll
  for (int off = 1; off < 8; off <<= 1) {
    s  += __shfl_xor(s, off);
    s2 += __shfl_xor(s2, off);
  }
  float m   = s * (1.f / 128.f);
  float var = s2 * (1.f / 128.f) - m * m;
  float inv = rsqrtf(var + 1e-5f);
  if (gr < N) {
    #pragma unroll
    for (int q = 0; q < 4; ++q) {
      float4 g4 = *(const float4*)&g[seg + q * 4];
      float4 b4 = *(const float4*)&bl[seg + q * 4];
      float4 o;
      o.x = (y[q*4+0] - m) * inv * g4.x + b4.x;
      o.y = (y[q*4+1] - m) * inv * g4.y + b4.y;
      o.z = (y[q*4+2] - m) * inv * g4.z + b4.z;
      o.w = (y[q*4+3] - m) * inv * g4.w + b4.w;
      *(float4*)&Y[gr * 128 + seg + q * 4] = o;
    }
  }
}

// ---------------- packed-fragment helpers for k_ffn ----------------
// slot(row,ks,g) = (((row>>4)*4 + ks)*4 + g)*16 + (row&15),  k = ks*32 + g*8
template<bool LO>
__device__ __forceinline__ void stage_x_packed(uint4* __restrict__ dst,
    const float* __restrict__ src, long row0, int N) {
  #pragma unroll
  for (int it = 0; it < 2; ++it) {
    int s = it * 512 + threadIdx.x;
    int r16 = s & 15, g = (s >> 4) & 3, ks = (s >> 6) & 3, rb = s >> 8;
    long gr = row0 + rb * 16 + r16;
    uint4 w = make_uint4(0u, 0u, 0u, 0u);
    if (gr < N) {
      const float* p = src + gr * 128 + ks * 32 + g * 8;
      float v[8];
      *(float4*)&v[0] = *(const float4*)p;
      *(float4*)&v[4] = *(const float4*)(p + 4);
      unsigned q[8];
      #pragma unroll
      for (int j = 0; j < 8; ++j) {
        unsigned short h = f2bf(v[j]);
        q[j] = LO ? (unsigned)f2bf(v[j] - bf2f(h)) : (unsigned)h;
      }
      w.x = q[0] | (q[1] << 16);
      w.y = q[2] | (q[3] << 16);
      w.z = q[4] | (q[5] << 16);
      w.w = q[6] | (q[7] << 16);
    }
    dst[s] = w;
  }
}

__device__ __forceinline__ void load_afrags(short8 af[2][4], const uint4* __restrict__ Xp, int wr) {
  int lane = threadIdx.x & 63;
  #pragma unroll
  for (int mi = 0; mi < 2; ++mi)
    #pragma unroll
    for (int ks = 0; ks < 4; ++ks)
      af[mi][ks] = *(const short8*)&Xp[((wr >> 4) + mi) * 256 + ks * 64 + lane];
}

#define MF(a, b, c) __builtin_amdgcn_mfma_f32_16x16x32_bf16(a, b, c, 0, 0, 0)

// ---------------- big kernels ----------------
// round-4 exact: split-bf16 GEMM, plain store
__global__ __launch_bounds__(512) void k_gemm_plain(const float* __restrict__ X,
    const unsigned short* __restrict__ Wh, const unsigned short* __restrict__ Wl,
    float* __restrict__ Y, int N) {
  __shared__ __align__(16) unsigned short XsH[64][136];
  __shared__ __align__(16) unsigned short XsL[64][136];
  __shared__ __align__(16) unsigned short WsH[128][136];
  __shared__ __align__(16) unsigned short WsL[128][136];
  long row0 = (long)blockIdx.x * 64;
  stage_xf32_split(XsH, XsL, X, row0, N);
  stage_w(WsH, Wh, 128);
  stage_w(WsL, Wl, 128);
  __syncthreads();
  floatx4 zero = {0.f, 0.f, 0.f, 0.f};
  floatx4 acc[2][2] = {{zero, zero}, {zero, zero}};
  mfma_64x128_3(XsH, XsL, WsH, WsL, acc);
  int lane = threadIdx.x & 63;
  int wave = threadIdx.x >> 6;
  int rowb = (wave >> 2) * 32 + (lane >> 4) * 4;
  int colb = (wave & 3) * 32 + (lane & 15);
  #pragma unroll
  for (int mi = 0; mi < 2; ++mi)
    #pragma unroll
    for (int ni = 0; ni < 2; ++ni)
      #pragma unroll
      for (int r = 0; r < 4; ++r) {
        long gr = row0 + rowb + mi * 16 + r;
        if (gr < N) Y[gr * 128 + colb + ni * 16] = acc[mi][ni][r];
      }
}

// round-4 exact: split-bf16 GEMM + residual + LN epilogue
__global__ __launch_bounds__(512) void k_gemm_ln(const float* __restrict__ X,
    const unsigned short* __restrict__ Wh, const unsigned short* __restrict__ Wl,
    const float* __restrict__ bias,
    const float* __restrict__ g, const float* __restrict__ bl,
    float* __restrict__ Y, int N) {
  __shared__ __align__(16) unsigned short XsH[64][136];
  __shared__ __align__(16) unsigned short XsL[64][136];
  __shared__ union __align__(16) WY {
    struct { unsigned short h[128][136]; unsigned short l[128][136]; } w;
    float ys[64][132];
  } wy;
  long row0 = (long)blockIdx.x * 64;
  stage_xf32_split(XsH, XsL, X, row0, N);
  stage_w(wy.w.h, Wh, 128);
  stage_w(wy.w.l, Wl, 128);
  __syncthreads();
  floatx4 zero = {0.f, 0.f, 0.f, 0.f};
  floatx4 acc[2][2] = {{zero, zero}, {zero, zero}};
  mfma_64x128_3(XsH, XsL, wy.w.h, wy.w.l, acc);
  __syncthreads();
  frag_to_ys(wy.ys, acc);
  __syncthreads();
  ln_store(wy.ys, bias, X, g, bl, Y, row0, N);
}

// k_ffn v5: round-4 numerics (X split + W1 split, single Z@W2).
// X frags in regs (verified), Z packed LDS exchange (verified),
// W fragments read DIRECTLY from global in packed fragment order (coalesced,
// L2-resident) -- no W staging, no prefetch registers.
// LDS = 16K (zx) + 33K (ys) ~= 49.5KB.
__global__ __launch_bounds__(512) void k_ffn(const float* __restrict__ T1,
    const uint4* __restrict__ W1hp, const uint4* __restrict__ W1lp,
    const float* __restrict__ b1,
    const uint4* __restrict__ W2p, const float* __restrict__ b2,
    const float* __restrict__ gam, const float* __restrict__ bet,
    float* __restrict__ Y, int N) {
  __shared__ __align__(16) uint4 zx[1024];
  __shared__ __align__(16) float ys[64][132];
  long row0 = (long)blockIdx.x * 64;
  int lane = threadIdx.x & 63;
  int wave = threadIdx.x >> 6;
  int wr = (wave >> 2) * 32, wc = (wave & 3) * 32;
  int gq = lane >> 4, r16c = lane & 15;

  // X hi+lo fragments -> registers (verified pattern)
  stage_x_packed<false>(zx, T1, row0, N);
  __syncthreads();
  short8 afh[2][4], afl[2][4];
  load_afrags(afh, zx, wr);
  __syncthreads();
  stage_x_packed<true>(zx, T1, row0, N);
  __syncthreads();
  load_afrags(afl, zx, wr);
  __syncthreads();                         // afl reads done; zx -> Z buffer

  unsigned short* Zu = (unsigned short*)zx;
  int zb0 = (((wr >> 4) + 0) * 4 + (wc >> 5)) * 4 + (r16c >> 3);
  int zb1 = (((wr >> 4) + 1) * 4 + (wc >> 5)) * 4 + (r16c >> 3);

  // per-wave global fragment bases (packed layout, coalesced across lanes)
  const uint4* p1h = W1hp + (wc >> 4) * 256;
  const uint4* p1l = W1lp + (wc >> 4) * 256;
  const uint4* p2b = W2p  + (wc >> 4) * 256;

  floatx4 zero = {0.f, 0.f, 0.f, 0.f};
  floatx4 acc2[2][2] = {{zero, zero}, {zero, zero}};

  for (int fc = 0; fc < 16; ++fc) {
    // phase A: Zc = relu(X @ W1c^T + b1c)  (X regs; W1 frags from global, split 3-product)
    const uint4* ph = p1h + fc * 2048;
    const uint4* pl = p1l + fc * 2048;
    floatx4 acc1[2][2] = {{zero, zero}, {zero, zero}};
    #pragma unroll
    for (int ks = 0; ks < 4; ++ks) {
      int nb = ks * 64 + lane;
      short8 bh0 = *(const short8*)&ph[nb];
      short8 bh1 = *(const short8*)&ph[nb + 256];
      short8 bl0 = *(const short8*)&pl[nb];
      short8 bl1 = *(const short8*)&pl[nb + 256];
      acc1[0][0] = MF(afh[0][ks], bh0, acc1[0][0]);
      acc1[0][0] = MF(afh[0][ks], bl0, acc1[0][0]);
      acc1[0][0] = MF(afl[0][ks], bh0, acc1[0][0]);
      acc1[0][1] = MF(afh[0][ks], bh1, acc1[0][1]);
      acc1[0][1] = MF(afh[0][ks], bl1, acc1[0][1]);
      acc1[0][1] = MF(afl[0][ks], bh1, acc1[0][1]);
      acc1[1][0] = MF(afh[1][ks], bh0, acc1[1][0]);
      acc1[1][0] = MF(afh[1][ks], bl0, acc1[1][0]);
      acc1[1][0] = MF(afl[1][ks], bh0, acc1[1][0]);
      acc1[1][1] = MF(afh[1][ks], bh1, acc1[1][1]);
      acc1[1][1] = MF(afh[1][ks], bl1, acc1[1][1]);
      acc1[1][1] = MF(afl[1][ks], bh1, acc1[1][1]);
    }
    float bv0 = b1[fc * 128 + wc + r16c];
    float bv1 = b1[fc * 128 + wc + 16 + r16c];
    #pragma unroll
    for (int mi = 0; mi < 2; ++mi) {
      int zb = mi ? zb1 : zb0;
      #pragma unroll
      for (int ni = 0; ni < 2; ++ni) {
        float bv = ni ? bv1 : bv0;
        #pragma unroll
        for (int r = 0; r < 4; ++r) {
          float z = fmaxf(acc1[mi][ni][r] + bv, 0.f);
          Zu[(zb + 2 * ni) * 128 + (4 * gq + r) * 8 + (r16c & 7)] = f2bf(z);
        }
      }
    }
    __syncthreads();                       // Z visible
    // phase B: acc2 += Zc @ W2c^T  (single bf16; W2 frags from global)
    const uint4* p2 = p2b + fc * 2048;
    #pragma unroll
    for (int ks = 0; ks < 4; ++ks) {
      int za = (wr >> 4) * 256 + ks * 64 + lane;
      short8 a0 = *(const short8*)&zx[za];
      short8 a1 = *(const short8*)&zx[za + 256];
      int nb = ks * 64 + lane;
      short8 b0  = *(const short8*)&p2[nb];
      short8 b1f = *(const short8*)&p2[nb + 256];
      acc2[0][0] = MF(a0, b0,  acc2[0][0]);
      acc2[0][1] = MF(a0, b1f, acc2[0][1]);
      acc2[1][0] = MF(a1, b0,  acc2[1][0]);
      acc2[1][1] = MF(a1, b1f, acc2[1][1]);
    }
    __syncthreads();                       // Z reads done before next overwrite
  }
  frag_to_ys(ys, acc2);
  __syncthreads();
  ln_store(ys, b2, T1, gam, bet, Y, row0, N);
}

// ---------------- launcher ----------------
extern "C" void kernel_launch(void* const* d_in, const int* in_sizes, int n_in,
                              void* d_out, int out_size, void* d_ws, size_t ws_size,
                              hipStream_t stream) {
  const int N = in_sizes[0] / 128;
  const int E = in_sizes[1] / 2;
  const float* x     = (const float*)d_in[0];
  const int*   ei    = (const int*)d_in[1];
  const float* gcn_w = (const float*)d_in[2];
  const float* gcn_b = (const float*)d_in[3];
  const float* in_w  = (const float*)d_in[4];
  const float* in_b  = (const float*)d_in[5];
  const float* out_w = (const float*)d_in[6];
  const float* out_b = (const float*)d_in[7];
  const float* ln1_g = (const float*)d_in[8];
  const float* ln1_b = (const float*)d_in[9];
  const float* ff1_w = (const float*)d_in[10];
  const float* ff1_b = (const float*)d_in[11];
  const float* ff2_w = (const float*)d_in[12];
  const float* ff2_b = (const float*)d_in[13];
  const float* ln2_g = (const float*)d_in[14];
  const float* ln2_b = (const float*)d_in[15];
  float* out = (float*)d_out;

  char* w = (char*)d_ws;
  auto alloc = [&](size_t bytes) { char* p = w; w += (bytes + 255) & ~(size_t)255; return p; };
  float* deg  = (float*)alloc((size_t)N * 4);
  float* dinv = (float*)alloc((size_t)N * 4);
  int*   off  = (int*)alloc((size_t)(N + 1) * 4);
  int*   cur  = (int*)alloc((size_t)N * 4);
  int*   srcs = (int*)alloc((size_t)E * 4);
  float* h0   = (float*)alloc((size_t)N * 128 * 4);   // reused as B2
  float* Hb   = (float*)alloc((size_t)N * 128 * 4);
  float* B1   = (float*)alloc((size_t)N * 128 * 4);
  float* Wc   = (float*)alloc(2 * 16384 * 4);
  float* bc   = (float*)alloc(2 * 128 * 4);
  unsigned short* gcnh = (unsigned short*)alloc(16384 * 2);
  unsigned short* gcnl = (unsigned short*)alloc(16384 * 2);
  unsigned short* Wch  = (unsigned short*)alloc(2 * 16384 * 2);
  unsigned short* Wcl  = (unsigned short*)alloc(2 * 16384 * 2);
  unsigned short* ff1hp = (unsigned short*)alloc(2 * 262144 * 2);  // packed fragment order
  unsigned short* ff1lp = (unsigned short*)alloc(2 * 262144 * 2);
  unsigned short* ff2p  = (unsigned short*)alloc(2 * 262144 * 2);
  float* B2 = h0;

  const int gN = (N + 255) / 256;
  const int gT = (N + 63) / 64;
  const int gV = (int)(((long)N * 32 + 255) / 256);
  const int nslots = 32768;                 // 2048*128/8 per layer

  // CSR build
  k_fill1<<<gN, 256, 0, stream>>>(deg, N);
  k_edge_deg<<<(E + 255) / 256, 256, 0, stream>>>(ei, deg, E);
  k_rsqrt<<<gN, 256, 0, stream>>>(dinv, deg, N);
  k_scan<<<1, 1024, 0, stream>>>(deg, off, N);
  hipMemcpyAsync(cur, off, (size_t)N * 4, hipMemcpyDeviceToDevice, stream);
  k_scatter<<<(E + 255) / 256, 256, 0, stream>>>(ei, cur, srcs, E);

  // weight prep
  k_combine<<<2, 256, 0, stream>>>(in_w, in_b, out_w, out_b, Wc, bc);
  k_f32bf16_split<<<(16384 + 255) / 256, 256, 0, stream>>>(gcn_w, gcnh, gcnl, 16384);
  k_f32bf16_split<<<(32768 + 255) / 256, 256, 0, stream>>>(Wc, Wch, Wcl, 32768);
  for (int l = 0; l < 2; ++l) {
    k_pack_rows<<<(nslots + 255) / 256, 256, 0, stream>>>(
        ff1_w + (long)l * 262144, ff1hp + (long)l * 262144, ff1lp + (long)l * 262144, nslots);
    k_pack_cols<<<(nslots + 255) / 256, 256, 0, stream>>>(
        ff2_w + (long)l * 262144, ff2p + (long)l * 262144, 2048, nslots);
  }

  // GCN
  k_gemm_plain<<<gT, 512, 0, stream>>>(x, gcnh, gcnl, h0, N);
  k_gcn_agg<<<(N + 3) / 4, 256, 0, stream>>>(off, srcs, dinv, h0, gcn_b, Hb, N);

  for (int l = 0; l < 2; ++l) {
    const float* src = (l == 0) ? Hb : B2;
    k_gemm_ln<<<gT, 512, 0, stream>>>(src, Wch + l * 16384, Wcl + l * 16384, bc + l * 128,
                                      ln1_g + l * 128, ln1_b + l * 128, B1, N);
    k_ffn<<<gT, 512, 0, stream>>>(B1,
                                  (const uint4*)(ff1hp + (long)l * 262144),
                                  (const uint4*)(ff1lp + (long)l * 262144),
                                  ff1_b + l * 2048,
                                  (const uint4*)(ff2p + (long)l * 262144),
                                  ff2_b + l * 128,
                                  ln2_g + l * 128, ln2_b + l * 128, B2, N);
  }

  k_final<<<gV, 256, 0, stream>>>(B2, Hb, out, N);
}

// Round 12
// 820.169 us; speedup vs baseline: 1.5726x; 1.0209x over previous
//
#include <hip/hip_runtime.h>

using short8  = __attribute__((ext_vector_type(8))) short;
using floatx4 = __attribute__((ext_vector_type(4))) float;

__device__ __forceinline__ unsigned short f2bf(float x) {
  unsigned int u = __float_as_uint(x);
  return (unsigned short)((u + 0x7FFFu + ((u >> 16) & 1u)) >> 16);
}
__device__ __forceinline__ float bf2f(unsigned short h) {
  return __uint_as_float(((unsigned int)h) << 16);
}

// ---------------- small elementwise / setup kernels ----------------
__global__ void k_fill1(float* __restrict__ p, int n) {
  int i = blockIdx.x * 256 + threadIdx.x;
  if (i < n) p[i] = 1.0f;
}

__global__ void k_edge_deg(const int* __restrict__ ei, float* __restrict__ deg, int E) {
  int e = blockIdx.x * 256 + threadIdx.x;
  if (e < E) atomicAdd(&deg[ei[E + e]], 1.0f);
}

__global__ void k_rsqrt(float* __restrict__ dinv, const float* __restrict__ deg, int n) {
  int i = blockIdx.x * 256 + threadIdx.x;
  if (i < n) dinv[i] = rsqrtf(deg[i]);
}

// hi = bf16(x); lo = bf16(x - hi)
__global__ void k_f32bf16_split(const float* __restrict__ src, unsigned short* __restrict__ hi,
                                unsigned short* __restrict__ lo, int n) {
  int i = blockIdx.x * 256 + threadIdx.x;
  if (i < n) {
    float x = src[i];
    unsigned short h = f2bf(x);
    hi[i] = h;
    lo[i] = f2bf(x - bf2f(h));
  }
}

// ---------------- packed-fragment weight prep (global fragment order) ----------------
// slot within 128x128 chunk: rem = c16*256 + ks*64 + g*16 + r16  (uint4 slots, 8 bf16 each)
//   covers out-feature = c16*16 + r16, k = ks*32 + g*8
// k_pack_rows: W[OUT][128], chunks along OUT (W1: OUT=2048)
__global__ void k_pack_rows(const float* __restrict__ W, unsigned short* __restrict__ hi,
                            unsigned short* __restrict__ lo, int nslots) {
  int s = blockIdx.x * 256 + threadIdx.x;
  if (s >= nslots) return;
  int chunk = s >> 11, rem = s & 2047;
  int c16 = rem >> 8, ks = (rem >> 6) & 3, g = (rem >> 4) & 3, r16 = rem & 15;
  int out = chunk * 128 + c16 * 16 + r16;
  int k   = ks * 32 + g * 8;
  const float* p = W + (long)out * 128 + k;
  float v[8];
  *(float4*)&v[0] = *(const float4*)p;
  *(float4*)&v[4] = *(const float4*)(p + 4);
  unsigned h[8], l[8];
  #pragma unroll
  for (int j = 0; j < 8; ++j) {
    unsigned short hh = f2bf(v[j]);
    h[j] = hh;
    l[j] = f2bf(v[j] - bf2f(hh));
  }
  uint4 wh = make_uint4(h[0] | (h[1] << 16), h[2] | (h[3] << 16),
                        h[4] | (h[5] << 16), h[6] | (h[7] << 16));
  *(uint4*)&hi[(long)s * 8] = wh;
  if (lo) {
    uint4 wl = make_uint4(l[0] | (l[1] << 16), l[2] | (l[3] << 16),
                          l[4] | (l[5] << 16), l[6] | (l[7] << 16));
    *(uint4*)&lo[(long)s * 8] = wl;
  }
}

// k_pack_cols: W[128][K], chunks along K (W2: K=2048), hi only
__global__ void k_pack_cols(const float* __restrict__ W, unsigned short* __restrict__ hi,
                            int K, int nslots) {
  int s = blockIdx.x * 256 + threadIdx.x;
  if (s >= nslots) return;
  int chunk = s >> 11, rem = s & 2047;
  int c16 = rem >> 8, ks = (rem >> 6) & 3, g = (rem >> 4) & 3, r16 = rem & 15;
  int out = c16 * 16 + r16;
  int k   = chunk * 128 + ks * 32 + g * 8;
  const float* p = W + (long)out * K + k;
  float v[8];
  *(float4*)&v[0] = *(const float4*)p;
  *(float4*)&v[4] = *(const float4*)(p + 4);
  unsigned h[8];
  #pragma unroll
  for (int j = 0; j < 8; ++j) h[j] = f2bf(v[j]);
  uint4 wh = make_uint4(h[0] | (h[1] << 16), h[2] | (h[3] << 16),
                        h[4] | (h[5] << 16), h[6] | (h[7] << 16));
  *(uint4*)&hi[(long)s * 8] = wh;
}

// ---------------- CSR build: scan + scatter ----------------
__global__ __launch_bounds__(1024) void k_scan(const float* __restrict__ deg,
                                               int* __restrict__ off, int N) {
  __shared__ int wsum[16];
  __shared__ int carry;
  if (threadIdx.x == 0) carry = 0;
  int lane = threadIdx.x & 63, wv = threadIdx.x >> 6;
  for (int base = 0; base < N; base += 1024) {
    int i = base + threadIdx.x;
    int c = (i < N) ? ((int)deg[i] - 1) : 0;
    int s = c;
    #pragma unroll
    for (int o = 1; o < 64; o <<= 1) {
      int t = __shfl_up(s, o);
      if (lane >= o) s += t;
    }
    __syncthreads();
    if (lane == 63) wsum[wv] = s;
    __syncthreads();
    int wpre = 0, total = 0;
    #pragma unroll
    for (int w = 0; w < 16; ++w) {
      int v = wsum[w];
      if (w < wv) wpre += v;
      total += v;
    }
    if (i < N) off[i] = carry + wpre + s - c;
    __syncthreads();
    if (threadIdx.x == 0) carry += total;
  }
  __syncthreads();
  if (threadIdx.x == 0) off[N] = carry;
}

__global__ void k_scatter(const int* __restrict__ ei, int* __restrict__ cur,
                          int* __restrict__ srcs, int E) {
  int e = blockIdx.x * 256 + threadIdx.x;
  if (e < E) {
    int r = ei[e], c = ei[E + e];
    int p = atomicAdd(&cur[c], 1);
    srcs[p] = r;
  }
}

__global__ __launch_bounds__(256) void k_gcn_agg(const int* __restrict__ off,
    const int* __restrict__ srcs, const float* __restrict__ dinv,
    const float* __restrict__ h0, const float* __restrict__ gcn_b,
    float* __restrict__ Hb, int N) {
  int node = blockIdx.x * 4 + (threadIdx.x >> 6);
  if (node >= N) return;
  int c2 = (threadIdx.x & 63) * 2;
  float dc = dinv[node];
  float a0 = 0.f, a1 = 0.f;
  int j = off[node], end = off[node + 1];
  for (; j + 1 < end; j += 2) {
    int s0 = srcs[j], s1 = srcs[j + 1];
    float w0 = dinv[s0] * dc, w1 = dinv[s1] * dc;
    float2 h0v = *(const float2*)&h0[(long)s0 * 128 + c2];
    float2 h1v = *(const float2*)&h0[(long)s1 * 128 + c2];
    a0 += w0 * h0v.x + w1 * h1v.x;
    a1 += w0 * h0v.y + w1 * h1v.y;
  }
  if (j < end) {
    int s0 = srcs[j];
    float w0 = dinv[s0] * dc;
    float2 hv = *(const float2*)&h0[(long)s0 * 128 + c2];
    a0 += w0 * hv.x;
    a1 += w0 * hv.y;
  }
  float2 hv = *(const float2*)&h0[(long)node * 128 + c2];
  float2 b  = *(const float2*)&gcn_b[c2];
  float v0 = a0 + dc * dc * hv.x + b.x;
  float v1 = a1 + dc * dc * hv.y + b.y;
  *(float2*)&Hb[(long)node * 128 + c2] = make_float2(fmaxf(v0, 0.f), fmaxf(v1, 0.f));
}

__global__ void k_final(const float* __restrict__ T, const float* __restrict__ Hb,
                        float* __restrict__ out, int N) {
  long i = (long)blockIdx.x * 256 + threadIdx.x;
  if (i >= (long)N * 32) return;
  long off = i * 4;
  float4 t = *(const float4*)&T[off];
  float4 h = *(const float4*)&Hb[off];
  float4 o;
  o.x = fmaxf(t.x + h.x, 0.f);
  o.y = fmaxf(t.y + h.y, 0.f);
  o.z = fmaxf(t.z + h.z, 0.f);
  o.w = fmaxf(t.w + h.w, 0.f);
  *(float4*)&out[off] = o;
}

// Wc[l] = out_w[l] @ Wv[l]; bc[l] = out_w[l] @ bv[l] + out_b[l]
__global__ void k_combine(const float* __restrict__ in_w, const float* __restrict__ in_b,
                          const float* __restrict__ out_w, const float* __restrict__ out_b,
                          float* __restrict__ Wc, float* __restrict__ bc) {
  __shared__ float Wvs[128][129];
  int l = blockIdx.x;
  const float* Wv = in_w + (long)l * 384 * 128 + 256 * 128;
  const float* bv = in_b + l * 384 + 256;
  const float* Wo = out_w + (long)l * 128 * 128;
  for (int i = threadIdx.x; i < 128 * 128; i += 256)
    Wvs[i >> 7][i & 127] = Wv[i];
  __syncthreads();
  for (int o = threadIdx.x; o < 128 * 128; o += 256) {
    int i = o >> 7, j = o & 127;
    float acc = 0.f;
    for (int k = 0; k < 128; ++k) acc += Wo[i * 128 + k] * Wvs[k][j];
    Wc[(long)l * 16384 + o] = acc;
  }
  if (threadIdx.x < 128) {
    int i = threadIdx.x;
    float acc = out_b[l * 128 + i];
    for (int k = 0; k < 128; ++k) acc += Wo[i * 128 + k] * bv[k];
    bc[l * 128 + i] = acc;
  }
}

// ---------------- round-4 MFMA GEMM helpers (verified) ----------------
__device__ __forceinline__ void stage_xf32_split(unsigned short (*dh)[136], unsigned short (*dl)[136],
                                                 const float* __restrict__ src, long row0, int N) {
  #pragma unroll
  for (int it = 0; it < 2; ++it) {
    int i = it * 512 + threadIdx.x;
    int r = i >> 4, c8 = (i & 15) * 8;
    long gr = row0 + r;
    uint4 wh = make_uint4(0u, 0u, 0u, 0u);
    uint4 wl = make_uint4(0u, 0u, 0u, 0u);
    if (gr < N) {
      const float* p = src + gr * 128 + c8;
      float v[8];
      *(float4*)&v[0] = *(const float4*)p;
      *(float4*)&v[4] = *(const float4*)(p + 4);
      unsigned short h[8], l[8];
      #pragma unroll
      for (int j = 0; j < 8; ++j) {
        h[j] = f2bf(v[j]);
        l[j] = f2bf(v[j] - bf2f(h[j]));
      }
      wh.x = (unsigned)h[0] | ((unsigned)h[1] << 16);
      wh.y = (unsigned)h[2] | ((unsigned)h[3] << 16);
      wh.z = (unsigned)h[4] | ((unsigned)h[5] << 16);
      wh.w = (unsigned)h[6] | ((unsigned)h[7] << 16);
      wl.x = (unsigned)l[0] | ((unsigned)l[1] << 16);
      wl.y = (unsigned)l[2] | ((unsigned)l[3] << 16);
      wl.z = (unsigned)l[4] | ((unsigned)l[5] << 16);
      wl.w = (unsigned)l[6] | ((unsigned)l[7] << 16);
    }
    *(uint4*)&dh[r][c8] = wh;
    *(uint4*)&dl[r][c8] = wl;
  }
}

__device__ __forceinline__ void stage_w(unsigned short (*dst)[136], const unsigned short* __restrict__ src,
                                        int ld) {
  #pragma unroll
  for (int it = 0; it < 4; ++it) {
    int i = it * 512 + threadIdx.x;
    int r = i >> 4, c8 = (i & 15) * 8;
    *(uint4*)&dst[r][c8] = *(const uint4*)&src[(long)r * ld + c8];
  }
}

__device__ __forceinline__ void mfma_64x128_3(const unsigned short (*Ah)[136], const unsigned short (*Al)[136],
                                              const unsigned short (*Bh)[136], const unsigned short (*Bl)[136],
                                              floatx4 acc[2][2]) {
  int lane = threadIdx.x & 63;
  int wave = threadIdx.x >> 6;
  int wr = (wave >> 2) * 32;
  int wc = (wave & 3) * 32;
  int r16 = lane & 15;
  int k8 = (lane >> 4) * 8;
  #pragma unroll
  for (int ks = 0; ks < 4; ++ks) {
    int k0 = ks * 32 + k8;
    short8 a0h = *(const short8*)&Ah[wr + r16][k0];
    short8 a1h = *(const short8*)&Ah[wr + 16 + r16][k0];
    short8 a0l = *(const short8*)&Al[wr + r16][k0];
    short8 a1l = *(const short8*)&Al[wr + 16 + r16][k0];
    short8 b0h = *(const short8*)&Bh[wc + r16][k0];
    short8 b1h = *(const short8*)&Bh[wc + 16 + r16][k0];
    short8 b0l = *(const short8*)&Bl[wc + r16][k0];
    short8 b1l = *(const short8*)&Bl[wc + 16 + r16][k0];
    acc[0][0] = __builtin_amdgcn_mfma_f32_16x16x32_bf16(a0h, b0h, acc[0][0], 0, 0, 0);
    acc[0][0] = __builtin_amdgcn_mfma_f32_16x16x32_bf16(a0h, b0l, acc[0][0], 0, 0, 0);
    acc[0][0] = __builtin_amdgcn_mfma_f32_16x16x32_bf16(a0l, b0h, acc[0][0], 0, 0, 0);
    acc[0][1] = __builtin_amdgcn_mfma_f32_16x16x32_bf16(a0h, b1h, acc[0][1], 0, 0, 0);
    acc[0][1] = __builtin_amdgcn_mfma_f32_16x16x32_bf16(a0h, b1l, acc[0][1], 0, 0, 0);
    acc[0][1] = __builtin_amdgcn_mfma_f32_16x16x32_bf16(a0l, b1h, acc[0][1], 0, 0, 0);
    acc[1][0] = __builtin_amdgcn_mfma_f32_16x16x32_bf16(a1h, b0h, acc[1][0], 0, 0, 0);
    acc[1][0] = __builtin_amdgcn_mfma_f32_16x16x32_bf16(a1h, b0l, acc[1][0], 0, 0, 0);
    acc[1][0] = __builtin_amdgcn_mfma_f32_16x16x32_bf16(a1l, b0h, acc[1][0], 0, 0, 0);
    acc[1][1] = __builtin_amdgcn_mfma_f32_16x16x32_bf16(a1h, b1h, acc[1][1], 0, 0, 0);
    acc[1][1] = __builtin_amdgcn_mfma_f32_16x16x32_bf16(a1h, b1l, acc[1][1], 0, 0, 0);
    acc[1][1] = __builtin_amdgcn_mfma_f32_16x16x32_bf16(a1l, b1h, acc[1][1], 0, 0, 0);
  }
}

__device__ __forceinline__ void frag_to_ys(float (*Ys)[132], const floatx4 acc[2][2]) {
  int lane = threadIdx.x & 63;
  int wave = threadIdx.x >> 6;
  int row0 = (wave >> 2) * 32 + (lane >> 4) * 4;
  int col0 = (wave & 3) * 32 + (lane & 15);
  #pragma unroll
  for (int mi = 0; mi < 2; ++mi)
    #pragma unroll
    for (int ni = 0; ni < 2; ++ni)
      #pragma unroll
      for (int r = 0; r < 4; ++r)
        Ys[row0 + mi * 16 + r][col0 + ni * 16] = acc[mi][ni][r];
}

__device__ __forceinline__ void ln_store(const float (*Ys)[132],
    const float* __restrict__ bias, const float* __restrict__ res,
    const float* __restrict__ g, const float* __restrict__ bl,
    float* __restrict__ Y, long row0, int N) {
  int r = threadIdx.x >> 3;
  int seg = (threadIdx.x & 7) * 16;
  long gr = row0 + r;
  float y[16];
  float s = 0.f, s2 = 0.f;
  if (gr < N) {
    #pragma unroll
    for (int q = 0; q < 4; ++q) {
      float4 v  = *(const float4*)&Ys[r][seg + q * 4];
      float4 b4 = *(const float4*)&bias[seg + q * 4];
      float4 rv = *(const float4*)&res[gr * 128 + seg + q * 4];
      float t0 = v.x + b4.x + rv.x;
      float t1 = v.y + b4.y + rv.y;
      float t2 = v.z + b4.z + rv.z;
      float t3 = v.w + b4.w + rv.w;
      y[q*4+0] = t0; y[q*4+1] = t1; y[q*4+2] = t2; y[q*4+3] = t3;
      s  += t0 + t1 + t2 + t3;
      s2 += t0*t0 + t1*t1 + t2*t2 + t3*t3;
    }
  } else {
    #pragma unroll
    for (int q = 0; q < 16; ++q) y[q] = 0.f;
  }
  #pragma unroll
  for (int off = 1; off < 8; off <<= 1) {
    s  += __shfl_xor(s, off);
    s2 += __shfl_xor(s2, off);
  }
  float m   = s * (1.f / 128.f);
  float var = s2 * (1.f / 128.f) - m * m;
  float inv = rsqrtf(var + 1e-5f);
  if (gr < N) {
    #pragma unroll
    for (int q = 0; q < 4; ++q) {
      float4 g4 = *(const float4*)&g[seg + q * 4];
      float4 b4 = *(const float4*)&bl[seg + q * 4];
      float4 o;
      o.x = (y[q*4+0] - m) * inv * g4.x + b4.x;
      o.y = (y[q*4+1] - m) * inv * g4.y + b4.y;
      o.z = (y[q*4+2] - m) * inv * g4.z + b4.z;
      o.w = (y[q*4+3] - m) * inv * g4.w + b4.w;
      *(float4*)&Y[gr * 128 + seg + q * 4] = o;
    }
  }
}

// ---------------- packed-fragment helpers for k_ffn ----------------
// slot(row,ks,g) = (((row>>4)*4 + ks)*4 + g)*16 + (row&15),  k = ks*32 + g*8
template<bool LO>
__device__ __forceinline__ void stage_x_packed(uint4* __restrict__ dst,
    const float* __restrict__ src, long row0, int N) {
  #pragma unroll
  for (int it = 0; it < 2; ++it) {
    int s = it * 512 + threadIdx.x;
    int r16 = s & 15, g = (s >> 4) & 3, ks = (s >> 6) & 3, rb = s >> 8;
    long gr = row0 + rb * 16 + r16;
    uint4 w = make_uint4(0u, 0u, 0u, 0u);
    if (gr < N) {
      const float* p = src + gr * 128 + ks * 32 + g * 8;
      float v[8];
      *(float4*)&v[0] = *(const float4*)p;
      *(float4*)&v[4] = *(const float4*)(p + 4);
      unsigned q[8];
      #pragma unroll
      for (int j = 0; j < 8; ++j) {
        unsigned short h = f2bf(v[j]);
        q[j] = LO ? (unsigned)f2bf(v[j] - bf2f(h)) : (unsigned)h;
      }
      w.x = q[0] | (q[1] << 16);
      w.y = q[2] | (q[3] << 16);
      w.z = q[4] | (q[5] << 16);
      w.w = q[6] | (q[7] << 16);
    }
    dst[s] = w;
  }
}

__device__ __forceinline__ void load_afrags(short8 af[2][4], const uint4* __restrict__ Xp, int wr) {
  int lane = threadIdx.x & 63;
  #pragma unroll
  for (int mi = 0; mi < 2; ++mi)
    #pragma unroll
    for (int ks = 0; ks < 4; ++ks)
      af[mi][ks] = *(const short8*)&Xp[((wr >> 4) + mi) * 256 + ks * 64 + lane];
}

#define MF(a, b, c) __builtin_amdgcn_mfma_f32_16x16x32_bf16(a, b, c, 0, 0, 0)

// ---------------- big kernels ----------------
// round-4 exact: split-bf16 GEMM, plain store
__global__ __launch_bounds__(512) void k_gemm_plain(const float* __restrict__ X,
    const unsigned short* __restrict__ Wh, const unsigned short* __restrict__ Wl,
    float* __restrict__ Y, int N) {
  __shared__ __align__(16) unsigned short XsH[64][136];
  __shared__ __align__(16) unsigned short XsL[64][136];
  __shared__ __align__(16) unsigned short WsH[128][136];
  __shared__ __align__(16) unsigned short WsL[128][136];
  long row0 = (long)blockIdx.x * 64;
  stage_xf32_split(XsH, XsL, X, row0, N);
  stage_w(WsH, Wh, 128);
  stage_w(WsL, Wl, 128);
  __syncthreads();
  floatx4 zero = {0.f, 0.f, 0.f, 0.f};
  floatx4 acc[2][2] = {{zero, zero}, {zero, zero}};
  mfma_64x128_3(XsH, XsL, WsH, WsL, acc);
  int lane = threadIdx.x & 63;
  int wave = threadIdx.x >> 6;
  int rowb = (wave >> 2) * 32 + (lane >> 4) * 4;
  int colb = (wave & 3) * 32 + (lane & 15);
  #pragma unroll
  for (int mi = 0; mi < 2; ++mi)
    #pragma unroll
    for (int ni = 0; ni < 2; ++ni)
      #pragma unroll
      for (int r = 0; r < 4; ++r) {
        long gr = row0 + rowb + mi * 16 + r;
        if (gr < N) Y[gr * 128 + colb + ni * 16] = acc[mi][ni][r];
      }
}

// round-4 exact: split-bf16 GEMM + residual + LN epilogue
__global__ __launch_bounds__(512) void k_gemm_ln(const float* __restrict__ X,
    const unsigned short* __restrict__ Wh, const unsigned short* __restrict__ Wl,
    const float* __restrict__ bias,
    const float* __restrict__ g, const float* __restrict__ bl,
    float* __restrict__ Y, int N) {
  __shared__ __align__(16) unsigned short XsH[64][136];
  __shared__ __align__(16) unsigned short XsL[64][136];
  __shared__ union __align__(16) WY {
    struct { unsigned short h[128][136]; unsigned short l[128][136]; } w;
    float ys[64][132];
  } wy;
  long row0 = (long)blockIdx.x * 64;
  stage_xf32_split(XsH, XsL, X, row0, N);
  stage_w(wy.w.h, Wh, 128);
  stage_w(wy.w.l, Wl, 128);
  __syncthreads();
  floatx4 zero = {0.f, 0.f, 0.f, 0.f};
  floatx4 acc[2][2] = {{zero, zero}, {zero, zero}};
  mfma_64x128_3(XsH, XsL, wy.w.h, wy.w.l, acc);
  __syncthreads();
  frag_to_ys(wy.ys, acc);
  __syncthreads();
  ln_store(wy.ys, bias, X, g, bl, Y, row0, N);
}

// k_ffn v7 = r10's verified kernel + Z DOUBLE-BUFFER (the ONLY change this round).
// Z alternates between zx and the first 16KB of the ys region -> one barrier per
// chunk (20 total vs 36). Safety: phase B(fc) reads buf[fc&1]; the next write to
// that buffer is phase A(fc+2), which follows barrier(fc+1) in every wave, while
// B(fc)'s reads complete before that wave passes barrier(fc+1) (syncthreads
// drains lgkmcnt). ys is only overlaid after the post-loop barrier.
__global__ __launch_bounds__(512) void k_ffn(const float* __restrict__ T1,
    const uint4* __restrict__ W1hp, const uint4* __restrict__ W1lp,
    const float* __restrict__ b1,
    const uint4* __restrict__ W2p, const float* __restrict__ b2,
    const float* __restrict__ gam, const float* __restrict__ bet,
    float* __restrict__ Y, int N) {
  __shared__ __align__(16) uint4 zx[1024];
  __shared__ __align__(16) float ys[64][132];
  uint4* zalt = (uint4*)ys;                     // 16KB of ys = second Z buffer
  long row0 = (long)blockIdx.x * 64;
  int lane = threadIdx.x & 63;
  int wave = threadIdx.x >> 6;
  int wr = (wave >> 2) * 32, wc = (wave & 3) * 32;
  int gq = lane >> 4, r16c = lane & 15;

  // X hi+lo fragments -> registers (r10-verbatim 4-barrier prologue)
  stage_x_packed<false>(zx, T1, row0, N);
  __syncthreads();
  short8 afh[2][4], afl[2][4];
  load_afrags(afh, zx, wr);
  __syncthreads();
  stage_x_packed<true>(zx, T1, row0, N);
  __syncthreads();
  load_afrags(afl, zx, wr);
  __syncthreads();                              // afl reads done; zx/zalt -> Z dbuf

  int zb0 = (((wr >> 4) + 0) * 4 + (wc >> 5)) * 4 + (r16c >> 3);
  int zb1 = (((wr >> 4) + 1) * 4 + (wc >> 5)) * 4 + (r16c >> 3);

  // per-wave global fragment bases (packed layout, coalesced across lanes)
  const uint4* p1h = W1hp + (wc >> 4) * 256;
  const uint4* p1l = W1lp + (wc >> 4) * 256;
  const uint4* p2b = W2p  + (wc >> 4) * 256;

  floatx4 zero = {0.f, 0.f, 0.f, 0.f};
  floatx4 acc2[2][2] = {{zero, zero}, {zero, zero}};

  for (int fc = 0; fc < 16; ++fc) {
    uint4* zb = (fc & 1) ? zalt : zx;
    unsigned short* Zu = (unsigned short*)zb;
    // phase A: Zc = relu(X @ W1c^T + b1c)  (X regs; W1 frags from global, split 3-product)
    const uint4* ph = p1h + fc * 2048;
    const uint4* pl = p1l + fc * 2048;
    floatx4 acc1[2][2] = {{zero, zero}, {zero, zero}};
    #pragma unroll
    for (int ks = 0; ks < 4; ++ks) {
      int nb = ks * 64 + lane;
      short8 bh0 = *(const short8*)&ph[nb];
      short8 bh1 = *(const short8*)&ph[nb + 256];
      short8 bl0 = *(const short8*)&pl[nb];
      short8 bl1 = *(const short8*)&pl[nb + 256];
      acc1[0][0] = MF(afh[0][ks], bh0, acc1[0][0]);
      acc1[0][0] = MF(afh[0][ks], bl0, acc1[0][0]);
      acc1[0][0] = MF(afl[0][ks], bh0, acc1[0][0]);
      acc1[0][1] = MF(afh[0][ks], bh1, acc1[0][1]);
      acc1[0][1] = MF(afh[0][ks], bl1, acc1[0][1]);
      acc1[0][1] = MF(afl[0][ks], bh1, acc1[0][1]);
      acc1[1][0] = MF(afh[1][ks], bh0, acc1[1][0]);
      acc1[1][0] = MF(afh[1][ks], bl0, acc1[1][0]);
      acc1[1][0] = MF(afl[1][ks], bh0, acc1[1][0]);
      acc1[1][1] = MF(afh[1][ks], bh1, acc1[1][1]);
      acc1[1][1] = MF(afh[1][ks], bl1, acc1[1][1]);
      acc1[1][1] = MF(afl[1][ks], bh1, acc1[1][1]);
    }
    float bv0 = b1[fc * 128 + wc + r16c];
    float bv1 = b1[fc * 128 + wc + 16 + r16c];
    #pragma unroll
    for (int mi = 0; mi < 2; ++mi) {
      int zbi = mi ? zb1 : zb0;
      #pragma unroll
      for (int ni = 0; ni < 2; ++ni) {
        float bv = ni ? bv1 : bv0;
        #pragma unroll
        for (int r = 0; r < 4; ++r) {
          float z = fmaxf(acc1[mi][ni][r] + bv, 0.f);
          Zu[(zbi + 2 * ni) * 128 + (4 * gq + r) * 8 + (r16c & 7)] = f2bf(z);
        }
      }
    }
    __syncthreads();                            // Z(fc) visible (only barrier this chunk)
    // phase B: acc2 += Zc @ W2c^T  (single bf16; W2 frags from global)
    const uint4* p2 = p2b + fc * 2048;
    #pragma unroll
    for (int ks = 0; ks < 4; ++ks) {
      int za = (wr >> 4) * 256 + ks * 64 + lane;
      short8 a0 = *(const short8*)&zb[za];
      short8 a1 = *(const short8*)&zb[za + 256];
      int nb = ks * 64 + lane;
      short8 b0  = *(const short8*)&p2[nb];
      short8 b1f = *(const short8*)&p2[nb + 256];
      acc2[0][0] = MF(a0, b0,  acc2[0][0]);
      acc2[0][1] = MF(a0, b1f, acc2[0][1]);
      acc2[1][0] = MF(a1, b0,  acc2[1][0]);
      acc2[1][1] = MF(a1, b1f, acc2[1][1]);
    }
    // no second barrier: next phase A writes the OTHER buffer
  }
  __syncthreads();                              // last phase-B reads done before ys overlay
  frag_to_ys(ys, acc2);
  __syncthreads();
  ln_store(ys, b2, T1, gam, bet, Y, row0, N);
}

// ---------------- launcher ----------------
extern "C" void kernel_launch(void* const* d_in, const int* in_sizes, int n_in,
                              void* d_out, int out_size, void* d_ws, size_t ws_size,
                              hipStream_t stream) {
  const int N = in_sizes[0] / 128;
  const int E = in_sizes[1] / 2;
  const float* x     = (const float*)d_in[0];
  const int*   ei    = (const int*)d_in[1];
  const float* gcn_w = (const float*)d_in[2];
  const float* gcn_b = (const float*)d_in[3];
  const float* in_w  = (const float*)d_in[4];
  const float* in_b  = (const float*)d_in[5];
  const float* out_w = (const float*)d_in[6];
  const float* out_b = (const float*)d_in[7];
  const float* ln1_g = (const float*)d_in[8];
  const float* ln1_b = (const float*)d_in[9];
  const float* ff1_w = (const float*)d_in[10];
  const float* ff1_b = (const float*)d_in[11];
  const float* ff2_w = (const float*)d_in[12];
  const float* ff2_b = (const float*)d_in[13];
  const float* ln2_g = (const float*)d_in[14];
  const float* ln2_b = (const float*)d_in[15];
  float* out = (float*)d_out;

  char* w = (char*)d_ws;
  auto alloc = [&](size_t bytes) { char* p = w; w += (bytes + 255) & ~(size_t)255; return p; };
  float* deg  = (float*)alloc((size_t)N * 4);
  float* dinv = (float*)alloc((size_t)N * 4);
  int*   off  = (int*)alloc((size_t)(N + 1) * 4);
  int*   cur  = (int*)alloc((size_t)N * 4);
  int*   srcs = (int*)alloc((size_t)E * 4);
  float* h0   = (float*)alloc((size_t)N * 128 * 4);   // reused as B2
  float* Hb   = (float*)alloc((size_t)N * 128 * 4);
  float* B1   = (float*)alloc((size_t)N * 128 * 4);
  float* Wc   = (float*)alloc(2 * 16384 * 4);
  float* bc   = (float*)alloc(2 * 128 * 4);
  unsigned short* gcnh = (unsigned short*)alloc(16384 * 2);
  unsigned short* gcnl = (unsigned short*)alloc(16384 * 2);
  unsigned short* Wch  = (unsigned short*)alloc(2 * 16384 * 2);
  unsigned short* Wcl  = (unsigned short*)alloc(2 * 16384 * 2);
  unsigned short* ff1hp = (unsigned short*)alloc(2 * 262144 * 2);  // packed fragment order
  unsigned short* ff1lp = (unsigned short*)alloc(2 * 262144 * 2);
  unsigned short* ff2p  = (unsigned short*)alloc(2 * 262144 * 2);
  float* B2 = h0;

  const int gN = (N + 255) / 256;
  const int gT = (N + 63) / 64;
  const int gV = (int)(((long)N * 32 + 255) / 256);
  const int nslots = 32768;                 // 2048*128/8 per FFN layer

  // CSR build
  k_fill1<<<gN, 256, 0, stream>>>(deg, N);
  k_edge_deg<<<(E + 255) / 256, 256, 0, stream>>>(ei, deg, E);
  k_rsqrt<<<gN, 256, 0, stream>>>(dinv, deg, N);
  k_scan<<<1, 1024, 0, stream>>>(deg, off, N);
  hipMemcpyAsync(cur, off, (size_t)N * 4, hipMemcpyDeviceToDevice, stream);
  k_scatter<<<(E + 255) / 256, 256, 0, stream>>>(ei, cur, srcs, E);

  // weight prep (r10-verbatim: split arrays for gemm kernels, packed for ffn)
  k_combine<<<2, 256, 0, stream>>>(in_w, in_b, out_w, out_b, Wc, bc);
  k_f32bf16_split<<<(16384 + 255) / 256, 256, 0, stream>>>(gcn_w, gcnh, gcnl, 16384);
  k_f32bf16_split<<<(32768 + 255) / 256, 256, 0, stream>>>(Wc, Wch, Wcl, 32768);
  for (int l = 0; l < 2; ++l) {
    k_pack_rows<<<(nslots + 255) / 256, 256, 0, stream>>>(
        ff1_w + (long)l * 262144, ff1hp + (long)l * 262144, ff1lp + (long)l * 262144, nslots);
    k_pack_cols<<<(nslots + 255) / 256, 256, 0, stream>>>(
        ff2_w + (long)l * 262144, ff2p + (long)l * 262144, 2048, nslots);
  }

  // GCN
  k_gemm_plain<<<gT, 512, 0, stream>>>(x, gcnh, gcnl, h0, N);
  k_gcn_agg<<<(N + 3) / 4, 256, 0, stream>>>(off, srcs, dinv, h0, gcn_b, Hb, N);

  for (int l = 0; l < 2; ++l) {
    const float* src = (l == 0) ? Hb : B2;
    k_gemm_ln<<<gT, 512, 0, stream>>>(src, Wch + l * 16384, Wcl + l * 16384, bc + l * 128,
                                      ln1_g + l * 128, ln1_b + l * 128, B1, N);
    k_ffn<<<gT, 512, 0, stream>>>(B1,
                                  (const uint4*)(ff1hp + (long)l * 262144),
                                  (const uint4*)(ff1lp + (long)l * 262144),
                                  ff1_b + l * 2048,
                                  (const uint4*)(ff2p + (long)l * 262144),
                                  ff2_b + l * 128,
                                  ln2_g + l * 128, ln2_b + l * 128, B2, N);
  }

  k_final<<<gV, 256, 0, stream>>>(B2, Hb, out, N);
}

// Round 13
// 620.332 us; speedup vs baseline: 2.0792x; 1.3221x over previous
//
#include <hip/hip_runtime.h>

using short8  = __attribute__((ext_vector_type(8))) short;
using floatx4 = __attribute__((ext_vector_type(4))) float;

__device__ __forceinline__ unsigned short f2bf(float x) {
  unsigned int u = __float_as_uint(x);
  return (unsigned short)((u + 0x7FFFu + ((u >> 16) & 1u)) >> 16);
}
__device__ __forceinline__ float bf2f(unsigned short h) {
  return __uint_as_float(((unsigned int)h) << 16);
}

// ---------------- small elementwise / setup kernels ----------------
__global__ void k_fill1(float* __restrict__ p, int n) {
  int i = blockIdx.x * 256 + threadIdx.x;
  if (i < n) p[i] = 1.0f;
}

__global__ void k_edge_deg(const int* __restrict__ ei, float* __restrict__ deg, int E) {
  int e = blockIdx.x * 256 + threadIdx.x;
  if (e < E) atomicAdd(&deg[ei[E + e]], 1.0f);
}

__global__ void k_rsqrt(float* __restrict__ dinv, const float* __restrict__ deg, int n) {
  int i = blockIdx.x * 256 + threadIdx.x;
  if (i < n) dinv[i] = rsqrtf(deg[i]);
}

// hi = bf16(x); lo = bf16(x - hi)
__global__ void k_f32bf16_split(const float* __restrict__ src, unsigned short* __restrict__ hi,
                                unsigned short* __restrict__ lo, int n) {
  int i = blockIdx.x * 256 + threadIdx.x;
  if (i < n) {
    float x = src[i];
    unsigned short h = f2bf(x);
    hi[i] = h;
    lo[i] = f2bf(x - bf2f(h));
  }
}

// ---------------- packed-fragment weight prep (global fragment order) ----------------
// slot within 128x128 chunk: rem = c16*256 + ks*64 + g*16 + r16  (uint4 slots, 8 bf16 each)
//   covers out-feature = c16*16 + r16, k = ks*32 + g*8
// k_pack_rows: W[OUT][128], chunks along OUT (W1: OUT=2048)
__global__ void k_pack_rows(const float* __restrict__ W, unsigned short* __restrict__ hi,
                            unsigned short* __restrict__ lo, int nslots) {
  int s = blockIdx.x * 256 + threadIdx.x;
  if (s >= nslots) return;
  int chunk = s >> 11, rem = s & 2047;
  int c16 = rem >> 8, ks = (rem >> 6) & 3, g = (rem >> 4) & 3, r16 = rem & 15;
  int out = chunk * 128 + c16 * 16 + r16;
  int k   = ks * 32 + g * 8;
  const float* p = W + (long)out * 128 + k;
  float v[8];
  *(float4*)&v[0] = *(const float4*)p;
  *(float4*)&v[4] = *(const float4*)(p + 4);
  unsigned h[8], l[8];
  #pragma unroll
  for (int j = 0; j < 8; ++j) {
    unsigned short hh = f2bf(v[j]);
    h[j] = hh;
    l[j] = f2bf(v[j] - bf2f(hh));
  }
  uint4 wh = make_uint4(h[0] | (h[1] << 16), h[2] | (h[3] << 16),
                        h[4] | (h[5] << 16), h[6] | (h[7] << 16));
  *(uint4*)&hi[(long)s * 8] = wh;
  if (lo) {
    uint4 wl = make_uint4(l[0] | (l[1] << 16), l[2] | (l[3] << 16),
                          l[4] | (l[5] << 16), l[6] | (l[7] << 16));
    *(uint4*)&lo[(long)s * 8] = wl;
  }
}

// k_pack_cols: W[128][K], chunks along K (W2: K=2048), hi only
__global__ void k_pack_cols(const float* __restrict__ W, unsigned short* __restrict__ hi,
                            int K, int nslots) {
  int s = blockIdx.x * 256 + threadIdx.x;
  if (s >= nslots) return;
  int chunk = s >> 11, rem = s & 2047;
  int c16 = rem >> 8, ks = (rem >> 6) & 3, g = (rem >> 4) & 3, r16 = rem & 15;
  int out = c16 * 16 + r16;
  int k   = chunk * 128 + ks * 32 + g * 8;
  const float* p = W + (long)out * K + k;
  float v[8];
  *(float4*)&v[0] = *(const float4*)p;
  *(float4*)&v[4] = *(const float4*)(p + 4);
  unsigned h[8];
  #pragma unroll
  for (int j = 0; j < 8; ++j) h[j] = f2bf(v[j]);
  uint4 wh = make_uint4(h[0] | (h[1] << 16), h[2] | (h[3] << 16),
                        h[4] | (h[5] << 16), h[6] | (h[7] << 16));
  *(uint4*)&hi[(long)s * 8] = wh;
}

// ---------------- CSR build: scan + scatter ----------------
__global__ __launch_bounds__(1024) void k_scan(const float* __restrict__ deg,
                                               int* __restrict__ off, int N) {
  __shared__ int wsum[16];
  __shared__ int carry;
  if (threadIdx.x == 0) carry = 0;
  int lane = threadIdx.x & 63, wv = threadIdx.x >> 6;
  for (int base = 0; base < N; base += 1024) {
    int i = base + threadIdx.x;
    int c = (i < N) ? ((int)deg[i] - 1) : 0;
    int s = c;
    #pragma unroll
    for (int o = 1; o < 64; o <<= 1) {
      int t = __shfl_up(s, o);
      if (lane >= o) s += t;
    }
    __syncthreads();
    if (lane == 63) wsum[wv] = s;
    __syncthreads();
    int wpre = 0, total = 0;
    #pragma unroll
    for (int w = 0; w < 16; ++w) {
      int v = wsum[w];
      if (w < wv) wpre += v;
      total += v;
    }
    if (i < N) off[i] = carry + wpre + s - c;
    __syncthreads();
    if (threadIdx.x == 0) carry += total;
  }
  __syncthreads();
  if (threadIdx.x == 0) off[N] = carry;
}

__global__ void k_scatter(const int* __restrict__ ei, int* __restrict__ cur,
                          int* __restrict__ srcs, int E) {
  int e = blockIdx.x * 256 + threadIdx.x;
  if (e < E) {
    int r = ei[e], c = ei[E + e];
    int p = atomicAdd(&cur[c], 1);
    srcs[p] = r;
  }
}

__global__ __launch_bounds__(256) void k_gcn_agg(const int* __restrict__ off,
    const int* __restrict__ srcs, const float* __restrict__ dinv,
    const float* __restrict__ h0, const float* __restrict__ gcn_b,
    float* __restrict__ Hb, int N) {
  int node = blockIdx.x * 4 + (threadIdx.x >> 6);
  if (node >= N) return;
  int c2 = (threadIdx.x & 63) * 2;
  float dc = dinv[node];
  float a0 = 0.f, a1 = 0.f;
  int j = off[node], end = off[node + 1];
  for (; j + 1 < end; j += 2) {
    int s0 = srcs[j], s1 = srcs[j + 1];
    float w0 = dinv[s0] * dc, w1 = dinv[s1] * dc;
    float2 h0v = *(const float2*)&h0[(long)s0 * 128 + c2];
    float2 h1v = *(const float2*)&h0[(long)s1 * 128 + c2];
    a0 += w0 * h0v.x + w1 * h1v.x;
    a1 += w0 * h0v.y + w1 * h1v.y;
  }
  if (j < end) {
    int s0 = srcs[j];
    float w0 = dinv[s0] * dc;
    float2 hv = *(const float2*)&h0[(long)s0 * 128 + c2];
    a0 += w0 * hv.x;
    a1 += w0 * hv.y;
  }
  float2 hv = *(const float2*)&h0[(long)node * 128 + c2];
  float2 b  = *(const float2*)&gcn_b[c2];
  float v0 = a0 + dc * dc * hv.x + b.x;
  float v1 = a1 + dc * dc * hv.y + b.y;
  *(float2*)&Hb[(long)node * 128 + c2] = make_float2(fmaxf(v0, 0.f), fmaxf(v1, 0.f));
}

__global__ void k_final(const float* __restrict__ T, const float* __restrict__ Hb,
                        float* __restrict__ out, int N) {
  long i = (long)blockIdx.x * 256 + threadIdx.x;
  if (i >= (long)N * 32) return;
  long off = i * 4;
  float4 t = *(const float4*)&T[off];
  float4 h = *(const float4*)&Hb[off];
  float4 o;
  o.x = fmaxf(t.x + h.x, 0.f);
  o.y = fmaxf(t.y + h.y, 0.f);
  o.z = fmaxf(t.z + h.z, 0.f);
  o.w = fmaxf(t.w + h.w, 0.f);
  *(float4*)&out[off] = o;
}

// Wc[l] = out_w[l] @ Wv[l]; bc[l] = out_w[l] @ bv[l] + out_b[l]
__global__ void k_combine(const float* __restrict__ in_w, const float* __restrict__ in_b,
                          const float* __restrict__ out_w, const float* __restrict__ out_b,
                          float* __restrict__ Wc, float* __restrict__ bc) {
  __shared__ float Wvs[128][129];
  int l = blockIdx.x;
  const float* Wv = in_w + (long)l * 384 * 128 + 256 * 128;
  const float* bv = in_b + l * 384 + 256;
  const float* Wo = out_w + (long)l * 128 * 128;
  for (int i = threadIdx.x; i < 128 * 128; i += 256)
    Wvs[i >> 7][i & 127] = Wv[i];
  __syncthreads();
  for (int o = threadIdx.x; o < 128 * 128; o += 256) {
    int i = o >> 7, j = o & 127;
    float acc = 0.f;
    for (int k = 0; k < 128; ++k) acc += Wo[i * 128 + k] * Wvs[k][j];
    Wc[(long)l * 16384 + o] = acc;
  }
  if (threadIdx.x < 128) {
    int i = threadIdx.x;
    float acc = out_b[l * 128 + i];
    for (int k = 0; k < 128; ++k) acc += Wo[i * 128 + k] * bv[k];
    bc[l * 128 + i] = acc;
  }
}

// ---------------- round-4 MFMA GEMM helpers (verified) ----------------
__device__ __forceinline__ void stage_xf32_split(unsigned short (*dh)[136], unsigned short (*dl)[136],
                                                 const float* __restrict__ src, long row0, int N) {
  #pragma unroll
  for (int it = 0; it < 2; ++it) {
    int i = it * 512 + threadIdx.x;
    int r = i >> 4, c8 = (i & 15) * 8;
    long gr = row0 + r;
    uint4 wh = make_uint4(0u, 0u, 0u, 0u);
    uint4 wl = make_uint4(0u, 0u, 0u, 0u);
    if (gr < N) {
      const float* p = src + gr * 128 + c8;
      float v[8];
      *(float4*)&v[0] = *(const float4*)p;
      *(float4*)&v[4] = *(const float4*)(p + 4);
      unsigned short h[8], l[8];
      #pragma unroll
      for (int j = 0; j < 8; ++j) {
        h[j] = f2bf(v[j]);
        l[j] = f2bf(v[j] - bf2f(h[j]));
      }
      wh.x = (unsigned)h[0] | ((unsigned)h[1] << 16);
      wh.y = (unsigned)h[2] | ((unsigned)h[3] << 16);
      wh.z = (unsigned)h[4] | ((unsigned)h[5] << 16);
      wh.w = (unsigned)h[6] | ((unsigned)h[7] << 16);
      wl.x = (unsigned)l[0] | ((unsigned)l[1] << 16);
      wl.y = (unsigned)l[2] | ((unsigned)l[3] << 16);
      wl.z = (unsigned)l[4] | ((unsigned)l[5] << 16);
      wl.w = (unsigned)l[6] | ((unsigned)l[7] << 16);
    }
    *(uint4*)&dh[r][c8] = wh;
    *(uint4*)&dl[r][c8] = wl;
  }
}

__device__ __forceinline__ void stage_w(unsigned short (*dst)[136], const unsigned short* __restrict__ src,
                                        int ld) {
  #pragma unroll
  for (int it = 0; it < 4; ++it) {
    int i = it * 512 + threadIdx.x;
    int r = i >> 4, c8 = (i & 15) * 8;
    *(uint4*)&dst[r][c8] = *(const uint4*)&src[(long)r * ld + c8];
  }
}

__device__ __forceinline__ void mfma_64x128_3(const unsigned short (*Ah)[136], const unsigned short (*Al)[136],
                                              const unsigned short (*Bh)[136], const unsigned short (*Bl)[136],
                                              floatx4 acc[2][2]) {
  int lane = threadIdx.x & 63;
  int wave = threadIdx.x >> 6;
  int wr = (wave >> 2) * 32;
  int wc = (wave & 3) * 32;
  int r16 = lane & 15;
  int k8 = (lane >> 4) * 8;
  #pragma unroll
  for (int ks = 0; ks < 4; ++ks) {
    int k0 = ks * 32 + k8;
    short8 a0h = *(const short8*)&Ah[wr + r16][k0];
    short8 a1h = *(const short8*)&Ah[wr + 16 + r16][k0];
    short8 a0l = *(const short8*)&Al[wr + r16][k0];
    short8 a1l = *(const short8*)&Al[wr + 16 + r16][k0];
    short8 b0h = *(const short8*)&Bh[wc + r16][k0];
    short8 b1h = *(const short8*)&Bh[wc + 16 + r16][k0];
    short8 b0l = *(const short8*)&Bl[wc + r16][k0];
    short8 b1l = *(const short8*)&Bl[wc + 16 + r16][k0];
    acc[0][0] = __builtin_amdgcn_mfma_f32_16x16x32_bf16(a0h, b0h, acc[0][0], 0, 0, 0);
    acc[0][0] = __builtin_amdgcn_mfma_f32_16x16x32_bf16(a0h, b0l, acc[0][0], 0, 0, 0);
    acc[0][0] = __builtin_amdgcn_mfma_f32_16x16x32_bf16(a0l, b0h, acc[0][0], 0, 0, 0);
    acc[0][1] = __builtin_amdgcn_mfma_f32_16x16x32_bf16(a0h, b1h, acc[0][1], 0, 0, 0);
    acc[0][1] = __builtin_amdgcn_mfma_f32_16x16x32_bf16(a0h, b1l, acc[0][1], 0, 0, 0);
    acc[0][1] = __builtin_amdgcn_mfma_f32_16x16x32_bf16(a0l, b1h, acc[0][1], 0, 0, 0);
    acc[1][0] = __builtin_amdgcn_mfma_f32_16x16x32_bf16(a1h, b0h, acc[1][0], 0, 0, 0);
    acc[1][0] = __builtin_amdgcn_mfma_f32_16x16x32_bf16(a1h, b0l, acc[1][0], 0, 0, 0);
    acc[1][0] = __builtin_amdgcn_mfma_f32_16x16x32_bf16(a1l, b0h, acc[1][0], 0, 0, 0);
    acc[1][1] = __builtin_amdgcn_mfma_f32_16x16x32_bf16(a1h, b1h, acc[1][1], 0, 0, 0);
    acc[1][1] = __builtin_amdgcn_mfma_f32_16x16x32_bf16(a1h, b1l, acc[1][1], 0, 0, 0);
    acc[1][1] = __builtin_amdgcn_mfma_f32_16x16x32_bf16(a1l, b1h, acc[1][1], 0, 0, 0);
  }
}

__device__ __forceinline__ void frag_to_ys(float (*Ys)[132], const floatx4 acc[2][2]) {
  int lane = threadIdx.x & 63;
  int wave = threadIdx.x >> 6;
  int row0 = (wave >> 2) * 32 + (lane >> 4) * 4;
  int col0 = (wave & 3) * 32 + (lane & 15);
  #pragma unroll
  for (int mi = 0; mi < 2; ++mi)
    #pragma unroll
    for (int ni = 0; ni < 2; ++ni)
      #pragma unroll
      for (int r = 0; r < 4; ++r)
        Ys[row0 + mi * 16 + r][col0 + ni * 16] = acc[mi][ni][r];
}

__device__ __forceinline__ void ln_store(const float (*Ys)[132],
    const float* __restrict__ bias, const float* __restrict__ res,
    const float* __restrict__ g, const float* __restrict__ bl,
    float* __restrict__ Y, long row0, int N) {
  int r = threadIdx.x >> 3;
  int seg = (threadIdx.x & 7) * 16;
  long gr = row0 + r;
  float y[16];
  float s = 0.f, s2 = 0.f;
  if (gr < N) {
    #pragma unroll
    for (int q = 0; q < 4; ++q) {
      float4 v  = *(const float4*)&Ys[r][seg + q * 4];
      float4 b4 = *(const float4*)&bias[seg + q * 4];
      float4 rv = *(const float4*)&res[gr * 128 + seg + q * 4];
      float t0 = v.x + b4.x + rv.x;
      float t1 = v.y + b4.y + rv.y;
      float t2 = v.z + b4.z + rv.z;
      float t3 = v.w + b4.w + rv.w;
      y[q*4+0] = t0; y[q*4+1] = t1; y[q*4+2] = t2; y[q*4+3] = t3;
      s  += t0 + t1 + t2 + t3;
      s2 += t0*t0 + t1*t1 + t2*t2 + t3*t3;
    }
  } else {
    #pragma unroll
    for (int q = 0; q < 16; ++q) y[q] = 0.f;
  }
  #pragma unroll
  for (int off = 1; off < 8; off <<= 1) {
    s  += __shfl_xor(s, off);
    s2 += __shfl_xor(s2, off);
  }
  float m   = s * (1.f / 128.f);
  float var = s2 * (1.f / 128.f) - m * m;
  float inv = rsqrtf(var + 1e-5f);
  if (gr < N) {
    #pragma unroll
    for (int q = 0; q < 4; ++q) {
      float4 g4 = *(const float4*)&g[seg + q * 4];
      float4 b4 = *(const float4*)&bl[seg + q * 4];
      float4 o;
      o.x = (y[q*4+0] - m) * inv * g4.x + b4.x;
      o.y = (y[q*4+1] - m) * inv * g4.y + b4.y;
      o.z = (y[q*4+2] - m) * inv * g4.z + b4.z;
      o.w = (y[q*4+3] - m) * inv * g4.w + b4.w;
      *(float4*)&Y[gr * 128 + seg + q * 4] = o;
    }
  }
}

// ---------------- packed-fragment helpers for k_ffn ----------------
// slot(row,ks,g) = (((row>>4)*4 + ks)*4 + g)*16 + (row&15),  k = ks*32 + g*8
template<bool LO>
__device__ __forceinline__ void stage_x_packed(uint4* __restrict__ dst,
    const float* __restrict__ src, long row0, int N) {
  #pragma unroll
  for (int it = 0; it < 2; ++it) {
    int s = it * 512 + threadIdx.x;
    int r16 = s & 15, g = (s >> 4) & 3, ks = (s >> 6) & 3, rb = s >> 8;
    long gr = row0 + rb * 16 + r16;
    uint4 w = make_uint4(0u, 0u, 0u, 0u);
    if (gr < N) {
      const float* p = src + gr * 128 + ks * 32 + g * 8;
      float v[8];
      *(float4*)&v[0] = *(const float4*)p;
      *(float4*)&v[4] = *(const float4*)(p + 4);
      unsigned q[8];
      #pragma unroll
      for (int j = 0; j < 8; ++j) {
        unsigned short h = f2bf(v[j]);
        q[j] = LO ? (unsigned)f2bf(v[j] - bf2f(h)) : (unsigned)h;
      }
      w.x = q[0] | (q[1] << 16);
      w.y = q[2] | (q[3] << 16);
      w.z = q[4] | (q[5] << 16);
      w.w = q[6] | (q[7] << 16);
    }
    dst[s] = w;
  }
}

__device__ __forceinline__ void load_afrags(short8 af[2][4], const uint4* __restrict__ Xp, int wr) {
  int lane = threadIdx.x & 63;
  #pragma unroll
  for (int mi = 0; mi < 2; ++mi)
    #pragma unroll
    for (int ks = 0; ks < 4; ++ks)
      af[mi][ks] = *(const short8*)&Xp[((wr >> 4) + mi) * 256 + ks * 64 + lane];
}

#define MF(a, b, c) __builtin_amdgcn_mfma_f32_16x16x32_bf16(a, b, c, 0, 0, 0)

// ---------------- big kernels ----------------
// round-4 exact: split-bf16 GEMM, plain store
__global__ __launch_bounds__(512) void k_gemm_plain(const float* __restrict__ X,
    const unsigned short* __restrict__ Wh, const unsigned short* __restrict__ Wl,
    float* __restrict__ Y, int N) {
  __shared__ __align__(16) unsigned short XsH[64][136];
  __shared__ __align__(16) unsigned short XsL[64][136];
  __shared__ __align__(16) unsigned short WsH[128][136];
  __shared__ __align__(16) unsigned short WsL[128][136];
  long row0 = (long)blockIdx.x * 64;
  stage_xf32_split(XsH, XsL, X, row0, N);
  stage_w(WsH, Wh, 128);
  stage_w(WsL, Wl, 128);
  __syncthreads();
  floatx4 zero = {0.f, 0.f, 0.f, 0.f};
  floatx4 acc[2][2] = {{zero, zero}, {zero, zero}};
  mfma_64x128_3(XsH, XsL, WsH, WsL, acc);
  int lane = threadIdx.x & 63;
  int wave = threadIdx.x >> 6;
  int rowb = (wave >> 2) * 32 + (lane >> 4) * 4;
  int colb = (wave & 3) * 32 + (lane & 15);
  #pragma unroll
  for (int mi = 0; mi < 2; ++mi)
    #pragma unroll
    for (int ni = 0; ni < 2; ++ni)
      #pragma unroll
      for (int r = 0; r < 4; ++r) {
        long gr = row0 + rowb + mi * 16 + r;
        if (gr < N) Y[gr * 128 + colb + ni * 16] = acc[mi][ni][r];
      }
}

// round-4 exact: split-bf16 GEMM + residual + LN epilogue
__global__ __launch_bounds__(512) void k_gemm_ln(const float* __restrict__ X,
    const unsigned short* __restrict__ Wh, const unsigned short* __restrict__ Wl,
    const float* __restrict__ bias,
    const float* __restrict__ g, const float* __restrict__ bl,
    float* __restrict__ Y, int N) {
  __shared__ __align__(16) unsigned short XsH[64][136];
  __shared__ __align__(16) unsigned short XsL[64][136];
  __shared__ union __align__(16) WY {
    struct { unsigned short h[128][136]; unsigned short l[128][136]; } w;
    float ys[64][132];
  } wy;
  long row0 = (long)blockIdx.x * 64;
  stage_xf32_split(XsH, XsL, X, row0, N);
  stage_w(wy.w.h, Wh, 128);
  stage_w(wy.w.l, Wl, 128);
  __syncthreads();
  floatx4 zero = {0.f, 0.f, 0.f, 0.f};
  floatx4 acc[2][2] = {{zero, zero}, {zero, zero}};
  mfma_64x128_3(XsH, XsL, wy.w.h, wy.w.l, acc);
  __syncthreads();
  frag_to_ys(wy.ys, acc);
  __syncthreads();
  ln_store(wy.ys, bias, X, g, bl, Y, row0, N);
}

// k_ffn v8 = r12's verified kernel with FFN numerics dropped to single-bf16
// (the ONLY change this round): phase A = 16 MFMA (X-hi @ W1-hi), no X-lo/W1-lo.
// Error budget: FFN feeds LN2 (input sigma~1, no amplifier); z-error ~1e-3.
// Z double-buffer + packed-global W + Z packed-LDS exchange all r12-verbatim.
__global__ __launch_bounds__(512) void k_ffn(const float* __restrict__ T1,
    const uint4* __restrict__ W1hp, const float* __restrict__ b1,
    const uint4* __restrict__ W2p, const float* __restrict__ b2,
    const float* __restrict__ gam, const float* __restrict__ bet,
    float* __restrict__ Y, int N) {
  __shared__ __align__(16) uint4 zx[1024];
  __shared__ __align__(16) float ys[64][132];
  uint4* zalt = (uint4*)ys;                     // 16KB of ys = second Z buffer
  long row0 = (long)blockIdx.x * 64;
  int lane = threadIdx.x & 63;
  int wave = threadIdx.x >> 6;
  int wr = (wave >> 2) * 32, wc = (wave & 3) * 32;
  int gq = lane >> 4, r16c = lane & 15;

  // X-hi fragments -> registers (2-barrier prologue)
  stage_x_packed<false>(zx, T1, row0, N);
  __syncthreads();
  short8 afh[2][4];
  load_afrags(afh, zx, wr);
  __syncthreads();                              // afh reads done; zx/zalt -> Z dbuf

  int zb0 = (((wr >> 4) + 0) * 4 + (wc >> 5)) * 4 + (r16c >> 3);
  int zb1 = (((wr >> 4) + 1) * 4 + (wc >> 5)) * 4 + (r16c >> 3);

  // per-wave global fragment bases (packed layout, coalesced across lanes)
  const uint4* p1h = W1hp + (wc >> 4) * 256;
  const uint4* p2b = W2p  + (wc >> 4) * 256;

  floatx4 zero = {0.f, 0.f, 0.f, 0.f};
  floatx4 acc2[2][2] = {{zero, zero}, {zero, zero}};

  for (int fc = 0; fc < 16; ++fc) {
    uint4* zb = (fc & 1) ? zalt : zx;
    unsigned short* Zu = (unsigned short*)zb;
    // phase A: Zc = relu(X @ W1c^T + b1c)  (single bf16, 16 MFMA)
    const uint4* ph = p1h + fc * 2048;
    floatx4 acc1[2][2] = {{zero, zero}, {zero, zero}};
    #pragma unroll
    for (int ks = 0; ks < 4; ++ks) {
      int nb = ks * 64 + lane;
      short8 bh0 = *(const short8*)&ph[nb];
      short8 bh1 = *(const short8*)&ph[nb + 256];
      acc1[0][0] = MF(afh[0][ks], bh0, acc1[0][0]);
      acc1[0][1] = MF(afh[0][ks], bh1, acc1[0][1]);
      acc1[1][0] = MF(afh[1][ks], bh0, acc1[1][0]);
      acc1[1][1] = MF(afh[1][ks], bh1, acc1[1][1]);
    }
    float bv0 = b1[fc * 128 + wc + r16c];
    float bv1 = b1[fc * 128 + wc + 16 + r16c];
    #pragma unroll
    for (int mi = 0; mi < 2; ++mi) {
      int zbi = mi ? zb1 : zb0;
      #pragma unroll
      for (int ni = 0; ni < 2; ++ni) {
        float bv = ni ? bv1 : bv0;
        #pragma unroll
        for (int r = 0; r < 4; ++r) {
          float z = fmaxf(acc1[mi][ni][r] + bv, 0.f);
          Zu[(zbi + 2 * ni) * 128 + (4 * gq + r) * 8 + (r16c & 7)] = f2bf(z);
        }
      }
    }
    __syncthreads();                            // Z(fc) visible (only barrier this chunk)
    // phase B: acc2 += Zc @ W2c^T  (single bf16; W2 frags from global)
    const uint4* p2 = p2b + fc * 2048;
    #pragma unroll
    for (int ks = 0; ks < 4; ++ks) {
      int za = (wr >> 4) * 256 + ks * 64 + lane;
      short8 a0 = *(const short8*)&zb[za];
      short8 a1 = *(const short8*)&zb[za + 256];
      int nb = ks * 64 + lane;
      short8 b0  = *(const short8*)&p2[nb];
      short8 b1f = *(const short8*)&p2[nb + 256];
      acc2[0][0] = MF(a0, b0,  acc2[0][0]);
      acc2[0][1] = MF(a0, b1f, acc2[0][1]);
      acc2[1][0] = MF(a1, b0,  acc2[1][0]);
      acc2[1][1] = MF(a1, b1f, acc2[1][1]);
    }
    // no second barrier: next phase A writes the OTHER buffer
  }
  __syncthreads();                              // last phase-B reads done before ys overlay
  frag_to_ys(ys, acc2);
  __syncthreads();
  ln_store(ys, b2, T1, gam, bet, Y, row0, N);
}

// ---------------- launcher ----------------
extern "C" void kernel_launch(void* const* d_in, const int* in_sizes, int n_in,
                              void* d_out, int out_size, void* d_ws, size_t ws_size,
                              hipStream_t stream) {
  const int N = in_sizes[0] / 128;
  const int E = in_sizes[1] / 2;
  const float* x     = (const float*)d_in[0];
  const int*   ei    = (const int*)d_in[1];
  const float* gcn_w = (const float*)d_in[2];
  const float* gcn_b = (const float*)d_in[3];
  const float* in_w  = (const float*)d_in[4];
  const float* in_b  = (const float*)d_in[5];
  const float* out_w = (const float*)d_in[6];
  const float* out_b = (const float*)d_in[7];
  const float* ln1_g = (const float*)d_in[8];
  const float* ln1_b = (const float*)d_in[9];
  const float* ff1_w = (const float*)d_in[10];
  const float* ff1_b = (const float*)d_in[11];
  const float* ff2_w = (const float*)d_in[12];
  const float* ff2_b = (const float*)d_in[13];
  const float* ln2_g = (const float*)d_in[14];
  const float* ln2_b = (const float*)d_in[15];
  float* out = (float*)d_out;

  char* w = (char*)d_ws;
  auto alloc = [&](size_t bytes) { char* p = w; w += (bytes + 255) & ~(size_t)255; return p; };
  float* deg  = (float*)alloc((size_t)N * 4);
  float* dinv = (float*)alloc((size_t)N * 4);
  int*   off  = (int*)alloc((size_t)(N + 1) * 4);
  int*   cur  = (int*)alloc((size_t)N * 4);
  int*   srcs = (int*)alloc((size_t)E * 4);
  float* h0   = (float*)alloc((size_t)N * 128 * 4);   // reused as B2
  float* Hb   = (float*)alloc((size_t)N * 128 * 4);
  float* B1   = (float*)alloc((size_t)N * 128 * 4);
  float* Wc   = (float*)alloc(2 * 16384 * 4);
  float* bc   = (float*)alloc(2 * 128 * 4);
  unsigned short* gcnh = (unsigned short*)alloc(16384 * 2);
  unsigned short* gcnl = (unsigned short*)alloc(16384 * 2);
  unsigned short* Wch  = (unsigned short*)alloc(2 * 16384 * 2);
  unsigned short* Wcl  = (unsigned short*)alloc(2 * 16384 * 2);
  unsigned short* ff1hp = (unsigned short*)alloc(2 * 262144 * 2);  // packed fragment order
  unsigned short* ff2p  = (unsigned short*)alloc(2 * 262144 * 2);
  float* B2 = h0;

  const int gN = (N + 255) / 256;
  const int gT = (N + 63) / 64;
  const int gV = (int)(((long)N * 32 + 255) / 256);
  const int nslots = 32768;                 // 2048*128/8 per FFN layer

  // CSR build
  k_fill1<<<gN, 256, 0, stream>>>(deg, N);
  k_edge_deg<<<(E + 255) / 256, 256, 0, stream>>>(ei, deg, E);
  k_rsqrt<<<gN, 256, 0, stream>>>(dinv, deg, N);
  k_scan<<<1, 1024, 0, stream>>>(deg, off, N);
  hipMemcpyAsync(cur, off, (size_t)N * 4, hipMemcpyDeviceToDevice, stream);
  k_scatter<<<(E + 255) / 256, 256, 0, stream>>>(ei, cur, srcs, E);

  // weight prep (r12-verbatim except: ff1 packed hi-only)
  k_combine<<<2, 256, 0, stream>>>(in_w, in_b, out_w, out_b, Wc, bc);
  k_f32bf16_split<<<(16384 + 255) / 256, 256, 0, stream>>>(gcn_w, gcnh, gcnl, 16384);
  k_f32bf16_split<<<(32768 + 255) / 256, 256, 0, stream>>>(Wc, Wch, Wcl, 32768);
  for (int l = 0; l < 2; ++l) {
    k_pack_rows<<<(nslots + 255) / 256, 256, 0, stream>>>(
        ff1_w + (long)l * 262144, ff1hp + (long)l * 262144, (unsigned short*)nullptr, nslots);
    k_pack_cols<<<(nslots + 255) / 256, 256, 0, stream>>>(
        ff2_w + (long)l * 262144, ff2p + (long)l * 262144, 2048, nslots);
  }

  // GCN
  k_gemm_plain<<<gT, 512, 0, stream>>>(x, gcnh, gcnl, h0, N);
  k_gcn_agg<<<(N + 3) / 4, 256, 0, stream>>>(off, srcs, dinv, h0, gcn_b, Hb, N);

  for (int l = 0; l < 2; ++l) {
    const float* src = (l == 0) ? Hb : B2;
    k_gemm_ln<<<gT, 512, 0, stream>>>(src, Wch + l * 16384, Wcl + l * 16384, bc + l * 128,
                                      ln1_g + l * 128, ln1_b + l * 128, B1, N);
    k_ffn<<<gT, 512, 0, stream>>>(B1,
                                  (const uint4*)(ff1hp + (long)l * 262144),
                                  ff1_b + l * 2048,
                                  (const uint4*)(ff2p + (long)l * 262144),
                                  ff2_b + l * 128,
                                  ln2_g + l * 128, ln2_b + l * 128, B2, N);
  }

  k_final<<<gV, 256, 0, stream>>>(B2, Hb, out, N);
}

// Round 14
// 520.961 us; speedup vs baseline: 2.4758x; 1.1907x over previous
//
#include <hip/hip_runtime.h>

using short8  = __attribute__((ext_vector_type(8))) short;
using floatx4 = __attribute__((ext_vector_type(4))) float;

__device__ __forceinline__ unsigned short f2bf(float x) {
  unsigned int u = __float_as_uint(x);
  return (unsigned short)((u + 0x7FFFu + ((u >> 16) & 1u)) >> 16);
}
__device__ __forceinline__ float bf2f(unsigned short h) {
  return __uint_as_float(((unsigned int)h) << 16);
}

// ---------------- small elementwise / setup kernels ----------------
__global__ void k_fill1(float* __restrict__ p, int n) {
  int i = blockIdx.x * 256 + threadIdx.x;
  if (i < n) p[i] = 1.0f;
}

__global__ void k_edge_deg(const int* __restrict__ ei, float* __restrict__ deg, int E) {
  int e = blockIdx.x * 256 + threadIdx.x;
  if (e < E) atomicAdd(&deg[ei[E + e]], 1.0f);
}

__global__ void k_rsqrt(float* __restrict__ dinv, const float* __restrict__ deg, int n) {
  int i = blockIdx.x * 256 + threadIdx.x;
  if (i < n) dinv[i] = rsqrtf(deg[i]);
}

// hi = bf16(x); lo = bf16(x - hi)
__global__ void k_f32bf16_split(const float* __restrict__ src, unsigned short* __restrict__ hi,
                                unsigned short* __restrict__ lo, int n) {
  int i = blockIdx.x * 256 + threadIdx.x;
  if (i < n) {
    float x = src[i];
    unsigned short h = f2bf(x);
    hi[i] = h;
    lo[i] = f2bf(x - bf2f(h));
  }
}

// ---------------- packed-fragment weight prep (global fragment order) ----------------
// slot within 128x128 chunk: rem = c16*256 + ks*64 + g*16 + r16  (uint4 slots, 8 bf16 each)
//   covers out-feature = c16*16 + r16, k = ks*32 + g*8
// k_pack_rows: W[OUT][128], chunks along OUT (W1: OUT=2048)
__global__ void k_pack_rows(const float* __restrict__ W, unsigned short* __restrict__ hi,
                            unsigned short* __restrict__ lo, int nslots) {
  int s = blockIdx.x * 256 + threadIdx.x;
  if (s >= nslots) return;
  int chunk = s >> 11, rem = s & 2047;
  int c16 = rem >> 8, ks = (rem >> 6) & 3, g = (rem >> 4) & 3, r16 = rem & 15;
  int out = chunk * 128 + c16 * 16 + r16;
  int k   = ks * 32 + g * 8;
  const float* p = W + (long)out * 128 + k;
  float v[8];
  *(float4*)&v[0] = *(const float4*)p;
  *(float4*)&v[4] = *(const float4*)(p + 4);
  unsigned h[8], l[8];
  #pragma unroll
  for (int j = 0; j < 8; ++j) {
    unsigned short hh = f2bf(v[j]);
    h[j] = hh;
    l[j] = f2bf(v[j] - bf2f(hh));
  }
  uint4 wh = make_uint4(h[0] | (h[1] << 16), h[2] | (h[3] << 16),
                        h[4] | (h[5] << 16), h[6] | (h[7] << 16));
  *(uint4*)&hi[(long)s * 8] = wh;
  if (lo) {
    uint4 wl = make_uint4(l[0] | (l[1] << 16), l[2] | (l[3] << 16),
                          l[4] | (l[5] << 16), l[6] | (l[7] << 16));
    *(uint4*)&lo[(long)s * 8] = wl;
  }
}

// k_pack_cols: W[128][K], chunks along K (W2: K=2048), hi only
__global__ void k_pack_cols(const float* __restrict__ W, unsigned short* __restrict__ hi,
                            int K, int nslots) {
  int s = blockIdx.x * 256 + threadIdx.x;
  if (s >= nslots) return;
  int chunk = s >> 11, rem = s & 2047;
  int c16 = rem >> 8, ks = (rem >> 6) & 3, g = (rem >> 4) & 3, r16 = rem & 15;
  int out = c16 * 16 + r16;
  int k   = chunk * 128 + ks * 32 + g * 8;
  const float* p = W + (long)out * K + k;
  float v[8];
  *(float4*)&v[0] = *(const float4*)p;
  *(float4*)&v[4] = *(const float4*)(p + 4);
  unsigned h[8];
  #pragma unroll
  for (int j = 0; j < 8; ++j) h[j] = f2bf(v[j]);
  uint4 wh = make_uint4(h[0] | (h[1] << 16), h[2] | (h[3] << 16),
                        h[4] | (h[5] << 16), h[6] | (h[7] << 16));
  *(uint4*)&hi[(long)s * 8] = wh;
}

// ---------------- CSR build: scan + scatter ----------------
__global__ __launch_bounds__(1024) void k_scan(const float* __restrict__ deg,
                                               int* __restrict__ off, int N) {
  __shared__ int wsum[16];
  __shared__ int carry;
  if (threadIdx.x == 0) carry = 0;
  int lane = threadIdx.x & 63, wv = threadIdx.x >> 6;
  for (int base = 0; base < N; base += 1024) {
    int i = base + threadIdx.x;
    int c = (i < N) ? ((int)deg[i] - 1) : 0;
    int s = c;
    #pragma unroll
    for (int o = 1; o < 64; o <<= 1) {
      int t = __shfl_up(s, o);
      if (lane >= o) s += t;
    }
    __syncthreads();
    if (lane == 63) wsum[wv] = s;
    __syncthreads();
    int wpre = 0, total = 0;
    #pragma unroll
    for (int w = 0; w < 16; ++w) {
      int v = wsum[w];
      if (w < wv) wpre += v;
      total += v;
    }
    if (i < N) off[i] = carry + wpre + s - c;
    __syncthreads();
    if (threadIdx.x == 0) carry += total;
  }
  __syncthreads();
  if (threadIdx.x == 0) off[N] = carry;
}

__global__ void k_scatter(const int* __restrict__ ei, int* __restrict__ cur,
                          int* __restrict__ srcs, int E) {
  int e = blockIdx.x * 256 + threadIdx.x;
  if (e < E) {
    int r = ei[e], c = ei[E + e];
    int p = atomicAdd(&cur[c], 1);
    srcs[p] = r;
  }
}

__global__ __launch_bounds__(256) void k_gcn_agg(const int* __restrict__ off,
    const int* __restrict__ srcs, const float* __restrict__ dinv,
    const float* __restrict__ h0, const float* __restrict__ gcn_b,
    float* __restrict__ Hb, int N) {
  int node = blockIdx.x * 4 + (threadIdx.x >> 6);
  if (node >= N) return;
  int c2 = (threadIdx.x & 63) * 2;
  float dc = dinv[node];
  float a0 = 0.f, a1 = 0.f;
  int j = off[node], end = off[node + 1];
  for (; j + 1 < end; j += 2) {
    int s0 = srcs[j], s1 = srcs[j + 1];
    float w0 = dinv[s0] * dc, w1 = dinv[s1] * dc;
    float2 h0v = *(const float2*)&h0[(long)s0 * 128 + c2];
    float2 h1v = *(const float2*)&h0[(long)s1 * 128 + c2];
    a0 += w0 * h0v.x + w1 * h1v.x;
    a1 += w0 * h0v.y + w1 * h1v.y;
  }
  if (j < end) {
    int s0 = srcs[j];
    float w0 = dinv[s0] * dc;
    float2 hv = *(const float2*)&h0[(long)s0 * 128 + c2];
    a0 += w0 * hv.x;
    a1 += w0 * hv.y;
  }
  float2 hv = *(const float2*)&h0[(long)node * 128 + c2];
  float2 b  = *(const float2*)&gcn_b[c2];
  float v0 = a0 + dc * dc * hv.x + b.x;
  float v1 = a1 + dc * dc * hv.y + b.y;
  *(float2*)&Hb[(long)node * 128 + c2] = make_float2(fmaxf(v0, 0.f), fmaxf(v1, 0.f));
}

__global__ void k_final(const float* __restrict__ T, const float* __restrict__ Hb,
                        float* __restrict__ out, int N) {
  long i = (long)blockIdx.x * 256 + threadIdx.x;
  if (i >= (long)N * 32) return;
  long off = i * 4;
  float4 t = *(const float4*)&T[off];
  float4 h = *(const float4*)&Hb[off];
  float4 o;
  o.x = fmaxf(t.x + h.x, 0.f);
  o.y = fmaxf(t.y + h.y, 0.f);
  o.z = fmaxf(t.z + h.z, 0.f);
  o.w = fmaxf(t.w + h.w, 0.f);
  *(float4*)&out[off] = o;
}

// ---- parallel combine: Wc[l] = out_w[l] @ Wv[l] ----
// 32 blocks x 256 threads; thread (i, j4) computes Wc[i][j4..j4+3].
// Same fp32 op order as the old k_combine (k ascending) -> bit-identical.
__global__ __launch_bounds__(256) void k_combine2(const float* __restrict__ in_w,
    const float* __restrict__ out_w, float* __restrict__ Wc) {
  int l = blockIdx.x >> 4, b = blockIdx.x & 15;
  const float* Wv = in_w + (long)l * 384 * 128 + 256 * 128;
  const float* Wo = out_w + (long)l * 128 * 128;
  int i  = b * 8 + (threadIdx.x >> 5);
  int j4 = (threadIdx.x & 31) * 4;
  float4 acc = make_float4(0.f, 0.f, 0.f, 0.f);
  for (int k = 0; k < 128; ++k) {
    float w = Wo[i * 128 + k];
    float4 v = *(const float4*)&Wv[k * 128 + j4];
    acc.x += w * v.x;
    acc.y += w * v.y;
    acc.z += w * v.z;
    acc.w += w * v.w;
  }
  *(float4*)&Wc[(long)l * 16384 + i * 128 + j4] = acc;
}

// bc[l] = out_w[l] @ bv[l] + out_b[l]
__global__ void k_combine_b(const float* __restrict__ in_b, const float* __restrict__ out_w,
                            const float* __restrict__ out_b, float* __restrict__ bc) {
  int l = blockIdx.x;
  const float* bv = in_b + l * 384 + 256;
  const float* Wo = out_w + (long)l * 128 * 128;
  int i = threadIdx.x;
  if (i < 128) {
    float acc = out_b[l * 128 + i];
    for (int k = 0; k < 128; ++k) acc += Wo[i * 128 + k] * bv[k];
    bc[l * 128 + i] = acc;
  }
}

// ---------------- round-4 MFMA GEMM helpers (verified) ----------------
__device__ __forceinline__ void stage_xf32_split(unsigned short (*dh)[136], unsigned short (*dl)[136],
                                                 const float* __restrict__ src, long row0, int N) {
  #pragma unroll
  for (int it = 0; it < 2; ++it) {
    int i = it * 512 + threadIdx.x;
    int r = i >> 4, c8 = (i & 15) * 8;
    long gr = row0 + r;
    uint4 wh = make_uint4(0u, 0u, 0u, 0u);
    uint4 wl = make_uint4(0u, 0u, 0u, 0u);
    if (gr < N) {
      const float* p = src + gr * 128 + c8;
      float v[8];
      *(float4*)&v[0] = *(const float4*)p;
      *(float4*)&v[4] = *(const float4*)(p + 4);
      unsigned short h[8], l[8];
      #pragma unroll
      for (int j = 0; j < 8; ++j) {
        h[j] = f2bf(v[j]);
        l[j] = f2bf(v[j] - bf2f(h[j]));
      }
      wh.x = (unsigned)h[0] | ((unsigned)h[1] << 16);
      wh.y = (unsigned)h[2] | ((unsigned)h[3] << 16);
      wh.z = (unsigned)h[4] | ((unsigned)h[5] << 16);
      wh.w = (unsigned)h[6] | ((unsigned)h[7] << 16);
      wl.x = (unsigned)l[0] | ((unsigned)l[1] << 16);
      wl.y = (unsigned)l[2] | ((unsigned)l[3] << 16);
      wl.z = (unsigned)l[4] | ((unsigned)l[5] << 16);
      wl.w = (unsigned)l[6] | ((unsigned)l[7] << 16);
    }
    *(uint4*)&dh[r][c8] = wh;
    *(uint4*)&dl[r][c8] = wl;
  }
}

__device__ __forceinline__ void stage_w(unsigned short (*dst)[136], const unsigned short* __restrict__ src,
                                        int ld) {
  #pragma unroll
  for (int it = 0; it < 4; ++it) {
    int i = it * 512 + threadIdx.x;
    int r = i >> 4, c8 = (i & 15) * 8;
    *(uint4*)&dst[r][c8] = *(const uint4*)&src[(long)r * ld + c8];
  }
}

__device__ __forceinline__ void mfma_64x128_3(const unsigned short (*Ah)[136], const unsigned short (*Al)[136],
                                              const unsigned short (*Bh)[136], const unsigned short (*Bl)[136],
                                              floatx4 acc[2][2]) {
  int lane = threadIdx.x & 63;
  int wave = threadIdx.x >> 6;
  int wr = (wave >> 2) * 32;
  int wc = (wave & 3) * 32;
  int r16 = lane & 15;
  int k8 = (lane >> 4) * 8;
  #pragma unroll
  for (int ks = 0; ks < 4; ++ks) {
    int k0 = ks * 32 + k8;
    short8 a0h = *(const short8*)&Ah[wr + r16][k0];
    short8 a1h = *(const short8*)&Ah[wr + 16 + r16][k0];
    short8 a0l = *(const short8*)&Al[wr + r16][k0];
    short8 a1l = *(const short8*)&Al[wr + 16 + r16][k0];
    short8 b0h = *(const short8*)&Bh[wc + r16][k0];
    short8 b1h = *(const short8*)&Bh[wc + 16 + r16][k0];
    short8 b0l = *(const short8*)&Bl[wc + r16][k0];
    short8 b1l = *(const short8*)&Bl[wc + 16 + r16][k0];
    acc[0][0] = __builtin_amdgcn_mfma_f32_16x16x32_bf16(a0h, b0h, acc[0][0], 0, 0, 0);
    acc[0][0] = __builtin_amdgcn_mfma_f32_16x16x32_bf16(a0h, b0l, acc[0][0], 0, 0, 0);
    acc[0][0] = __builtin_amdgcn_mfma_f32_16x16x32_bf16(a0l, b0h, acc[0][0], 0, 0, 0);
    acc[0][1] = __builtin_amdgcn_mfma_f32_16x16x32_bf16(a0h, b1h, acc[0][1], 0, 0, 0);
    acc[0][1] = __builtin_amdgcn_mfma_f32_16x16x32_bf16(a0h, b1l, acc[0][1], 0, 0, 0);
    acc[0][1] = __builtin_amdgcn_mfma_f32_16x16x32_bf16(a0l, b1h, acc[0][1], 0, 0, 0);
    acc[1][0] = __builtin_amdgcn_mfma_f32_16x16x32_bf16(a1h, b0h, acc[1][0], 0, 0, 0);
    acc[1][0] = __builtin_amdgcn_mfma_f32_16x16x32_bf16(a1h, b0l, acc[1][0], 0, 0, 0);
    acc[1][0] = __builtin_amdgcn_mfma_f32_16x16x32_bf16(a1l, b0h, acc[1][0], 0, 0, 0);
    acc[1][1] = __builtin_amdgcn_mfma_f32_16x16x32_bf16(a1h, b1h, acc[1][1], 0, 0, 0);
    acc[1][1] = __builtin_amdgcn_mfma_f32_16x16x32_bf16(a1h, b1l, acc[1][1], 0, 0, 0);
    acc[1][1] = __builtin_amdgcn_mfma_f32_16x16x32_bf16(a1l, b1h, acc[1][1], 0, 0, 0);
  }
}

__device__ __forceinline__ void frag_to_ys(float (*Ys)[132], const floatx4 acc[2][2]) {
  int lane = threadIdx.x & 63;
  int wave = threadIdx.x >> 6;
  int row0 = (wave >> 2) * 32 + (lane >> 4) * 4;
  int col0 = (wave & 3) * 32 + (lane & 15);
  #pragma unroll
  for (int mi = 0; mi < 2; ++mi)
    #pragma unroll
    for (int ni = 0; ni < 2; ++ni)
      #pragma unroll
      for (int r = 0; r < 4; ++r)
        Ys[row0 + mi * 16 + r][col0 + ni * 16] = acc[mi][ni][r];
}

__device__ __forceinline__ void ln_store(const float (*Ys)[132],
    const float* __restrict__ bias, const float* __restrict__ res,
    const float* __restrict__ g, const float* __restrict__ bl,
    float* __restrict__ Y, long row0, int N) {
  int r = threadIdx.x >> 3;
  int seg = (threadIdx.x & 7) * 16;
  long gr = row0 + r;
  float y[16];
  float s = 0.f, s2 = 0.f;
  if (gr < N) {
    #pragma unroll
    for (int q = 0; q < 4; ++q) {
      float4 v  = *(const float4*)&Ys[r][seg + q * 4];
      float4 b4 = *(const float4*)&bias[seg + q * 4];
      float4 rv = *(const float4*)&res[gr * 128 + seg + q * 4];
      float t0 = v.x + b4.x + rv.x;
      float t1 = v.y + b4.y + rv.y;
      float t2 = v.z + b4.z + rv.z;
      float t3 = v.w + b4.w + rv.w;
      y[q*4+0] = t0; y[q*4+1] = t1; y[q*4+2] = t2; y[q*4+3] = t3;
      s  += t0 + t1 + t2 + t3;
      s2 += t0*t0 + t1*t1 + t2*t2 + t3*t3;
    }
  } else {
    #pragma unroll
    for (int q = 0; q < 16; ++q) y[q] = 0.f;
  }
  #pragma unroll
  for (int off = 1; off < 8; off <<= 1) {
    s  += __shfl_xor(s, off);
    s2 += __shfl_xor(s2, off);
  }
  float m   = s * (1.f / 128.f);
  float var = s2 * (1.f / 128.f) - m * m;
  float inv = rsqrtf(var + 1e-5f);
  if (gr < N) {
    #pragma unroll
    for (int q = 0; q < 4; ++q) {
      float4 g4 = *(const float4*)&g[seg + q * 4];
      float4 b4 = *(const float4*)&bl[seg + q * 4];
      float4 o;
      o.x = (y[q*4+0] - m) * inv * g4.x + b4.x;
      o.y = (y[q*4+1] - m) * inv * g4.y + b4.y;
      o.z = (y[q*4+2] - m) * inv * g4.z + b4.z;
      o.w = (y[q*4+3] - m) * inv * g4.w + b4.w;
      *(float4*)&Y[gr * 128 + seg + q * 4] = o;
    }
  }
}

// ---------------- packed-fragment helpers for k_ffn ----------------
// slot(row,ks,g) = (((row>>4)*4 + ks)*4 + g)*16 + (row&15),  k = ks*32 + g*8
template<bool LO>
__device__ __forceinline__ void stage_x_packed(uint4* __restrict__ dst,
    const float* __restrict__ src, long row0, int N) {
  #pragma unroll
  for (int it = 0; it < 2; ++it) {
    int s = it * 512 + threadIdx.x;
    int r16 = s & 15, g = (s >> 4) & 3, ks = (s >> 6) & 3, rb = s >> 8;
    long gr = row0 + rb * 16 + r16;
    uint4 w = make_uint4(0u, 0u, 0u, 0u);
    if (gr < N) {
      const float* p = src + gr * 128 + ks * 32 + g * 8;
      float v[8];
      *(float4*)&v[0] = *(const float4*)p;
      *(float4*)&v[4] = *(const float4*)(p + 4);
      unsigned q[8];
      #pragma unroll
      for (int j = 0; j < 8; ++j) {
        unsigned short h = f2bf(v[j]);
        q[j] = LO ? (unsigned)f2bf(v[j] - bf2f(h)) : (unsigned)h;
      }
      w.x = q[0] | (q[1] << 16);
      w.y = q[2] | (q[3] << 16);
      w.z = q[4] | (q[5] << 16);
      w.w = q[6] | (q[7] << 16);
    }
    dst[s] = w;
  }
}

__device__ __forceinline__ void load_afrags(short8 af[2][4], const uint4* __restrict__ Xp, int wr) {
  int lane = threadIdx.x & 63;
  #pragma unroll
  for (int mi = 0; mi < 2; ++mi)
    #pragma unroll
    for (int ks = 0; ks < 4; ++ks)
      af[mi][ks] = *(const short8*)&Xp[((wr >> 4) + mi) * 256 + ks * 64 + lane];
}

#define MF(a, b, c) __builtin_amdgcn_mfma_f32_16x16x32_bf16(a, b, c, 0, 0, 0)

// ---------------- big kernels ----------------
// round-4 exact: split-bf16 GEMM, plain store
__global__ __launch_bounds__(512) void k_gemm_plain(const float* __restrict__ X,
    const unsigned short* __restrict__ Wh, const unsigned short* __restrict__ Wl,
    float* __restrict__ Y, int N) {
  __shared__ __align__(16) unsigned short XsH[64][136];
  __shared__ __align__(16) unsigned short XsL[64][136];
  __shared__ __align__(16) unsigned short WsH[128][136];
  __shared__ __align__(16) unsigned short WsL[128][136];
  long row0 = (long)blockIdx.x * 64;
  stage_xf32_split(XsH, XsL, X, row0, N);
  stage_w(WsH, Wh, 128);
  stage_w(WsL, Wl, 128);
  __syncthreads();
  floatx4 zero = {0.f, 0.f, 0.f, 0.f};
  floatx4 acc[2][2] = {{zero, zero}, {zero, zero}};
  mfma_64x128_3(XsH, XsL, WsH, WsL, acc);
  int lane = threadIdx.x & 63;
  int wave = threadIdx.x >> 6;
  int rowb = (wave >> 2) * 32 + (lane >> 4) * 4;
  int colb = (wave & 3) * 32 + (lane & 15);
  #pragma unroll
  for (int mi = 0; mi < 2; ++mi)
    #pragma unroll
    for (int ni = 0; ni < 2; ++ni)
      #pragma unroll
      for (int r = 0; r < 4; ++r) {
        long gr = row0 + rowb + mi * 16 + r;
        if (gr < N) Y[gr * 128 + colb + ni * 16] = acc[mi][ni][r];
      }
}

// round-4 exact: split-bf16 GEMM + residual + LN epilogue
__global__ __launch_bounds__(512) void k_gemm_ln(const float* __restrict__ X,
    const unsigned short* __restrict__ Wh, const unsigned short* __restrict__ Wl,
    const float* __restrict__ bias,
    const float* __restrict__ g, const float* __restrict__ bl,
    float* __restrict__ Y, int N) {
  __shared__ __align__(16) unsigned short XsH[64][136];
  __shared__ __align__(16) unsigned short XsL[64][136];
  __shared__ union __align__(16) WY {
    struct { unsigned short h[128][136]; unsigned short l[128][136]; } w;
    float ys[64][132];
  } wy;
  long row0 = (long)blockIdx.x * 64;
  stage_xf32_split(XsH, XsL, X, row0, N);
  stage_w(wy.w.h, Wh, 128);
  stage_w(wy.w.l, Wl, 128);
  __syncthreads();
  floatx4 zero = {0.f, 0.f, 0.f, 0.f};
  floatx4 acc[2][2] = {{zero, zero}, {zero, zero}};
  mfma_64x128_3(XsH, XsL, wy.w.h, wy.w.l, acc);
  __syncthreads();
  frag_to_ys(wy.ys, acc);
  __syncthreads();
  ln_store(wy.ys, bias, X, g, bl, Y, row0, N);
}

// k_ffn v8 (r13-verified): single-bf16 FFN, X frags in regs, packed-global W,
// Z double-buffered across zx and the ys region -> 1 barrier/chunk.
__global__ __launch_bounds__(512) void k_ffn(const float* __restrict__ T1,
    const uint4* __restrict__ W1hp, const float* __restrict__ b1,
    const uint4* __restrict__ W2p, const float* __restrict__ b2,
    const float* __restrict__ gam, const float* __restrict__ bet,
    float* __restrict__ Y, int N) {
  __shared__ __align__(16) uint4 zx[1024];
  __shared__ __align__(16) float ys[64][132];
  uint4* zalt = (uint4*)ys;                     // 16KB of ys = second Z buffer
  long row0 = (long)blockIdx.x * 64;
  int lane = threadIdx.x & 63;
  int wave = threadIdx.x >> 6;
  int wr = (wave >> 2) * 32, wc = (wave & 3) * 32;
  int gq = lane >> 4, r16c = lane & 15;

  // X-hi fragments -> registers (2-barrier prologue)
  stage_x_packed<false>(zx, T1, row0, N);
  __syncthreads();
  short8 afh[2][4];
  load_afrags(afh, zx, wr);
  __syncthreads();                              // afh reads done; zx/zalt -> Z dbuf

  int zb0 = (((wr >> 4) + 0) * 4 + (wc >> 5)) * 4 + (r16c >> 3);
  int zb1 = (((wr >> 4) + 1) * 4 + (wc >> 5)) * 4 + (r16c >> 3);

  // per-wave global fragment bases (packed layout, coalesced across lanes)
  const uint4* p1h = W1hp + (wc >> 4) * 256;
  const uint4* p2b = W2p  + (wc >> 4) * 256;

  floatx4 zero = {0.f, 0.f, 0.f, 0.f};
  floatx4 acc2[2][2] = {{zero, zero}, {zero, zero}};

  for (int fc = 0; fc < 16; ++fc) {
    uint4* zb = (fc & 1) ? zalt : zx;
    unsigned short* Zu = (unsigned short*)zb;
    // phase A: Zc = relu(X @ W1c^T + b1c)  (single bf16, 16 MFMA)
    const uint4* ph = p1h + fc * 2048;
    floatx4 acc1[2][2] = {{zero, zero}, {zero, zero}};
    #pragma unroll
    for (int ks = 0; ks < 4; ++ks) {
      int nb = ks * 64 + lane;
      short8 bh0 = *(const short8*)&ph[nb];
      short8 bh1 = *(const short8*)&ph[nb + 256];
      acc1[0][0] = MF(afh[0][ks], bh0, acc1[0][0]);
      acc1[0][1] = MF(afh[0][ks], bh1, acc1[0][1]);
      acc1[1][0] = MF(afh[1][ks], bh0, acc1[1][0]);
      acc1[1][1] = MF(afh[1][ks], bh1, acc1[1][1]);
    }
    float bv0 = b1[fc * 128 + wc + r16c];
    float bv1 = b1[fc * 128 + wc + 16 + r16c];
    #pragma unroll
    for (int mi = 0; mi < 2; ++mi) {
      int zbi = mi ? zb1 : zb0;
      #pragma unroll
      for (int ni = 0; ni < 2; ++ni) {
        float bv = ni ? bv1 : bv0;
        #pragma unroll
        for (int r = 0; r < 4; ++r) {
          float z = fmaxf(acc1[mi][ni][r] + bv, 0.f);
          Zu[(zbi + 2 * ni) * 128 + (4 * gq + r) * 8 + (r16c & 7)] = f2bf(z);
        }
      }
    }
    __syncthreads();                            // Z(fc) visible (only barrier this chunk)
    // phase B: acc2 += Zc @ W2c^T  (single bf16; W2 frags from global)
    const uint4* p2 = p2b + fc * 2048;
    #pragma unroll
    for (int ks = 0; ks < 4; ++ks) {
      int za = (wr >> 4) * 256 + ks * 64 + lane;
      short8 a0 = *(const short8*)&zb[za];
      short8 a1 = *(const short8*)&zb[za + 256];
      int nb = ks * 64 + lane;
      short8 b0  = *(const short8*)&p2[nb];
      short8 b1f = *(const short8*)&p2[nb + 256];
      acc2[0][0] = MF(a0, b0,  acc2[0][0]);
      acc2[0][1] = MF(a0, b1f, acc2[0][1]);
      acc2[1][0] = MF(a1, b0,  acc2[1][0]);
      acc2[1][1] = MF(a1, b1f, acc2[1][1]);
    }
    // no second barrier: next phase A writes the OTHER buffer
  }
  __syncthreads();                              // last phase-B reads done before ys overlay
  frag_to_ys(ys, acc2);
  __syncthreads();
  ln_store(ys, b2, T1, gam, bet, Y, row0, N);
}

// ---------------- launcher ----------------
extern "C" void kernel_launch(void* const* d_in, const int* in_sizes, int n_in,
                              void* d_out, int out_size, void* d_ws, size_t ws_size,
                              hipStream_t stream) {
  const int N = in_sizes[0] / 128;
  const int E = in_sizes[1] / 2;
  const float* x     = (const float*)d_in[0];
  const int*   ei    = (const int*)d_in[1];
  const float* gcn_w = (const float*)d_in[2];
  const float* gcn_b = (const float*)d_in[3];
  const float* in_w  = (const float*)d_in[4];
  const float* in_b  = (const float*)d_in[5];
  const float* out_w = (const float*)d_in[6];
  const float* out_b = (const float*)d_in[7];
  const float* ln1_g = (const float*)d_in[8];
  const float* ln1_b = (const float*)d_in[9];
  const float* ff1_w = (const float*)d_in[10];
  const float* ff1_b = (const float*)d_in[11];
  const float* ff2_w = (const float*)d_in[12];
  const float* ff2_b = (const float*)d_in[13];
  const float* ln2_g = (const float*)d_in[14];
  const float* ln2_b = (const float*)d_in[15];
  float* out = (float*)d_out;

  char* w = (char*)d_ws;
  auto alloc = [&](size_t bytes) { char* p = w; w += (bytes + 255) & ~(size_t)255; return p; };
  float* deg  = (float*)alloc((size_t)N * 4);
  float* dinv = (float*)alloc((size_t)N * 4);
  int*   off  = (int*)alloc((size_t)(N + 1) * 4);
  int*   cur  = (int*)alloc((size_t)N * 4);
  int*   srcs = (int*)alloc((size_t)E * 4);
  float* h0   = (float*)alloc((size_t)N * 128 * 4);   // reused as B2
  float* Hb   = (float*)alloc((size_t)N * 128 * 4);
  float* B1   = (float*)alloc((size_t)N * 128 * 4);
  float* Wc   = (float*)alloc(2 * 16384 * 4);
  float* bc   = (float*)alloc(2 * 128 * 4);
  unsigned short* gcnh = (unsigned short*)alloc(16384 * 2);
  unsigned short* gcnl = (unsigned short*)alloc(16384 * 2);
  unsigned short* Wch  = (unsigned short*)alloc(2 * 16384 * 2);
  unsigned short* Wcl  = (unsigned short*)alloc(2 * 16384 * 2);
  unsigned short* ff1hp = (unsigned short*)alloc(2 * 262144 * 2);  // packed fragment order
  unsigned short* ff2p  = (unsigned short*)alloc(2 * 262144 * 2);
  float* B2 = h0;

  const int gN = (N + 255) / 256;
  const int gT = (N + 63) / 64;
  const int gV = (int)(((long)N * 32 + 255) / 256);
  const int nslots = 32768;                 // 2048*128/8 per FFN layer

  // CSR build
  k_fill1<<<gN, 256, 0, stream>>>(deg, N);
  k_edge_deg<<<(E + 255) / 256, 256, 0, stream>>>(ei, deg, E);
  k_rsqrt<<<gN, 256, 0, stream>>>(dinv, deg, N);
  k_scan<<<1, 1024, 0, stream>>>(deg, off, N);
  hipMemcpyAsync(cur, off, (size_t)N * 4, hipMemcpyDeviceToDevice, stream);
  k_scatter<<<(E + 255) / 256, 256, 0, stream>>>(ei, cur, srcs, E);

  // weight prep (r13-verbatim except: parallel combine)
  k_combine2<<<32, 256, 0, stream>>>(in_w, out_w, Wc);
  k_combine_b<<<2, 128, 0, stream>>>(in_b, out_w, out_b, bc);
  k_f32bf16_split<<<(16384 + 255) / 256, 256, 0, stream>>>(gcn_w, gcnh, gcnl, 16384);
  k_f32bf16_split<<<(32768 + 255) / 256, 256, 0, stream>>>(Wc, Wch, Wcl, 32768);
  for (int l = 0; l < 2; ++l) {
    k_pack_rows<<<(nslots + 255) / 256, 256, 0, stream>>>(
        ff1_w + (long)l * 262144, ff1hp + (long)l * 262144, (unsigned short*)nullptr, nslots);
    k_pack_cols<<<(nslots + 255) / 256, 256, 0, stream>>>(
        ff2_w + (long)l * 262144, ff2p + (long)l * 262144, 2048, nslots);
  }

  // GCN
  k_gemm_plain<<<gT, 512, 0, stream>>>(x, gcnh, gcnl, h0, N);
  k_gcn_agg<<<(N + 3) / 4, 256, 0, stream>>>(off, srcs, dinv, h0, gcn_b, Hb, N);

  for (int l = 0; l < 2; ++l) {
    const float* src = (l == 0) ? Hb : B2;
    k_gemm_ln<<<gT, 512, 0, stream>>>(src, Wch + l * 16384, Wcl + l * 16384, bc + l * 128,
                                      ln1_g + l * 128, ln1_b + l * 128, B1, N);
    k_ffn<<<gT, 512, 0, stream>>>(B1,
                                  (const uint4*)(ff1hp + (long)l * 262144),
                                  ff1_b + l * 2048,
                                  (const uint4*)(ff2p + (long)l * 262144),
                                  ff2_b + l * 128,
                                  ln2_g + l * 128, ln2_b + l * 128, B2, N);
  }

  k_final<<<gV, 256, 0, stream>>>(B2, Hb, out, N);
}

// Round 15
// 506.271 us; speedup vs baseline: 2.5476x; 1.0290x over previous
//
#include <hip/hip_runtime.h>

using short8  = __attribute__((ext_vector_type(8))) short;
using floatx4 = __attribute__((ext_vector_type(4))) float;

__device__ __forceinline__ unsigned short f2bf(float x) {
  unsigned int u = __float_as_uint(x);
  return (unsigned short)((u + 0x7FFFu + ((u >> 16) & 1u)) >> 16);
}
__device__ __forceinline__ float bf2f(unsigned short h) {
  return __uint_as_float(((unsigned int)h) << 16);
}

// ---------------- small elementwise / setup kernels ----------------
__global__ void k_fill1(float* __restrict__ p, int n) {
  int i = blockIdx.x * 256 + threadIdx.x;
  if (i < n) p[i] = 1.0f;
}

__global__ void k_edge_deg(const int* __restrict__ ei, float* __restrict__ deg, int E) {
  int e = blockIdx.x * 256 + threadIdx.x;
  if (e < E) atomicAdd(&deg[ei[E + e]], 1.0f);
}

__global__ void k_rsqrt(float* __restrict__ dinv, const float* __restrict__ deg, int n) {
  int i = blockIdx.x * 256 + threadIdx.x;
  if (i < n) dinv[i] = rsqrtf(deg[i]);
}

// hi = bf16(x); lo = bf16(x - hi)
__global__ void k_f32bf16_split(const float* __restrict__ src, unsigned short* __restrict__ hi,
                                unsigned short* __restrict__ lo, int n) {
  int i = blockIdx.x * 256 + threadIdx.x;
  if (i < n) {
    float x = src[i];
    unsigned short h = f2bf(x);
    hi[i] = h;
    lo[i] = f2bf(x - bf2f(h));
  }
}

// ---------------- packed-fragment weight prep (global fragment order) ----------------
// slot within 128x128 chunk: rem = c16*256 + ks*64 + g*16 + r16  (uint4 slots, 8 bf16 each)
//   covers out-feature = c16*16 + r16, k = ks*32 + g*8
// k_pack_rows: W[OUT][128], chunks along OUT (W1: OUT=2048)
__global__ void k_pack_rows(const float* __restrict__ W, unsigned short* __restrict__ hi,
                            unsigned short* __restrict__ lo, int nslots) {
  int s = blockIdx.x * 256 + threadIdx.x;
  if (s >= nslots) return;
  int chunk = s >> 11, rem = s & 2047;
  int c16 = rem >> 8, ks = (rem >> 6) & 3, g = (rem >> 4) & 3, r16 = rem & 15;
  int out = chunk * 128 + c16 * 16 + r16;
  int k   = ks * 32 + g * 8;
  const float* p = W + (long)out * 128 + k;
  float v[8];
  *(float4*)&v[0] = *(const float4*)p;
  *(float4*)&v[4] = *(const float4*)(p + 4);
  unsigned h[8], l[8];
  #pragma unroll
  for (int j = 0; j < 8; ++j) {
    unsigned short hh = f2bf(v[j]);
    h[j] = hh;
    l[j] = f2bf(v[j] - bf2f(hh));
  }
  uint4 wh = make_uint4(h[0] | (h[1] << 16), h[2] | (h[3] << 16),
                        h[4] | (h[5] << 16), h[6] | (h[7] << 16));
  *(uint4*)&hi[(long)s * 8] = wh;
  if (lo) {
    uint4 wl = make_uint4(l[0] | (l[1] << 16), l[2] | (l[3] << 16),
                          l[4] | (l[5] << 16), l[6] | (l[7] << 16));
    *(uint4*)&lo[(long)s * 8] = wl;
  }
}

// k_pack_cols: W[128][K], chunks along K (W2: K=2048), hi only
__global__ void k_pack_cols(const float* __restrict__ W, unsigned short* __restrict__ hi,
                            int K, int nslots) {
  int s = blockIdx.x * 256 + threadIdx.x;
  if (s >= nslots) return;
  int chunk = s >> 11, rem = s & 2047;
  int c16 = rem >> 8, ks = (rem >> 6) & 3, g = (rem >> 4) & 3, r16 = rem & 15;
  int out = c16 * 16 + r16;
  int k   = chunk * 128 + ks * 32 + g * 8;
  const float* p = W + (long)out * K + k;
  float v[8];
  *(float4*)&v[0] = *(const float4*)p;
  *(float4*)&v[4] = *(const float4*)(p + 4);
  unsigned h[8];
  #pragma unroll
  for (int j = 0; j < 8; ++j) h[j] = f2bf(v[j]);
  uint4 wh = make_uint4(h[0] | (h[1] << 16), h[2] | (h[3] << 16),
                        h[4] | (h[5] << 16), h[6] | (h[7] << 16));
  *(uint4*)&hi[(long)s * 8] = wh;
}

// ---------------- CSR build: scan + scatter ----------------
__global__ __launch_bounds__(1024) void k_scan(const float* __restrict__ deg,
                                               int* __restrict__ off, int N) {
  __shared__ int wsum[16];
  __shared__ int carry;
  if (threadIdx.x == 0) carry = 0;
  int lane = threadIdx.x & 63, wv = threadIdx.x >> 6;
  for (int base = 0; base < N; base += 1024) {
    int i = base + threadIdx.x;
    int c = (i < N) ? ((int)deg[i] - 1) : 0;
    int s = c;
    #pragma unroll
    for (int o = 1; o < 64; o <<= 1) {
      int t = __shfl_up(s, o);
      if (lane >= o) s += t;
    }
    __syncthreads();
    if (lane == 63) wsum[wv] = s;
    __syncthreads();
    int wpre = 0, total = 0;
    #pragma unroll
    for (int w = 0; w < 16; ++w) {
      int v = wsum[w];
      if (w < wv) wpre += v;
      total += v;
    }
    if (i < N) off[i] = carry + wpre + s - c;
    __syncthreads();
    if (threadIdx.x == 0) carry += total;
  }
  __syncthreads();
  if (threadIdx.x == 0) off[N] = carry;
}

__global__ void k_scatter(const int* __restrict__ ei, int* __restrict__ cur,
                          int* __restrict__ srcs, int E) {
  int e = blockIdx.x * 256 + threadIdx.x;
  if (e < E) {
    int r = ei[e], c = ei[E + e];
    int p = atomicAdd(&cur[c], 1);
    srcs[p] = r;
  }
}

__global__ __launch_bounds__(256) void k_gcn_agg(const int* __restrict__ off,
    const int* __restrict__ srcs, const float* __restrict__ dinv,
    const float* __restrict__ h0, const float* __restrict__ gcn_b,
    float* __restrict__ Hb, int N) {
  int node = blockIdx.x * 4 + (threadIdx.x >> 6);
  if (node >= N) return;
  int c2 = (threadIdx.x & 63) * 2;
  float dc = dinv[node];
  float a0 = 0.f, a1 = 0.f;
  int j = off[node], end = off[node + 1];
  for (; j + 1 < end; j += 2) {
    int s0 = srcs[j], s1 = srcs[j + 1];
    float w0 = dinv[s0] * dc, w1 = dinv[s1] * dc;
    float2 h0v = *(const float2*)&h0[(long)s0 * 128 + c2];
    float2 h1v = *(const float2*)&h0[(long)s1 * 128 + c2];
    a0 += w0 * h0v.x + w1 * h1v.x;
    a1 += w0 * h0v.y + w1 * h1v.y;
  }
  if (j < end) {
    int s0 = srcs[j];
    float w0 = dinv[s0] * dc;
    float2 hv = *(const float2*)&h0[(long)s0 * 128 + c2];
    a0 += w0 * hv.x;
    a1 += w0 * hv.y;
  }
  float2 hv = *(const float2*)&h0[(long)node * 128 + c2];
  float2 b  = *(const float2*)&gcn_b[c2];
  float v0 = a0 + dc * dc * hv.x + b.x;
  float v1 = a1 + dc * dc * hv.y + b.y;
  *(float2*)&Hb[(long)node * 128 + c2] = make_float2(fmaxf(v0, 0.f), fmaxf(v1, 0.f));
}

__global__ void k_final(const float* __restrict__ T, const float* __restrict__ Hb,
                        float* __restrict__ out, int N) {
  long i = (long)blockIdx.x * 256 + threadIdx.x;
  if (i >= (long)N * 32) return;
  long off = i * 4;
  float4 t = *(const float4*)&T[off];
  float4 h = *(const float4*)&Hb[off];
  float4 o;
  o.x = fmaxf(t.x + h.x, 0.f);
  o.y = fmaxf(t.y + h.y, 0.f);
  o.z = fmaxf(t.z + h.z, 0.f);
  o.w = fmaxf(t.w + h.w, 0.f);
  *(float4*)&out[off] = o;
}

// ---- parallel combine: Wc[l] = out_w[l] @ Wv[l] ----
__global__ __launch_bounds__(256) void k_combine2(const float* __restrict__ in_w,
    const float* __restrict__ out_w, float* __restrict__ Wc) {
  int l = blockIdx.x >> 4, b = blockIdx.x & 15;
  const float* Wv = in_w + (long)l * 384 * 128 + 256 * 128;
  const float* Wo = out_w + (long)l * 128 * 128;
  int i  = b * 8 + (threadIdx.x >> 5);
  int j4 = (threadIdx.x & 31) * 4;
  float4 acc = make_float4(0.f, 0.f, 0.f, 0.f);
  for (int k = 0; k < 128; ++k) {
    float w = Wo[i * 128 + k];
    float4 v = *(const float4*)&Wv[k * 128 + j4];
    acc.x += w * v.x;
    acc.y += w * v.y;
    acc.z += w * v.z;
    acc.w += w * v.w;
  }
  *(float4*)&Wc[(long)l * 16384 + i * 128 + j4] = acc;
}

// bc[l] = out_w[l] @ bv[l] + out_b[l]
__global__ void k_combine_b(const float* __restrict__ in_b, const float* __restrict__ out_w,
                            const float* __restrict__ out_b, float* __restrict__ bc) {
  int l = blockIdx.x;
  const float* bv = in_b + l * 384 + 256;
  const float* Wo = out_w + (long)l * 128 * 128;
  int i = threadIdx.x;
  if (i < 128) {
    float acc = out_b[l * 128 + i];
    for (int k = 0; k < 128; ++k) acc += Wo[i * 128 + k] * bv[k];
    bc[l * 128 + i] = acc;
  }
}

// ---------------- round-4 MFMA GEMM helpers (verified) ----------------
__device__ __forceinline__ void stage_xf32_split(unsigned short (*dh)[136], unsigned short (*dl)[136],
                                                 const float* __restrict__ src, long row0, int N) {
  #pragma unroll
  for (int it = 0; it < 2; ++it) {
    int i = it * 512 + threadIdx.x;
    int r = i >> 4, c8 = (i & 15) * 8;
    long gr = row0 + r;
    uint4 wh = make_uint4(0u, 0u, 0u, 0u);
    uint4 wl = make_uint4(0u, 0u, 0u, 0u);
    if (gr < N) {
      const float* p = src + gr * 128 + c8;
      float v[8];
      *(float4*)&v[0] = *(const float4*)p;
      *(float4*)&v[4] = *(const float4*)(p + 4);
      unsigned short h[8], l[8];
      #pragma unroll
      for (int j = 0; j < 8; ++j) {
        h[j] = f2bf(v[j]);
        l[j] = f2bf(v[j] - bf2f(h[j]));
      }
      wh.x = (unsigned)h[0] | ((unsigned)h[1] << 16);
      wh.y = (unsigned)h[2] | ((unsigned)h[3] << 16);
      wh.z = (unsigned)h[4] | ((unsigned)h[5] << 16);
      wh.w = (unsigned)h[6] | ((unsigned)h[7] << 16);
      wl.x = (unsigned)l[0] | ((unsigned)l[1] << 16);
      wl.y = (unsigned)l[2] | ((unsigned)l[3] << 16);
      wl.z = (unsigned)l[4] | ((unsigned)l[5] << 16);
      wl.w = (unsigned)l[6] | ((unsigned)l[7] << 16);
    }
    *(uint4*)&dh[r][c8] = wh;
    *(uint4*)&dl[r][c8] = wl;
  }
}

__device__ __forceinline__ void stage_w(unsigned short (*dst)[136], const unsigned short* __restrict__ src,
                                        int ld) {
  #pragma unroll
  for (int it = 0; it < 4; ++it) {
    int i = it * 512 + threadIdx.x;
    int r = i >> 4, c8 = (i & 15) * 8;
    *(uint4*)&dst[r][c8] = *(const uint4*)&src[(long)r * ld + c8];
  }
}

__device__ __forceinline__ void mfma_64x128_3(const unsigned short (*Ah)[136], const unsigned short (*Al)[136],
                                              const unsigned short (*Bh)[136], const unsigned short (*Bl)[136],
                                              floatx4 acc[2][2]) {
  int lane = threadIdx.x & 63;
  int wave = threadIdx.x >> 6;
  int wr = (wave >> 2) * 32;
  int wc = (wave & 3) * 32;
  int r16 = lane & 15;
  int k8 = (lane >> 4) * 8;
  #pragma unroll
  for (int ks = 0; ks < 4; ++ks) {
    int k0 = ks * 32 + k8;
    short8 a0h = *(const short8*)&Ah[wr + r16][k0];
    short8 a1h = *(const short8*)&Ah[wr + 16 + r16][k0];
    short8 a0l = *(const short8*)&Al[wr + r16][k0];
    short8 a1l = *(const short8*)&Al[wr + 16 + r16][k0];
    short8 b0h = *(const short8*)&Bh[wc + r16][k0];
    short8 b1h = *(const short8*)&Bh[wc + 16 + r16][k0];
    short8 b0l = *(const short8*)&Bl[wc + r16][k0];
    short8 b1l = *(const short8*)&Bl[wc + 16 + r16][k0];
    acc[0][0] = __builtin_amdgcn_mfma_f32_16x16x32_bf16(a0h, b0h, acc[0][0], 0, 0, 0);
    acc[0][0] = __builtin_amdgcn_mfma_f32_16x16x32_bf16(a0h, b0l, acc[0][0], 0, 0, 0);
    acc[0][0] = __builtin_amdgcn_mfma_f32_16x16x32_bf16(a0l, b0h, acc[0][0], 0, 0, 0);
    acc[0][1] = __builtin_amdgcn_mfma_f32_16x16x32_bf16(a0h, b1h, acc[0][1], 0, 0, 0);
    acc[0][1] = __builtin_amdgcn_mfma_f32_16x16x32_bf16(a0h, b1l, acc[0][1], 0, 0, 0);
    acc[0][1] = __builtin_amdgcn_mfma_f32_16x16x32_bf16(a0l, b1h, acc[0][1], 0, 0, 0);
    acc[1][0] = __builtin_amdgcn_mfma_f32_16x16x32_bf16(a1h, b0h, acc[1][0], 0, 0, 0);
    acc[1][0] = __builtin_amdgcn_mfma_f32_16x16x32_bf16(a1h, b0l, acc[1][0], 0, 0, 0);
    acc[1][0] = __builtin_amdgcn_mfma_f32_16x16x32_bf16(a1l, b0h, acc[1][0], 0, 0, 0);
    acc[1][1] = __builtin_amdgcn_mfma_f32_16x16x32_bf16(a1h, b1h, acc[1][1], 0, 0, 0);
    acc[1][1] = __builtin_amdgcn_mfma_f32_16x16x32_bf16(a1h, b1l, acc[1][1], 0, 0, 0);
    acc[1][1] = __builtin_amdgcn_mfma_f32_16x16x32_bf16(a1l, b1h, acc[1][1], 0, 0, 0);
  }
}

__device__ __forceinline__ void frag_to_ys(float (*Ys)[132], const floatx4 acc[2][2]) {
  int lane = threadIdx.x & 63;
  int wave = threadIdx.x >> 6;
  int row0 = (wave >> 2) * 32 + (lane >> 4) * 4;
  int col0 = (wave & 3) * 32 + (lane & 15);
  #pragma unroll
  for (int mi = 0; mi < 2; ++mi)
    #pragma unroll
    for (int ni = 0; ni < 2; ++ni)
      #pragma unroll
      for (int r = 0; r < 4; ++r)
        Ys[row0 + mi * 16 + r][col0 + ni * 16] = acc[mi][ni][r];
}

__device__ __forceinline__ void ln_store(const float (*Ys)[132],
    const float* __restrict__ bias, const float* __restrict__ res,
    const float* __restrict__ g, const float* __restrict__ bl,
    float* __restrict__ Y, long row0, int N) {
  int r = threadIdx.x >> 3;
  int seg = (threadIdx.x & 7) * 16;
  long gr = row0 + r;
  float y[16];
  float s = 0.f, s2 = 0.f;
  if (gr < N) {
    #pragma unroll
    for (int q = 0; q < 4; ++q) {
      float4 v  = *(const float4*)&Ys[r][seg + q * 4];
      float4 b4 = *(const float4*)&bias[seg + q * 4];
      float4 rv = *(const float4*)&res[gr * 128 + seg + q * 4];
      float t0 = v.x + b4.x + rv.x;
      float t1 = v.y + b4.y + rv.y;
      float t2 = v.z + b4.z + rv.z;
      float t3 = v.w + b4.w + rv.w;
      y[q*4+0] = t0; y[q*4+1] = t1; y[q*4+2] = t2; y[q*4+3] = t3;
      s  += t0 + t1 + t2 + t3;
      s2 += t0*t0 + t1*t1 + t2*t2 + t3*t3;
    }
  } else {
    #pragma unroll
    for (int q = 0; q < 16; ++q) y[q] = 0.f;
  }
  #pragma unroll
  for (int off = 1; off < 8; off <<= 1) {
    s  += __shfl_xor(s, off);
    s2 += __shfl_xor(s2, off);
  }
  float m   = s * (1.f / 128.f);
  float var = s2 * (1.f / 128.f) - m * m;
  float inv = rsqrtf(var + 1e-5f);
  if (gr < N) {
    #pragma unroll
    for (int q = 0; q < 4; ++q) {
      float4 g4 = *(const float4*)&g[seg + q * 4];
      float4 b4 = *(const float4*)&bl[seg + q * 4];
      float4 o;
      o.x = (y[q*4+0] - m) * inv * g4.x + b4.x;
      o.y = (y[q*4+1] - m) * inv * g4.y + b4.y;
      o.z = (y[q*4+2] - m) * inv * g4.z + b4.z;
      o.w = (y[q*4+3] - m) * inv * g4.w + b4.w;
      *(float4*)&Y[gr * 128 + seg + q * 4] = o;
    }
  }
}

// ---------------- packed-fragment helpers for k_ffn ----------------
// slot(row,ks,g) = (((row>>4)*4 + ks)*4 + g)*16 + (row&15),  k = ks*32 + g*8
template<bool LO>
__device__ __forceinline__ void stage_x_packed(uint4* __restrict__ dst,
    const float* __restrict__ src, long row0, int N) {
  #pragma unroll
  for (int it = 0; it < 2; ++it) {
    int s = it * 512 + threadIdx.x;
    int r16 = s & 15, g = (s >> 4) & 3, ks = (s >> 6) & 3, rb = s >> 8;
    long gr = row0 + rb * 16 + r16;
    uint4 w = make_uint4(0u, 0u, 0u, 0u);
    if (gr < N) {
      const float* p = src + gr * 128 + ks * 32 + g * 8;
      float v[8];
      *(float4*)&v[0] = *(const float4*)p;
      *(float4*)&v[4] = *(const float4*)(p + 4);
      unsigned q[8];
      #pragma unroll
      for (int j = 0; j < 8; ++j) {
        unsigned short h = f2bf(v[j]);
        q[j] = LO ? (unsigned)f2bf(v[j] - bf2f(h)) : (unsigned)h;
      }
      w.x = q[0] | (q[1] << 16);
      w.y = q[2] | (q[3] << 16);
      w.z = q[4] | (q[5] << 16);
      w.w = q[6] | (q[7] << 16);
    }
    dst[s] = w;
  }
}

__device__ __forceinline__ void load_afrags(short8 af[2][4], const uint4* __restrict__ Xp, int wr) {
  int lane = threadIdx.x & 63;
  #pragma unroll
  for (int mi = 0; mi < 2; ++mi)
    #pragma unroll
    for (int ks = 0; ks < 4; ++ks)
      af[mi][ks] = *(const short8*)&Xp[((wr >> 4) + mi) * 256 + ks * 64 + lane];
}

#define MF(a, b, c) __builtin_amdgcn_mfma_f32_16x16x32_bf16(a, b, c, 0, 0, 0)

// ---------------- big kernels ----------------
// round-4 exact: split-bf16 GEMM, plain store
__global__ __launch_bounds__(512) void k_gemm_plain(const float* __restrict__ X,
    const unsigned short* __restrict__ Wh, const unsigned short* __restrict__ Wl,
    float* __restrict__ Y, int N) {
  __shared__ __align__(16) unsigned short XsH[64][136];
  __shared__ __align__(16) unsigned short XsL[64][136];
  __shared__ __align__(16) unsigned short WsH[128][136];
  __shared__ __align__(16) unsigned short WsL[128][136];
  long row0 = (long)blockIdx.x * 64;
  stage_xf32_split(XsH, XsL, X, row0, N);
  stage_w(WsH, Wh, 128);
  stage_w(WsL, Wl, 128);
  __syncthreads();
  floatx4 zero = {0.f, 0.f, 0.f, 0.f};
  floatx4 acc[2][2] = {{zero, zero}, {zero, zero}};
  mfma_64x128_3(XsH, XsL, WsH, WsL, acc);
  int lane = threadIdx.x & 63;
  int wave = threadIdx.x >> 6;
  int rowb = (wave >> 2) * 32 + (lane >> 4) * 4;
  int colb = (wave & 3) * 32 + (lane & 15);
  #pragma unroll
  for (int mi = 0; mi < 2; ++mi)
    #pragma unroll
    for (int ni = 0; ni < 2; ++ni)
      #pragma unroll
      for (int r = 0; r < 4; ++r) {
        long gr = row0 + rowb + mi * 16 + r;
        if (gr < N) Y[gr * 128 + colb + ni * 16] = acc[mi][ni][r];
      }
}

// round-4 exact: split-bf16 GEMM + residual + LN epilogue
__global__ __launch_bounds__(512) void k_gemm_ln(const float* __restrict__ X,
    const unsigned short* __restrict__ Wh, const unsigned short* __restrict__ Wl,
    const float* __restrict__ bias,
    const float* __restrict__ g, const float* __restrict__ bl,
    float* __restrict__ Y, int N) {
  __shared__ __align__(16) unsigned short XsH[64][136];
  __shared__ __align__(16) unsigned short XsL[64][136];
  __shared__ union __align__(16) WY {
    struct { unsigned short h[128][136]; unsigned short l[128][136]; } w;
    float ys[64][132];
  } wy;
  long row0 = (long)blockIdx.x * 64;
  stage_xf32_split(XsH, XsL, X, row0, N);
  stage_w(wy.w.h, Wh, 128);
  stage_w(wy.w.l, Wl, 128);
  __syncthreads();
  floatx4 zero = {0.f, 0.f, 0.f, 0.f};
  floatx4 acc[2][2] = {{zero, zero}, {zero, zero}};
  mfma_64x128_3(XsH, XsL, wy.w.h, wy.w.l, acc);
  __syncthreads();
  frag_to_ys(wy.ys, acc);
  __syncthreads();
  ln_store(wy.ys, bias, X, g, bl, Y, row0, N);
}

// k_ffn v9 = r14's verified kernel + W2 register prefetch for ks 0,1 (the ONLY
// change this round; T14 async-split). The 4 short8 loads are issued during
// phase A so their ~250cyc L2 latency hides under the MFMA+pack+barrier; the
// barrier's vmcnt(0) confirms arrival; phase B's first 8 MFMAs run from regs.
// +16 VGPR (52 -> ~68), safely under the 85-reg 3-blocks/CU threshold.
__global__ __launch_bounds__(512) void k_ffn(const float* __restrict__ T1,
    const uint4* __restrict__ W1hp, const float* __restrict__ b1,
    const uint4* __restrict__ W2p, const float* __restrict__ b2,
    const float* __restrict__ gam, const float* __restrict__ bet,
    float* __restrict__ Y, int N) {
  __shared__ __align__(16) uint4 zx[1024];
  __shared__ __align__(16) float ys[64][132];
  uint4* zalt = (uint4*)ys;                     // 16KB of ys = second Z buffer
  long row0 = (long)blockIdx.x * 64;
  int lane = threadIdx.x & 63;
  int wave = threadIdx.x >> 6;
  int wr = (wave >> 2) * 32, wc = (wave & 3) * 32;
  int gq = lane >> 4, r16c = lane & 15;

  // X-hi fragments -> registers (2-barrier prologue)
  stage_x_packed<false>(zx, T1, row0, N);
  __syncthreads();
  short8 afh[2][4];
  load_afrags(afh, zx, wr);
  __syncthreads();                              // afh reads done; zx/zalt -> Z dbuf

  int zb0 = (((wr >> 4) + 0) * 4 + (wc >> 5)) * 4 + (r16c >> 3);
  int zb1 = (((wr >> 4) + 1) * 4 + (wc >> 5)) * 4 + (r16c >> 3);

  // per-wave global fragment bases (packed layout, coalesced across lanes)
  const uint4* p1h = W1hp + (wc >> 4) * 256;
  const uint4* p2b = W2p  + (wc >> 4) * 256;

  floatx4 zero = {0.f, 0.f, 0.f, 0.f};
  floatx4 acc2[2][2] = {{zero, zero}, {zero, zero}};

  for (int fc = 0; fc < 16; ++fc) {
    uint4* zb = (fc & 1) ? zalt : zx;
    unsigned short* Zu = (unsigned short*)zb;
    const uint4* ph = p1h + fc * 2048;
    const uint4* p2 = p2b + fc * 2048;
    // phase A: Zc = relu(X @ W1c^T + b1c)  (single bf16, 16 MFMA)
    floatx4 acc1[2][2] = {{zero, zero}, {zero, zero}};
    #pragma unroll
    for (int ks = 0; ks < 4; ++ks) {
      int nb = ks * 64 + lane;
      short8 bh0 = *(const short8*)&ph[nb];
      short8 bh1 = *(const short8*)&ph[nb + 256];
      acc1[0][0] = MF(afh[0][ks], bh0, acc1[0][0]);
      acc1[0][1] = MF(afh[0][ks], bh1, acc1[0][1]);
      acc1[1][0] = MF(afh[1][ks], bh0, acc1[1][0]);
      acc1[1][1] = MF(afh[1][ks], bh1, acc1[1][1]);
    }
    // prefetch W2 fragments for ks 0,1 (in flight across the Z pack + barrier)
    short8 s2a = *(const short8*)&p2[lane];          // ks0, col-block 0
    short8 s2b = *(const short8*)&p2[lane + 256];    // ks0, col-block 1
    short8 s2c = *(const short8*)&p2[lane + 64];     // ks1, col-block 0
    short8 s2d = *(const short8*)&p2[lane + 320];    // ks1, col-block 1
    float bv0 = b1[fc * 128 + wc + r16c];
    float bv1 = b1[fc * 128 + wc + 16 + r16c];
    #pragma unroll
    for (int mi = 0; mi < 2; ++mi) {
      int zbi = mi ? zb1 : zb0;
      #pragma unroll
      for (int ni = 0; ni < 2; ++ni) {
        float bv = ni ? bv1 : bv0;
        #pragma unroll
        for (int r = 0; r < 4; ++r) {
          float z = fmaxf(acc1[mi][ni][r] + bv, 0.f);
          Zu[(zbi + 2 * ni) * 128 + (4 * gq + r) * 8 + (r16c & 7)] = f2bf(z);
        }
      }
    }
    __syncthreads();                            // Z(fc) visible (only barrier this chunk)
    // phase B: acc2 += Zc @ W2c^T  (ks 0,1 from prefetched regs; ks 2,3 fresh)
    #pragma unroll
    for (int ks = 0; ks < 4; ++ks) {
      int za = (wr >> 4) * 256 + ks * 64 + lane;
      short8 a0 = *(const short8*)&zb[za];
      short8 a1 = *(const short8*)&zb[za + 256];
      short8 b0  = (ks == 0) ? s2a : (ks == 1) ? s2c
                   : *(const short8*)&p2[ks * 64 + lane];
      short8 b1f = (ks == 0) ? s2b : (ks == 1) ? s2d
                   : *(const short8*)&p2[ks * 64 + lane + 256];
      acc2[0][0] = MF(a0, b0,  acc2[0][0]);
      acc2[0][1] = MF(a0, b1f, acc2[0][1]);
      acc2[1][0] = MF(a1, b0,  acc2[1][0]);
      acc2[1][1] = MF(a1, b1f, acc2[1][1]);
    }
    // no second barrier: next phase A writes the OTHER buffer
  }
  __syncthreads();                              // last phase-B reads done before ys overlay
  frag_to_ys(ys, acc2);
  __syncthreads();
  ln_store(ys, b2, T1, gam, bet, Y, row0, N);
}

// ---------------- launcher ----------------
extern "C" void kernel_launch(void* const* d_in, const int* in_sizes, int n_in,
                              void* d_out, int out_size, void* d_ws, size_t ws_size,
                              hipStream_t stream) {
  const int N = in_sizes[0] / 128;
  const int E = in_sizes[1] / 2;
  const float* x     = (const float*)d_in[0];
  const int*   ei    = (const int*)d_in[1];
  const float* gcn_w = (const float*)d_in[2];
  const float* gcn_b = (const float*)d_in[3];
  const float* in_w  = (const float*)d_in[4];
  const float* in_b  = (const float*)d_in[5];
  const float* out_w = (const float*)d_in[6];
  const float* out_b = (const float*)d_in[7];
  const float* ln1_g = (const float*)d_in[8];
  const float* ln1_b = (const float*)d_in[9];
  const float* ff1_w = (const float*)d_in[10];
  const float* ff1_b = (const float*)d_in[11];
  const float* ff2_w = (const float*)d_in[12];
  const float* ff2_b = (const float*)d_in[13];
  const float* ln2_g = (const float*)d_in[14];
  const float* ln2_b = (const float*)d_in[15];
  float* out = (float*)d_out;

  char* w = (char*)d_ws;
  auto alloc = [&](size_t bytes) { char* p = w; w += (bytes + 255) & ~(size_t)255; return p; };
  float* deg  = (float*)alloc((size_t)N * 4);
  float* dinv = (float*)alloc((size_t)N * 4);
  int*   off  = (int*)alloc((size_t)(N + 1) * 4);
  int*   cur  = (int*)alloc((size_t)N * 4);
  int*   srcs = (int*)alloc((size_t)E * 4);
  float* h0   = (float*)alloc((size_t)N * 128 * 4);   // reused as B2
  float* Hb   = (float*)alloc((size_t)N * 128 * 4);
  float* B1   = (float*)alloc((size_t)N * 128 * 4);
  float* Wc   = (float*)alloc(2 * 16384 * 4);
  float* bc   = (float*)alloc(2 * 128 * 4);
  unsigned short* gcnh = (unsigned short*)alloc(16384 * 2);
  unsigned short* gcnl = (unsigned short*)alloc(16384 * 2);
  unsigned short* Wch  = (unsigned short*)alloc(2 * 16384 * 2);
  unsigned short* Wcl  = (unsigned short*)alloc(2 * 16384 * 2);
  unsigned short* ff1hp = (unsigned short*)alloc(2 * 262144 * 2);  // packed fragment order
  unsigned short* ff2p  = (unsigned short*)alloc(2 * 262144 * 2);
  float* B2 = h0;

  const int gN = (N + 255) / 256;
  const int gT = (N + 63) / 64;
  const int gV = (int)(((long)N * 32 + 255) / 256);
  const int nslots = 32768;                 // 2048*128/8 per FFN layer

  // CSR build
  k_fill1<<<gN, 256, 0, stream>>>(deg, N);
  k_edge_deg<<<(E + 255) / 256, 256, 0, stream>>>(ei, deg, E);
  k_rsqrt<<<gN, 256, 0, stream>>>(dinv, deg, N);
  k_scan<<<1, 1024, 0, stream>>>(deg, off, N);
  hipMemcpyAsync(cur, off, (size_t)N * 4, hipMemcpyDeviceToDevice, stream);
  k_scatter<<<(E + 255) / 256, 256, 0, stream>>>(ei, cur, srcs, E);

  // weight prep
  k_combine2<<<32, 256, 0, stream>>>(in_w, out_w, Wc);
  k_combine_b<<<2, 128, 0, stream>>>(in_b, out_w, out_b, bc);
  k_f32bf16_split<<<(16384 + 255) / 256, 256, 0, stream>>>(gcn_w, gcnh, gcnl, 16384);
  k_f32bf16_split<<<(32768 + 255) / 256, 256, 0, stream>>>(Wc, Wch, Wcl, 32768);
  for (int l = 0; l < 2; ++l) {
    k_pack_rows<<<(nslots + 255) / 256, 256, 0, stream>>>(
        ff1_w + (long)l * 262144, ff1hp + (long)l * 262144, (unsigned short*)nullptr, nslots);
    k_pack_cols<<<(nslots + 255) / 256, 256, 0, stream>>>(
        ff2_w + (long)l * 262144, ff2p + (long)l * 262144, 2048, nslots);
  }

  // GCN
  k_gemm_plain<<<gT, 512, 0, stream>>>(x, gcnh, gcnl, h0, N);
  k_gcn_agg<<<(N + 3) / 4, 256, 0, stream>>>(off, srcs, dinv, h0, gcn_b, Hb, N);

  for (int l = 0; l < 2; ++l) {
    const float* src = (l == 0) ? Hb : B2;
    k_gemm_ln<<<gT, 512, 0, stream>>>(src, Wch + l * 16384, Wcl + l * 16384, bc + l * 128,
                                      ln1_g + l * 128, ln1_b + l * 128, B1, N);
    k_ffn<<<gT, 512, 0, stream>>>(B1,
                                  (const uint4*)(ff1hp + (long)l * 262144),
                                  ff1_b + l * 2048,
                                  (const uint4*)(ff2p + (long)l * 262144),
                                  ff2_b + l * 128,
                                  ln2_g + l * 128, ln2_b + l * 128, B2, N);
  }

  k_final<<<gV, 256, 0, stream>>>(B2, Hb, out, N);
}

// Round 18
// 499.777 us; speedup vs baseline: 2.5807x; 1.0130x over previous
//
#include <hip/hip_runtime.h>

using short8  = __attribute__((ext_vector_type(8))) short;
using floatx4 = __attribute__((ext_vector_type(4))) float;

__device__ __forceinline__ unsigned short f2bf(float x) {
  unsigned int u = __float_as_uint(x);
  return (unsigned short)((u + 0x7FFFu + ((u >> 16) & 1u)) >> 16);
}
__device__ __forceinline__ float bf2f(unsigned short h) {
  return __uint_as_float(((unsigned int)h) << 16);
}

// ---------------- small elementwise / setup kernels ----------------
__global__ void k_fill1(float* __restrict__ p, int n) {
  int i = blockIdx.x * 256 + threadIdx.x;
  if (i < n) p[i] = 1.0f;
}

__global__ void k_edge_deg(const int* __restrict__ ei, float* __restrict__ deg, int E) {
  int e = blockIdx.x * 256 + threadIdx.x;
  if (e < E) atomicAdd(&deg[ei[E + e]], 1.0f);
}

__global__ void k_rsqrt(float* __restrict__ dinv, const float* __restrict__ deg, int n) {
  int i = blockIdx.x * 256 + threadIdx.x;
  if (i < n) dinv[i] = rsqrtf(deg[i]);
}

// hi = bf16(x); lo = bf16(x - hi)
__global__ void k_f32bf16_split(const float* __restrict__ src, unsigned short* __restrict__ hi,
                                unsigned short* __restrict__ lo, int n) {
  int i = blockIdx.x * 256 + threadIdx.x;
  if (i < n) {
    float x = src[i];
    unsigned short h = f2bf(x);
    hi[i] = h;
    lo[i] = f2bf(x - bf2f(h));
  }
}

// ---------------- packed-fragment weight prep (global fragment order) ----------------
// slot within 128x128 chunk: rem = c16*256 + ks*64 + g*16 + r16  (uint4 slots, 8 bf16 each)
//   covers out-feature = c16*16 + r16, k = ks*32 + g*8
// k_pack_rows: W[OUT][128], chunks along OUT (W1: OUT=2048)
__global__ void k_pack_rows(const float* __restrict__ W, unsigned short* __restrict__ hi,
                            unsigned short* __restrict__ lo, int nslots) {
  int s = blockIdx.x * 256 + threadIdx.x;
  if (s >= nslots) return;
  int chunk = s >> 11, rem = s & 2047;
  int c16 = rem >> 8, ks = (rem >> 6) & 3, g = (rem >> 4) & 3, r16 = rem & 15;
  int out = chunk * 128 + c16 * 16 + r16;
  int k   = ks * 32 + g * 8;
  const float* p = W + (long)out * 128 + k;
  float v[8];
  *(float4*)&v[0] = *(const float4*)p;
  *(float4*)&v[4] = *(const float4*)(p + 4);
  unsigned h[8], l[8];
  #pragma unroll
  for (int j = 0; j < 8; ++j) {
    unsigned short hh = f2bf(v[j]);
    h[j] = hh;
    l[j] = f2bf(v[j] - bf2f(hh));
  }
  uint4 wh = make_uint4(h[0] | (h[1] << 16), h[2] | (h[3] << 16),
                        h[4] | (h[5] << 16), h[6] | (h[7] << 16));
  *(uint4*)&hi[(long)s * 8] = wh;
  if (lo) {
    uint4 wl = make_uint4(l[0] | (l[1] << 16), l[2] | (l[3] << 16),
                          l[4] | (l[5] << 16), l[6] | (l[7] << 16));
    *(uint4*)&lo[(long)s * 8] = wl;
  }
}

// k_pack_cols: W[128][K], chunks along K (W2: K=2048), hi only
__global__ void k_pack_cols(const float* __restrict__ W, unsigned short* __restrict__ hi,
                            int K, int nslots) {
  int s = blockIdx.x * 256 + threadIdx.x;
  if (s >= nslots) return;
  int chunk = s >> 11, rem = s & 2047;
  int c16 = rem >> 8, ks = (rem >> 6) & 3, g = (rem >> 4) & 3, r16 = rem & 15;
  int out = c16 * 16 + r16;
  int k   = chunk * 128 + ks * 32 + g * 8;
  const float* p = W + (long)out * K + k;
  float v[8];
  *(float4*)&v[0] = *(const float4*)p;
  *(float4*)&v[4] = *(const float4*)(p + 4);
  unsigned h[8];
  #pragma unroll
  for (int j = 0; j < 8; ++j) h[j] = f2bf(v[j]);
  uint4 wh = make_uint4(h[0] | (h[1] << 16), h[2] | (h[3] << 16),
                        h[4] | (h[5] << 16), h[6] | (h[7] << 16));
  *(uint4*)&hi[(long)s * 8] = wh;
}

// ---------------- CSR build: scan + scatter ----------------
__global__ __launch_bounds__(1024) void k_scan(const float* __restrict__ deg,
                                               int* __restrict__ off, int N) {
  __shared__ int wsum[16];
  __shared__ int carry;
  if (threadIdx.x == 0) carry = 0;
  int lane = threadIdx.x & 63, wv = threadIdx.x >> 6;
  for (int base = 0; base < N; base += 1024) {
    int i = base + threadIdx.x;
    int c = (i < N) ? ((int)deg[i] - 1) : 0;
    int s = c;
    #pragma unroll
    for (int o = 1; o < 64; o <<= 1) {
      int t = __shfl_up(s, o);
      if (lane >= o) s += t;
    }
    __syncthreads();
    if (lane == 63) wsum[wv] = s;
    __syncthreads();
    int wpre = 0, total = 0;
    #pragma unroll
    for (int w = 0; w < 16; ++w) {
      int v = wsum[w];
      if (w < wv) wpre += v;
      total += v;
    }
    if (i < N) off[i] = carry + wpre + s - c;
    __syncthreads();
    if (threadIdx.x == 0) carry += total;
  }
  __syncthreads();
  if (threadIdx.x == 0) off[N] = carry;
}

__global__ void k_scatter(const int* __restrict__ ei, int* __restrict__ cur,
                          int* __restrict__ srcs, int E) {
  int e = blockIdx.x * 256 + threadIdx.x;
  if (e < E) {
    int r = ei[e], c = ei[E + e];
    int p = atomicAdd(&cur[c], 1);
    srcs[p] = r;
  }
}

__global__ __launch_bounds__(256) void k_gcn_agg(const int* __restrict__ off,
    const int* __restrict__ srcs, const float* __restrict__ dinv,
    const float* __restrict__ h0, const float* __restrict__ gcn_b,
    float* __restrict__ Hb, int N) {
  int node = blockIdx.x * 4 + (threadIdx.x >> 6);
  if (node >= N) return;
  int c2 = (threadIdx.x & 63) * 2;
  float dc = dinv[node];
  float a0 = 0.f, a1 = 0.f;
  int j = off[node], end = off[node + 1];
  for (; j + 1 < end; j += 2) {
    int s0 = srcs[j], s1 = srcs[j + 1];
    float w0 = dinv[s0] * dc, w1 = dinv[s1] * dc;
    float2 h0v = *(const float2*)&h0[(long)s0 * 128 + c2];
    float2 h1v = *(const float2*)&h0[(long)s1 * 128 + c2];
    a0 += w0 * h0v.x + w1 * h1v.x;
    a1 += w0 * h0v.y + w1 * h1v.y;
  }
  if (j < end) {
    int s0 = srcs[j];
    float w0 = dinv[s0] * dc;
    float2 hv = *(const float2*)&h0[(long)s0 * 128 + c2];
    a0 += w0 * hv.x;
    a1 += w0 * hv.y;
  }
  float2 hv = *(const float2*)&h0[(long)node * 128 + c2];
  float2 b  = *(const float2*)&gcn_b[c2];
  float v0 = a0 + dc * dc * hv.x + b.x;
  float v1 = a1 + dc * dc * hv.y + b.y;
  *(float2*)&Hb[(long)node * 128 + c2] = make_float2(fmaxf(v0, 0.f), fmaxf(v1, 0.f));
}

__global__ void k_final(const float* __restrict__ T, const float* __restrict__ Hb,
                        float* __restrict__ out, int N) {
  long i = (long)blockIdx.x * 256 + threadIdx.x;
  if (i >= (long)N * 32) return;
  long off = i * 4;
  float4 t = *(const float4*)&T[off];
  float4 h = *(const float4*)&Hb[off];
  float4 o;
  o.x = fmaxf(t.x + h.x, 0.f);
  o.y = fmaxf(t.y + h.y, 0.f);
  o.z = fmaxf(t.z + h.z, 0.f);
  o.w = fmaxf(t.w + h.w, 0.f);
  *(float4*)&out[off] = o;
}

// ---- parallel combine: Wc[l] = out_w[l] @ Wv[l] ----
__global__ __launch_bounds__(256) void k_combine2(const float* __restrict__ in_w,
    const float* __restrict__ out_w, float* __restrict__ Wc) {
  int l = blockIdx.x >> 4, b = blockIdx.x & 15;
  const float* Wv = in_w + (long)l * 384 * 128 + 256 * 128;
  const float* Wo = out_w + (long)l * 128 * 128;
  int i  = b * 8 + (threadIdx.x >> 5);
  int j4 = (threadIdx.x & 31) * 4;
  float4 acc = make_float4(0.f, 0.f, 0.f, 0.f);
  for (int k = 0; k < 128; ++k) {
    float w = Wo[i * 128 + k];
    float4 v = *(const float4*)&Wv[k * 128 + j4];
    acc.x += w * v.x;
    acc.y += w * v.y;
    acc.z += w * v.z;
    acc.w += w * v.w;
  }
  *(float4*)&Wc[(long)l * 16384 + i * 128 + j4] = acc;
}

// bc[l] = out_w[l] @ bv[l] + out_b[l]
__global__ void k_combine_b(const float* __restrict__ in_b, const float* __restrict__ out_w,
                            const float* __restrict__ out_b, float* __restrict__ bc) {
  int l = blockIdx.x;
  const float* bv = in_b + l * 384 + 256;
  const float* Wo = out_w + (long)l * 128 * 128;
  int i = threadIdx.x;
  if (i < 128) {
    float acc = out_b[l * 128 + i];
    for (int k = 0; k < 128; ++k) acc += Wo[i * 128 + k] * bv[k];
    bc[l * 128 + i] = acc;
  }
}

// ---------------- round-4 MFMA GEMM helpers (verified; FROZEN) ----------------
__device__ __forceinline__ void stage_xf32_split(unsigned short (*dh)[136], unsigned short (*dl)[136],
                                                 const float* __restrict__ src, long row0, int N) {
  #pragma unroll
  for (int it = 0; it < 2; ++it) {
    int i = it * 512 + threadIdx.x;
    int r = i >> 4, c8 = (i & 15) * 8;
    long gr = row0 + r;
    uint4 wh = make_uint4(0u, 0u, 0u, 0u);
    uint4 wl = make_uint4(0u, 0u, 0u, 0u);
    if (gr < N) {
      const float* p = src + gr * 128 + c8;
      float v[8];
      *(float4*)&v[0] = *(const float4*)p;
      *(float4*)&v[4] = *(const float4*)(p + 4);
      unsigned short h[8], l[8];
      #pragma unroll
      for (int j = 0; j < 8; ++j) {
        h[j] = f2bf(v[j]);
        l[j] = f2bf(v[j] - bf2f(h[j]));
      }
      wh.x = (unsigned)h[0] | ((unsigned)h[1] << 16);
      wh.y = (unsigned)h[2] | ((unsigned)h[3] << 16);
      wh.z = (unsigned)h[4] | ((unsigned)h[5] << 16);
      wh.w = (unsigned)h[6] | ((unsigned)h[7] << 16);
      wl.x = (unsigned)l[0] | ((unsigned)l[1] << 16);
      wl.y = (unsigned)l[2] | ((unsigned)l[3] << 16);
      wl.z = (unsigned)l[4] | ((unsigned)l[5] << 16);
      wl.w = (unsigned)l[6] | ((unsigned)l[7] << 16);
    }
    *(uint4*)&dh[r][c8] = wh;
    *(uint4*)&dl[r][c8] = wl;
  }
}

__device__ __forceinline__ void stage_w(unsigned short (*dst)[136], const unsigned short* __restrict__ src,
                                        int ld) {
  #pragma unroll
  for (int it = 0; it < 4; ++it) {
    int i = it * 512 + threadIdx.x;
    int r = i >> 4, c8 = (i & 15) * 8;
    *(uint4*)&dst[r][c8] = *(const uint4*)&src[(long)r * ld + c8];
  }
}

__device__ __forceinline__ void mfma_64x128_3(const unsigned short (*Ah)[136], const unsigned short (*Al)[136],
                                              const unsigned short (*Bh)[136], const unsigned short (*Bl)[136],
                                              floatx4 acc[2][2]) {
  int lane = threadIdx.x & 63;
  int wave = threadIdx.x >> 6;
  int wr = (wave >> 2) * 32;
  int wc = (wave & 3) * 32;
  int r16 = lane & 15;
  int k8 = (lane >> 4) * 8;
  #pragma unroll
  for (int ks = 0; ks < 4; ++ks) {
    int k0 = ks * 32 + k8;
    short8 a0h = *(const short8*)&Ah[wr + r16][k0];
    short8 a1h = *(const short8*)&Ah[wr + 16 + r16][k0];
    short8 a0l = *(const short8*)&Al[wr + r16][k0];
    short8 a1l = *(const short8*)&Al[wr + 16 + r16][k0];
    short8 b0h = *(const short8*)&Bh[wc + r16][k0];
    short8 b1h = *(const short8*)&Bh[wc + 16 + r16][k0];
    short8 b0l = *(const short8*)&Bl[wc + r16][k0];
    short8 b1l = *(const short8*)&Bl[wc + 16 + r16][k0];
    acc[0][0] = __builtin_amdgcn_mfma_f32_16x16x32_bf16(a0h, b0h, acc[0][0], 0, 0, 0);
    acc[0][0] = __builtin_amdgcn_mfma_f32_16x16x32_bf16(a0h, b0l, acc[0][0], 0, 0, 0);
    acc[0][0] = __builtin_amdgcn_mfma_f32_16x16x32_bf16(a0l, b0h, acc[0][0], 0, 0, 0);
    acc[0][1] = __builtin_amdgcn_mfma_f32_16x16x32_bf16(a0h, b1h, acc[0][1], 0, 0, 0);
    acc[0][1] = __builtin_amdgcn_mfma_f32_16x16x32_bf16(a0h, b1l, acc[0][1], 0, 0, 0);
    acc[0][1] = __builtin_amdgcn_mfma_f32_16x16x32_bf16(a0l, b1h, acc[0][1], 0, 0, 0);
    acc[1][0] = __builtin_amdgcn_mfma_f32_16x16x32_bf16(a1h, b0h, acc[1][0], 0, 0, 0);
    acc[1][0] = __builtin_amdgcn_mfma_f32_16x16x32_bf16(a1h, b0l, acc[1][0], 0, 0, 0);
    acc[1][0] = __builtin_amdgcn_mfma_f32_16x16x32_bf16(a1l, b0h, acc[1][0], 0, 0, 0);
    acc[1][1] = __builtin_amdgcn_mfma_f32_16x16x32_bf16(a1h, b1h, acc[1][1], 0, 0, 0);
    acc[1][1] = __builtin_amdgcn_mfma_f32_16x16x32_bf16(a1h, b1l, acc[1][1], 0, 0, 0);
    acc[1][1] = __builtin_amdgcn_mfma_f32_16x16x32_bf16(a1l, b1h, acc[1][1], 0, 0, 0);
  }
}

__device__ __forceinline__ void frag_to_ys(float (*Ys)[132], const floatx4 acc[2][2]) {
  int lane = threadIdx.x & 63;
  int wave = threadIdx.x >> 6;
  int row0 = (wave >> 2) * 32 + (lane >> 4) * 4;
  int col0 = (wave & 3) * 32 + (lane & 15);
  #pragma unroll
  for (int mi = 0; mi < 2; ++mi)
    #pragma unroll
    for (int ni = 0; ni < 2; ++ni)
      #pragma unroll
      for (int r = 0; r < 4; ++r)
        Ys[row0 + mi * 16 + r][col0 + ni * 16] = acc[mi][ni][r];
}

__device__ __forceinline__ void ln_store(const float (*Ys)[132],
    const float* __restrict__ bias, const float* __restrict__ res,
    const float* __restrict__ g, const float* __restrict__ bl,
    float* __restrict__ Y, long row0, int N) {
  int r = threadIdx.x >> 3;
  int seg = (threadIdx.x & 7) * 16;
  long gr = row0 + r;
  float y[16];
  float s = 0.f, s2 = 0.f;
  if (gr < N) {
    #pragma unroll
    for (int q = 0; q < 4; ++q) {
      float4 v  = *(const float4*)&Ys[r][seg + q * 4];
      float4 b4 = *(const float4*)&bias[seg + q * 4];
      float4 rv = *(const float4*)&res[gr * 128 + seg + q * 4];
      float t0 = v.x + b4.x + rv.x;
      float t1 = v.y + b4.y + rv.y;
      float t2 = v.z + b4.z + rv.z;
      float t3 = v.w + b4.w + rv.w;
      y[q*4+0] = t0; y[q*4+1] = t1; y[q*4+2] = t2; y[q*4+3] = t3;
      s  += t0 + t1 + t2 + t3;
      s2 += t0*t0 + t1*t1 + t2*t2 + t3*t3;
    }
  } else {
    #pragma unroll
    for (int q = 0; q < 16; ++q) y[q] = 0.f;
  }
  #pragma unroll
  for (int off = 1; off < 8; off <<= 1) {
    s  += __shfl_xor(s, off);
    s2 += __shfl_xor(s2, off);
  }
  float m   = s * (1.f / 128.f);
  float var = s2 * (1.f / 128.f) - m * m;
  float inv = rsqrtf(var + 1e-5f);
  if (gr < N) {
    #pragma unroll
    for (int q = 0; q < 4; ++q) {
      float4 g4 = *(const float4*)&g[seg + q * 4];
      float4 b4 = *(const float4*)&bl[seg + q * 4];
      float4 o;
      o.x = (y[q*4+0] - m) * inv * g4.x + b4.x;
      o.y = (y[q*4+1] - m) * inv * g4.y + b4.y;
      o.z = (y[q*4+2] - m) * inv * g4.z + b4.z;
      o.w = (y[q*4+3] - m) * inv * g4.w + b4.w;
      *(float4*)&Y[gr * 128 + seg + q * 4] = o;
    }
  }
}

// ---------------- packed-fragment helpers for k_ffn (verified) ----------------
// slot(row,ks,g) = (((row>>4)*4 + ks)*4 + g)*16 + (row&15),  k = ks*32 + g*8
template<bool LO>
__device__ __forceinline__ void stage_x_packed(uint4* __restrict__ dst,
    const float* __restrict__ src, long row0, int N) {
  #pragma unroll
  for (int it = 0; it < 2; ++it) {
    int s = it * 512 + threadIdx.x;
    int r16 = s & 15, g = (s >> 4) & 3, ks = (s >> 6) & 3, rb = s >> 8;
    long gr = row0 + rb * 16 + r16;
    uint4 w = make_uint4(0u, 0u, 0u, 0u);
    if (gr < N) {
      const float* p = src + gr * 128 + ks * 32 + g * 8;
      float v[8];
      *(float4*)&v[0] = *(const float4*)p;
      *(float4*)&v[4] = *(const float4*)(p + 4);
      unsigned q[8];
      #pragma unroll
      for (int j = 0; j < 8; ++j) {
        unsigned short h = f2bf(v[j]);
        q[j] = LO ? (unsigned)f2bf(v[j] - bf2f(h)) : (unsigned)h;
      }
      w.x = q[0] | (q[1] << 16);
      w.y = q[2] | (q[3] << 16);
      w.z = q[4] | (q[5] << 16);
      w.w = q[6] | (q[7] << 16);
    }
    dst[s] = w;
  }
}

__device__ __forceinline__ void load_afrags(short8 af[2][4], const uint4* __restrict__ Xp, int wr) {
  int lane = threadIdx.x & 63;
  #pragma unroll
  for (int mi = 0; mi < 2; ++mi)
    #pragma unroll
    for (int ks = 0; ks < 4; ++ks)
      af[mi][ks] = *(const short8*)&Xp[((wr >> 4) + mi) * 256 + ks * 64 + lane];
}

#define MF(a, b, c) __builtin_amdgcn_mfma_f32_16x16x32_bf16(a, b, c, 0, 0, 0)

// ---------------- big kernels ----------------
// round-4 exact (FROZEN): split-bf16 GEMM, plain store
__global__ __launch_bounds__(512) void k_gemm_plain(const float* __restrict__ X,
    const unsigned short* __restrict__ Wh, const unsigned short* __restrict__ Wl,
    float* __restrict__ Y, int N) {
  __shared__ __align__(16) unsigned short XsH[64][136];
  __shared__ __align__(16) unsigned short XsL[64][136];
  __shared__ __align__(16) unsigned short WsH[128][136];
  __shared__ __align__(16) unsigned short WsL[128][136];
  long row0 = (long)blockIdx.x * 64;
  stage_xf32_split(XsH, XsL, X, row0, N);
  stage_w(WsH, Wh, 128);
  stage_w(WsL, Wl, 128);
  __syncthreads();
  floatx4 zero = {0.f, 0.f, 0.f, 0.f};
  floatx4 acc[2][2] = {{zero, zero}, {zero, zero}};
  mfma_64x128_3(XsH, XsL, WsH, WsL, acc);
  int lane = threadIdx.x & 63;
  int wave = threadIdx.x >> 6;
  int rowb = (wave >> 2) * 32 + (lane >> 4) * 4;
  int colb = (wave & 3) * 32 + (lane & 15);
  #pragma unroll
  for (int mi = 0; mi < 2; ++mi)
    #pragma unroll
    for (int ni = 0; ni < 2; ++ni)
      #pragma unroll
      for (int r = 0; r < 4; ++r) {
        long gr = row0 + rowb + mi * 16 + r;
        if (gr < N) Y[gr * 128 + colb + ni * 16] = acc[mi][ni][r];
      }
}

// round-4 exact (FROZEN): split-bf16 GEMM + residual + LN epilogue
__global__ __launch_bounds__(512) void k_gemm_ln(const float* __restrict__ X,
    const unsigned short* __restrict__ Wh, const unsigned short* __restrict__ Wl,
    const float* __restrict__ bias,
    const float* __restrict__ g, const float* __restrict__ bl,
    float* __restrict__ Y, int N) {
  __shared__ __align__(16) unsigned short XsH[64][136];
  __shared__ __align__(16) unsigned short XsL[64][136];
  __shared__ union __align__(16) WY {
    struct { unsigned short h[128][136]; unsigned short l[128][136]; } w;
    float ys[64][132];
  } wy;
  long row0 = (long)blockIdx.x * 64;
  stage_xf32_split(XsH, XsL, X, row0, N);
  stage_w(wy.w.h, Wh, 128);
  stage_w(wy.w.l, Wl, 128);
  __syncthreads();
  floatx4 zero = {0.f, 0.f, 0.f, 0.f};
  floatx4 acc[2][2] = {{zero, zero}, {zero, zero}};
  mfma_64x128_3(XsH, XsL, wy.w.h, wy.w.l, acc);
  __syncthreads();
  frag_to_ys(wy.ys, acc);
  __syncthreads();
  ln_store(wy.ys, bias, X, g, bl, Y, row0, N);
}

// k_ffn v10 = r15-verified + next-chunk W1 register prefetch (ks0/1), the ONLY
// change this round. Loads issue right after the barrier, flying under phase
// B's 16 MFMAs; next phase A's first 8 MFMAs run from registers. Values and
// sync structure identical -> numerics unchanged.
__global__ __launch_bounds__(512) void k_ffn(const float* __restrict__ T1,
    const uint4* __restrict__ W1hp, const float* __restrict__ b1,
    const uint4* __restrict__ W2p, const float* __restrict__ b2,
    const float* __restrict__ gam, const float* __restrict__ bet,
    float* __restrict__ Y, int N) {
  __shared__ __align__(16) uint4 zx[1024];
  __shared__ __align__(16) float ys[64][132];
  uint4* zalt = (uint4*)ys;                     // 16KB of ys = second Z buffer
  long row0 = (long)blockIdx.x * 64;
  int lane = threadIdx.x & 63;
  int wave = threadIdx.x >> 6;
  int wr = (wave >> 2) * 32, wc = (wave & 3) * 32;
  int gq = lane >> 4, r16c = lane & 15;

  stage_x_packed<false>(zx, T1, row0, N);
  __syncthreads();
  short8 afh[2][4];
  load_afrags(afh, zx, wr);
  __syncthreads();                              // afh reads done; zx/zalt -> Z dbuf

  int zb0 = (((wr >> 4) + 0) * 4 + (wc >> 5)) * 4 + (r16c >> 3);
  int zb1 = (((wr >> 4) + 1) * 4 + (wc >> 5)) * 4 + (r16c >> 3);

  const uint4* p1h = W1hp + (wc >> 4) * 256;
  const uint4* p2b = W2p  + (wc >> 4) * 256;

  floatx4 zero = {0.f, 0.f, 0.f, 0.f};
  floatx4 acc2[2][2] = {{zero, zero}, {zero, zero}};

  // prefetch chunk-0 W1 ks0/1 fragments
  short8 w1a = *(const short8*)&p1h[lane];
  short8 w1b = *(const short8*)&p1h[lane + 256];
  short8 w1c = *(const short8*)&p1h[lane + 64];
  short8 w1d = *(const short8*)&p1h[lane + 320];

  for (int fc = 0; fc < 16; ++fc) {
    uint4* zb = (fc & 1) ? zalt : zx;
    unsigned short* Zu = (unsigned short*)zb;
    const uint4* ph = p1h + fc * 2048;
    const uint4* p2 = p2b + fc * 2048;
    // phase A: Zc = relu(X @ W1c^T + b1c)  (ks0/1 from prefetched regs)
    floatx4 acc1[2][2] = {{zero, zero}, {zero, zero}};
    #pragma unroll
    for (int ks = 0; ks < 4; ++ks) {
      short8 bh0 = (ks == 0) ? w1a : (ks == 1) ? w1c
                   : *(const short8*)&ph[ks * 64 + lane];
      short8 bh1 = (ks == 0) ? w1b : (ks == 1) ? w1d
                   : *(const short8*)&ph[ks * 64 + lane + 256];
      acc1[0][0] = MF(afh[0][ks], bh0, acc1[0][0]);
      acc1[0][1] = MF(afh[0][ks], bh1, acc1[0][1]);
      acc1[1][0] = MF(afh[1][ks], bh0, acc1[1][0]);
      acc1[1][1] = MF(afh[1][ks], bh1, acc1[1][1]);
    }
    // prefetch W2 fragments for ks 0,1 (in flight across the Z pack + barrier)
    short8 s2a = *(const short8*)&p2[lane];
    short8 s2b = *(const short8*)&p2[lane + 256];
    short8 s2c = *(const short8*)&p2[lane + 64];
    short8 s2d = *(const short8*)&p2[lane + 320];
    float bv0 = b1[fc * 128 + wc + r16c];
    float bv1 = b1[fc * 128 + wc + 16 + r16c];
    #pragma unroll
    for (int mi = 0; mi < 2; ++mi) {
      int zbi = mi ? zb1 : zb0;
      #pragma unroll
      for (int ni = 0; ni < 2; ++ni) {
        float bv = ni ? bv1 : bv0;
        #pragma unroll
        for (int r = 0; r < 4; ++r) {
          float z = fmaxf(acc1[mi][ni][r] + bv, 0.f);
          Zu[(zbi + 2 * ni) * 128 + (4 * gq + r) * 8 + (r16c & 7)] = f2bf(z);
        }
      }
    }
    __syncthreads();                            // Z(fc) visible (only barrier this chunk)
    // prefetch next chunk's W1 ks0/1 (flies under phase B; index clamped)
    {
      int nfc = (fc < 15) ? fc + 1 : fc;
      const uint4* pn = p1h + nfc * 2048;
      w1a = *(const short8*)&pn[lane];
      w1b = *(const short8*)&pn[lane + 256];
      w1c = *(const short8*)&pn[lane + 64];
      w1d = *(const short8*)&pn[lane + 320];
    }
    // phase B: acc2 += Zc @ W2c^T  (ks 0,1 from prefetched regs; ks 2,3 fresh)
    #pragma unroll
    for (int ks = 0; ks < 4; ++ks) {
      int za = (wr >> 4) * 256 + ks * 64 + lane;
      short8 a0 = *(const short8*)&zb[za];
      short8 a1 = *(const short8*)&zb[za + 256];
      short8 b0  = (ks == 0) ? s2a : (ks == 1) ? s2c
                   : *(const short8*)&p2[ks * 64 + lane];
      short8 b1f = (ks == 0) ? s2b : (ks == 1) ? s2d
                   : *(const short8*)&p2[ks * 64 + lane + 256];
      acc2[0][0] = MF(a0, b0,  acc2[0][0]);
      acc2[0][1] = MF(a0, b1f, acc2[0][1]);
      acc2[1][0] = MF(a1, b0,  acc2[1][0]);
      acc2[1][1] = MF(a1, b1f, acc2[1][1]);
    }
    // no second barrier: next phase A writes the OTHER buffer
  }
  __syncthreads();                              // last phase-B reads done before ys overlay
  frag_to_ys(ys, acc2);
  __syncthreads();
  ln_store(ys, b2, T1, gam, bet, Y, row0, N);
}

// ---------------- launcher ----------------
extern "C" void kernel_launch(void* const* d_in, const int* in_sizes, int n_in,
                              void* d_out, int out_size, void* d_ws, size_t ws_size,
                              hipStream_t stream) {
  const int N = in_sizes[0] / 128;
  const int E = in_sizes[1] / 2;
  const float* x     = (const float*)d_in[0];
  const int*   ei    = (const int*)d_in[1];
  const float* gcn_w = (const float*)d_in[2];
  const float* gcn_b = (const float*)d_in[3];
  const float* in_w  = (const float*)d_in[4];
  const float* in_b  = (const float*)d_in[5];
  const float* out_w = (const float*)d_in[6];
  const float* out_b = (const float*)d_in[7];
  const float* ln1_g = (const float*)d_in[8];
  const float* ln1_b = (const float*)d_in[9];
  const float* ff1_w = (const float*)d_in[10];
  const float* ff1_b = (const float*)d_in[11];
  const float* ff2_w = (const float*)d_in[12];
  const float* ff2_b = (const float*)d_in[13];
  const float* ln2_g = (const float*)d_in[14];
  const float* ln2_b = (const float*)d_in[15];
  float* out = (float*)d_out;

  char* w = (char*)d_ws;
  auto alloc = [&](size_t bytes) { char* p = w; w += (bytes + 255) & ~(size_t)255; return p; };
  float* deg  = (float*)alloc((size_t)N * 4);
  float* dinv = (float*)alloc((size_t)N * 4);
  int*   off  = (int*)alloc((size_t)(N + 1) * 4);
  int*   cur  = (int*)alloc((size_t)N * 4);
  int*   srcs = (int*)alloc((size_t)E * 4);
  float* h0   = (float*)alloc((size_t)N * 128 * 4);   // reused as B2
  float* Hb   = (float*)alloc((size_t)N * 128 * 4);
  float* B1   = (float*)alloc((size_t)N * 128 * 4);
  float* Wc   = (float*)alloc(2 * 16384 * 4);
  float* bc   = (float*)alloc(2 * 128 * 4);
  unsigned short* gcnh = (unsigned short*)alloc(16384 * 2);
  unsigned short* gcnl = (unsigned short*)alloc(16384 * 2);
  unsigned short* Wch  = (unsigned short*)alloc(2 * 16384 * 2);
  unsigned short* Wcl  = (unsigned short*)alloc(2 * 16384 * 2);
  unsigned short* ff1hp = (unsigned short*)alloc(2 * 262144 * 2);  // packed fragment order
  unsigned short* ff2p  = (unsigned short*)alloc(2 * 262144 * 2);
  float* B2 = h0;

  const int gN = (N + 255) / 256;
  const int gT = (N + 63) / 64;
  const int gV = (int)(((long)N * 32 + 255) / 256);
  const int nslots = 32768;                 // 2048*128/8 per FFN layer

  // CSR build
  k_fill1<<<gN, 256, 0, stream>>>(deg, N);
  k_edge_deg<<<(E + 255) / 256, 256, 0, stream>>>(ei, deg, E);
  k_rsqrt<<<gN, 256, 0, stream>>>(dinv, deg, N);
  k_scan<<<1, 1024, 0, stream>>>(deg, off, N);
  hipMemcpyAsync(cur, off, (size_t)N * 4, hipMemcpyDeviceToDevice, stream);
  k_scatter<<<(E + 255) / 256, 256, 0, stream>>>(ei, cur, srcs, E);

  // weight prep
  k_combine2<<<32, 256, 0, stream>>>(in_w, out_w, Wc);
  k_combine_b<<<2, 128, 0, stream>>>(in_b, out_w, out_b, bc);
  k_f32bf16_split<<<(16384 + 255) / 256, 256, 0, stream>>>(gcn_w, gcnh, gcnl, 16384);
  k_f32bf16_split<<<(32768 + 255) / 256, 256, 0, stream>>>(Wc, Wch, Wcl, 32768);
  for (int l = 0; l < 2; ++l) {
    k_pack_rows<<<(nslots + 255) / 256, 256, 0, stream>>>(
        ff1_w + (long)l * 262144, ff1hp + (long)l * 262144, (unsigned short*)nullptr, nslots);
    k_pack_cols<<<(nslots + 255) / 256, 256, 0, stream>>>(
        ff2_w + (long)l * 262144, ff2p + (long)l * 262144, 2048, nslots);
  }

  // GCN
  k_gemm_plain<<<gT, 512, 0, stream>>>(x, gcnh, gcnl, h0, N);
  k_gcn_agg<<<(N + 3) / 4, 256, 0, stream>>>(off, srcs, dinv, h0, gcn_b, Hb, N);

  for (int l = 0; l < 2; ++l) {
    const float* src = (l == 0) ? Hb : B2;
    k_gemm_ln<<<gT, 512, 0, stream>>>(src, Wch + l * 16384, Wcl + l * 16384, bc + l * 128,
                                      ln1_g + l * 128, ln1_b + l * 128, B1, N);
    k_ffn<<<gT, 512, 0, stream>>>(B1,
                                  (const uint4*)(ff1hp + (long)l * 262144),
                                  ff1_b + l * 2048,
                                  (const uint4*)(ff2p + (long)l * 262144),
                                  ff2_b + l * 128,
                                  ln2_g + l * 128, ln2_b + l * 128, B2, N);
  }

  k_final<<<gV, 256, 0, stream>>>(B2, Hb, out, N);
}